// Round 1
// baseline (8589.019 us; speedup 1.0000x reference)
//
#include <hip/hip_runtime.h>
#include <cstddef>

// Problem constants
#define HW 16384           // 128*128
#define NELEM 819200       // 2*25*HW

__device__ __forceinline__ float sp_f(float x) {
    // jax.nn.softplus == logaddexp(x, 0) == max(x,0) + log1p(exp(-|x|))
    return fmaxf(x, 0.f) + log1pf(expf(-fabsf(x)));
}
__device__ __forceinline__ float sig_f(float x) {
    return 1.f / (1.f + expf(-x));
}

// ---------------- 3D conv 7x7x7, pad 3, NCDHW ----------------
// grid: x = tile (0..15) -> x0=(tile&1)*64, y0=(tile>>1)*16 ; y = oc ; z = b*8+zo
template<int IC, bool BIAS_SQ>
__global__ __launch_bounds__(256) void conv3d7_kernel(
    const float* __restrict__ in, const float* __restrict__ wgt,
    const float* __restrict__ bias, float* __restrict__ out)
{
    const int tile = blockIdx.x;
    const int oc   = blockIdx.y;
    const int OC   = gridDim.y;
    const int b    = blockIdx.z >> 3;
    const int zo   = blockIdx.z & 7;
    const int x0 = (tile & 1) * 64;
    const int y0 = (tile >> 1) * 16;

    __shared__ __align__(16) float lds[22 * 72];
    __shared__ __align__(16) float wl[56];

    const int tid  = threadIdx.x;
    const int rowo = tid >> 4;          // 0..15
    const int colo = (tid & 15) << 2;   // 0..60

    float acc0 = 0.f, acc1 = 0.f, acc2 = 0.f, acc3 = 0.f;

    for (int ic = 0; ic < IC; ++ic) {
        for (int dz = 0; dz < 7; ++dz) {
            const int zin = zo + dz - 3;
            if (zin < 0 || zin >= 8) continue;   // z zero-padding (block-uniform)
            __syncthreads();
            if (tid < 49) {
                int r = tid / 7, c = tid - r * 7;
                wl[r * 8 + c] = wgt[((oc * IC + ic) * 7 + dz) * 49 + tid];
            }
            const float* src = in + (((size_t)((b * IC + ic) * 8 + zin)) << 14);
            for (int idx = tid; idx < 22 * 70; idx += 256) {
                int r = idx / 70, c = idx - r * 70;
                int gy = y0 + r - 3, gx = x0 + c - 3;
                float v = 0.f;
                if (gy >= 0 && gy < 128 && gx >= 0 && gx < 128) v = src[(gy << 7) + gx];
                lds[r * 72 + c] = v;
            }
            __syncthreads();
            #pragma unroll
            for (int dy = 0; dy < 7; ++dy) {
                float rr[12], wr[8];
                const float* lp = &lds[(rowo + dy) * 72 + colo];
                #pragma unroll
                for (int i = 0; i < 3; ++i) ((float4*)rr)[i] = ((const float4*)lp)[i];
                #pragma unroll
                for (int i = 0; i < 2; ++i) ((float4*)wr)[i] = ((const float4*)&wl[dy * 8])[i];
                #pragma unroll
                for (int dx = 0; dx < 7; ++dx) {
                    float wv = wr[dx];
                    acc0 += rr[dx] * wv; acc1 += rr[dx + 1] * wv;
                    acc2 += rr[dx + 2] * wv; acc3 += rr[dx + 3] * wv;
                }
            }
        }
    }
    if (BIAS_SQ) {
        float bv = bias[oc];
        acc0 += bv; acc1 += bv; acc2 += bv; acc3 += bv;
        acc0 *= acc0; acc1 *= acc1; acc2 *= acc2; acc3 *= acc3;
    }
    const int oy = y0 + rowo, ox = x0 + colo;
    *(float4*)&out[(((size_t)((b * OC + oc) * 8 + zo)) << 14) + (oy << 7) + ox] =
        make_float4(acc0, acc1, acc2, acc3);
}

// ---------------- 2D conv 15x15, pad 7, 25ch -> 25ch ----------------
// grid: x = tile (0..15), y = oc (0..24), z = b (0..1)
__global__ __launch_bounds__(256) void conv2d15_kernel(
    const float* __restrict__ in, const float* __restrict__ wgt, float* __restrict__ out)
{
    const int tile = blockIdx.x;
    const int oc = blockIdx.y;
    const int b  = blockIdx.z;
    const int x0 = (tile & 1) * 64;
    const int y0 = (tile >> 1) * 16;

    __shared__ __align__(16) float lds[30 * 80];
    __shared__ __align__(16) float wl[15 * 16];

    const int tid  = threadIdx.x;
    const int rowo = tid >> 4;
    const int colo = (tid & 15) << 2;

    float acc0 = 0.f, acc1 = 0.f, acc2 = 0.f, acc3 = 0.f;

    for (int ic = 0; ic < 25; ++ic) {
        __syncthreads();
        if (tid < 225) {
            int r = tid / 15, c = tid - r * 15;
            wl[r * 16 + c] = wgt[(oc * 25 + ic) * 225 + tid];
        }
        const float* src = in + (((size_t)(b * 25 + ic)) << 14);
        for (int idx = tid; idx < 30 * 78; idx += 256) {
            int r = idx / 78, c = idx - r * 78;
            int gy = y0 + r - 7, gx = x0 + c - 7;
            float v = 0.f;
            if (gy >= 0 && gy < 128 && gx >= 0 && gx < 128) v = src[(gy << 7) + gx];
            lds[r * 80 + c] = v;
        }
        __syncthreads();
        #pragma unroll
        for (int dy = 0; dy < 15; ++dy) {
            float rr[20], wr[16];
            const float* lp = &lds[(rowo + dy) * 80 + colo];
            #pragma unroll
            for (int i = 0; i < 5; ++i) ((float4*)rr)[i] = ((const float4*)lp)[i];
            #pragma unroll
            for (int i = 0; i < 4; ++i) ((float4*)wr)[i] = ((const float4*)&wl[dy * 16])[i];
            #pragma unroll
            for (int dx = 0; dx < 15; ++dx) {
                float wv = wr[dx];
                acc0 += rr[dx] * wv; acc1 += rr[dx + 1] * wv;
                acc2 += rr[dx + 2] * wv; acc3 += rr[dx + 3] * wv;
            }
        }
    }
    const int oy = y0 + rowo, ox = x0 + colo;
    *(float4*)&out[(((size_t)(b * 25 + oc)) << 14) + (oy << 7) + ox] =
        make_float4(acc0, acc1, acc2, acc3);
}

// ---------------- 1x1 "gate" conv: sigmoid(W h + b); optionally h*g ----------------
template<bool WRITE_G, bool WRITE_PROD>
__global__ __launch_bounds__(256) void gate_kernel(
    const float* __restrict__ hin, const float* __restrict__ w,
    const float* __restrict__ bias, float* __restrict__ gout, float* __restrict__ prod)
{
    const int p = blockIdx.x * 256 + threadIdx.x;   // < 32768
    const int b = p >> 14, pix = p & (HW - 1);
    const float* hp = hin + (((size_t)b * 25) << 14) + pix;
    float hv[25];
    #pragma unroll
    for (int ic = 0; ic < 25; ++ic) hv[ic] = hp[(size_t)ic << 14];
    #pragma unroll
    for (int oc = 0; oc < 25; ++oc) {
        float acc = bias[oc];
        #pragma unroll
        for (int ic = 0; ic < 25; ++ic) acc += w[oc * 25 + ic] * hv[ic];
        const float g = sig_f(acc);
        const size_t off = (((size_t)(b * 25 + oc)) << 14) + pix;
        if (WRITE_G)    gout[off] = g;
        if (WRITE_PROD) prod[off] = hv[oc] * g;
    }
}

// ---------------- BN batch-stats: per-channel scale/shift ----------------
// one block per channel; x is [2,25,HW]; biased var; scale=g*rsqrt(v+eps), shift=b-m*scale
__global__ __launch_bounds__(1024) void bnstats_kernel(
    const float* __restrict__ x, const float* __restrict__ gw, const float* __restrict__ gb,
    float* __restrict__ scale, float* __restrict__ shift)
{
    const int c = blockIdx.x, tid = threadIdx.x;
    float s1 = 0.f, s2 = 0.f;
    const float4* p0 = (const float4*)(x + ((size_t)c << 14));
    const float4* p1 = (const float4*)(x + ((size_t)(25 + c) << 14));
    for (int i = tid; i < 4096; i += 1024) {
        float4 v = p0[i];
        s1 += v.x + v.y + v.z + v.w;
        s2 += v.x * v.x + v.y * v.y + v.z * v.z + v.w * v.w;
        float4 u = p1[i];
        s1 += u.x + u.y + u.z + u.w;
        s2 += u.x * u.x + u.y * u.y + u.z * u.z + u.w * u.w;
    }
    #pragma unroll
    for (int off = 32; off; off >>= 1) { s1 += __shfl_down(s1, off); s2 += __shfl_down(s2, off); }
    __shared__ float a1[16], a2[16];
    if ((tid & 63) == 0) { a1[tid >> 6] = s1; a2[tid >> 6] = s2; }
    __syncthreads();
    if (tid == 0) {
        float t1 = 0.f, t2 = 0.f;
        #pragma unroll
        for (int i = 0; i < 16; ++i) { t1 += a1[i]; t2 += a2[i]; }
        const float m = t1 * (1.f / 32768.f);
        const float var = fmaxf(t2 * (1.f / 32768.f) - m * m, 0.f);
        const float sc = gw[c] * rsqrtf(var + 1e-3f);
        scale[c] = sc;
        shift[c] = gb[c] - m * sc;
    }
}

// ---------------- ns1 = sp(y_t - sp(bn(c1) * (alpha*h + mu))) ----------------
__global__ __launch_bounds__(256) void ns1_kernel(
    const float* __restrict__ y, const float* __restrict__ h,
    const float* __restrict__ c1, const float* __restrict__ scale,
    const float* __restrict__ shift, const float* __restrict__ alpha,
    const float* __restrict__ mu, float* __restrict__ ns1, int t)
{
    const int idx = blockIdx.x * 256 + threadIdx.x;   // < NELEM
    const int bc = idx >> 14;
    const int c = bc >= 25 ? bc - 25 : bc;
    const int pix = idx & (HW - 1);
    const float yv = y[((size_t)bc << 17) + ((size_t)t << 14) + pix];
    const float c1n = c1[idx] * scale[c] + shift[c];
    const float pre = c1n * (alpha[c] * h[idx] + mu[c]);
    ns1[idx] = sp_f(yv - sp_f(pre));
}

// ---------------- h = sp((1-g2)*h + g2 * sp(kappa*n + gp*c2n + wmix*n*c2n)) ----------------
__global__ __launch_bounds__(256) void hnew_kernel(
    float* __restrict__ h, const float* __restrict__ g2,
    const float* __restrict__ ns1, const float* __restrict__ c2,
    const float* __restrict__ scale, const float* __restrict__ shift,
    const float* __restrict__ kappa, const float* __restrict__ gp,
    const float* __restrict__ wmix)
{
    const int idx = blockIdx.x * 256 + threadIdx.x;
    const int bc = idx >> 14;
    const int c = bc >= 25 ? bc - 25 : bc;
    const float c2n = c2[idx] * scale[c] + shift[c];
    const float n = ns1[idx];
    const float h2 = sp_f(kappa[c] * n + gp[c] * c2n + wmix[c] * n * c2n);
    const float g = g2[idx];
    h[idx] = sp_f((1.f - g) * h[idx] + g * h2);
}

// ---------------- fused bn_out + avgpool2 + fc partial dot ----------------
__global__ __launch_bounds__(256) void fc1_kernel(
    const float* __restrict__ h, const float* __restrict__ scale,
    const float* __restrict__ shift, const float* __restrict__ fcw,
    float2* __restrict__ part)
{
    const int tid = threadIdx.x;
    const int i = blockIdx.x * 256 + tid;   // < 204800, i = ((b*25+c)*64+py)*64+px
    int px = i & 63;
    int t = i >> 6;
    int py = t & 63; t >>= 6;               // t = b*25 + c
    int c = t >= 25 ? t - 25 : t;
    const float* hp = h + ((size_t)t << 14);
    const int y0 = py << 1, xg = px << 1;
    float s = hp[(y0 << 7) + xg] + hp[(y0 << 7) + xg + 1]
            + hp[((y0 + 1) << 7) + xg] + hp[((y0 + 1) << 7) + xg + 1];
    // avg(bn(x)) == bn(avg(x)) since bn is affine per channel
    const float o = 0.25f * s * scale[c] + shift[c];
    float p0 = o * fcw[i];
    float p1 = o * fcw[204800 + i];
    #pragma unroll
    for (int off = 32; off; off >>= 1) { p0 += __shfl_down(p0, off); p1 += __shfl_down(p1, off); }
    __shared__ float a0[4], a1[4];
    if ((tid & 63) == 0) { a0[tid >> 6] = p0; a1[tid >> 6] = p1; }
    __syncthreads();
    if (tid == 0)
        part[blockIdx.x] = make_float2(a0[0] + a0[1] + a0[2] + a0[3],
                                       a1[0] + a1[1] + a1[2] + a1[3]);
}

__global__ __launch_bounds__(256) void fc2_kernel(
    const float2* __restrict__ part, const float* __restrict__ fcb, float* __restrict__ out)
{
    const int tid = threadIdx.x;
    float s0 = 0.f, s1 = 0.f;
    for (int i = tid; i < 800; i += 256) { float2 v = part[i]; s0 += v.x; s1 += v.y; }
    #pragma unroll
    for (int off = 32; off; off >>= 1) { s0 += __shfl_down(s0, off); s1 += __shfl_down(s1, off); }
    __shared__ float a0[4], a1[4];
    if ((tid & 63) == 0) { a0[tid >> 6] = s0; a1[tid >> 6] = s1; }
    __syncthreads();
    if (tid == 0) {
        out[0] = sig_f(a0[0] + a0[1] + a0[2] + a0[3] + fcb[0]);
        out[1] = sig_f(a1[0] + a1[1] + a1[2] + a1[3] + fcb[1]);
    }
}

extern "C" void kernel_launch(void* const* d_in, const int* in_sizes, int n_in,
                              void* d_out, int out_size, void* d_ws, size_t ws_size,
                              hipStream_t stream)
{
    const float* x        = (const float*)d_in[0];
    const float* conv00_w = (const float*)d_in[1];
    const float* conv0_w  = (const float*)d_in[2];
    const float* conv1_w  = (const float*)d_in[3];
    const float* conv1_b  = (const float*)d_in[4];
    const float* u1_w     = (const float*)d_in[5];
    const float* u1_b     = (const float*)d_in[6];
    const float* u2_w     = (const float*)d_in[7];
    const float* u2_b     = (const float*)d_in[8];
    const float* w_inh    = (const float*)d_in[9];
    const float* w_exc    = (const float*)d_in[10];
    const float* alpha    = (const float*)d_in[11];
    const float* mu       = (const float*)d_in[12];
    const float* gamma_p  = (const float*)d_in[13];
    const float* kappa    = (const float*)d_in[14];
    const float* w_mix    = (const float*)d_in[15];
    const float* bn1_w    = (const float*)d_in[16];
    const float* bn1_b    = (const float*)d_in[17];
    const float* bn3_w    = (const float*)d_in[18];
    const float* bn3_b    = (const float*)d_in[19];
    const float* bn_out_w = (const float*)d_in[20];
    const float* bn_out_b = (const float*)d_in[21];
    const float* fc4_w    = (const float*)d_in[22];
    const float* fc4_b    = (const float*)d_in[23];

    float* ws = (float*)d_ws;
    // workspace layout (floats):
    float* Y    = ws;                    // 6,553,600  [2,25,8,128,128]  (conv1 out, squared)
    float* A    = ws + 6553600;          // 6,553,600  conv00 out; then recycled as step buffers
    float* B0   = ws + 13107200;         //   262,144  conv0 out [2,1,8,128,128]
    float* SC1  = ws + 13369344;         // small arrays
    float* SH1  = SC1 + 32;
    float* SC2  = SH1 + 32;
    float* SH2  = SC2 + 32;
    float* PART = SH2 + 32;              // 1600 (800 x float2)

    float* H    = A;                     // step buffers live in A's region (dead after conv0)
    float* HG1  = A + 1 * 819200;
    float* NS1  = A + 2 * 819200;
    float* G2   = A + 3 * 819200;
    float* C1   = A + 4 * 819200;
    float* C2   = A + 5 * 819200;

    // 3D conv front-end
    conv3d7_kernel<3,  false><<<dim3(16, 25, 16), 256, 0, stream>>>(x,  conv00_w, nullptr, A);
    conv3d7_kernel<25, false><<<dim3(16, 1,  16), 256, 0, stream>>>(A,  conv0_w,  nullptr, B0);
    conv3d7_kernel<1,  true ><<<dim3(16, 25, 16), 256, 0, stream>>>(B0, conv1_w,  conv1_b, Y);

    // h0 = 0
    (void)hipMemsetAsync(H, 0, 819200 * sizeof(float), stream);

    // hGRU recurrence, 8 timesteps
    for (int t = 0; t < 8; ++t) {
        gate_kernel<false, true><<<128, 256, 0, stream>>>(H, u1_w, u1_b, nullptr, HG1);
        conv2d15_kernel<<<dim3(16, 25, 2), 256, 0, stream>>>(HG1, w_inh, C1);
        bnstats_kernel<<<25, 1024, 0, stream>>>(C1, bn1_w, bn1_b, SC1, SH1);
        ns1_kernel<<<3200, 256, 0, stream>>>(Y, H, C1, SC1, SH1, alpha, mu, NS1, t);
        gate_kernel<true, false><<<128, 256, 0, stream>>>(NS1, u2_w, u2_b, G2, nullptr);
        conv2d15_kernel<<<dim3(16, 25, 2), 256, 0, stream>>>(NS1, w_exc, C2);
        bnstats_kernel<<<25, 1024, 0, stream>>>(C2, bn3_w, bn3_b, SC2, SH2);
        hnew_kernel<<<3200, 256, 0, stream>>>(H, G2, NS1, C2, SC2, SH2, kappa, gamma_p, w_mix);
    }

    // head: bn_out -> avgpool2 -> fc -> sigmoid
    bnstats_kernel<<<25, 1024, 0, stream>>>(H, bn_out_w, bn_out_b, SC1, SH1);
    fc1_kernel<<<800, 256, 0, stream>>>(H, SC1, SH1, fc4_w, (float2*)PART);
    fc2_kernel<<<1, 256, 0, stream>>>((const float2*)PART, fc4_b, (float*)d_out);
}

// Round 2
// 6399.765 us; speedup vs baseline: 1.3421x; 1.3421x over previous
//
#include <hip/hip_runtime.h>
#include <cstddef>

// Problem constants
#define HW 16384           // 128*128
#define NELEM 819200       // 2*25*HW

__device__ __forceinline__ float sp_f(float x) {
    // jax.nn.softplus == logaddexp(x, 0) == max(x,0) + log1p(exp(-|x|))
    return fmaxf(x, 0.f) + log1pf(expf(-fabsf(x)));
}
__device__ __forceinline__ float sig_f(float x) {
    return 1.f / (1.f + expf(-x));
}

// ---------------- 3D conv 7x7x7, pad 3, NCDHW ----------------
// 128 threads; tile 64 cols x 16 rows; thread = 4 cols x 2 rows, sliding window.
// grid: x = tile (0..15) -> x0=(tile&1)*64, y0=(tile>>1)*16 ; y = oc ; z = b*8+zo
template<int IC, bool BIAS_SQ>
__global__ __launch_bounds__(128) void conv3d7_kernel(
    const float* __restrict__ in, const float* __restrict__ wgt,
    const float* __restrict__ bias, float* __restrict__ out)
{
    const int tile = blockIdx.x;
    const int oc   = blockIdx.y;
    const int OC   = gridDim.y;
    const int b    = blockIdx.z >> 3;
    const int zo   = blockIdx.z & 7;
    const int x0 = (tile & 1) * 64;
    const int y0 = (tile >> 1) * 16;

    __shared__ __align__(16) float lds[22 * 72];   // rows y0-3..y0+18, cols x0-3..x0+66
    __shared__ __align__(16) float wl[7 * 8];

    const int tid  = threadIdx.x;
    const int tx   = tid & 15;          // 16 col-groups of 4
    const int ty   = tid >> 4;          // 0..7, 2 rows each
    const int colo = tx << 2;

    float acc0[4] = {0.f, 0.f, 0.f, 0.f};
    float acc1[4] = {0.f, 0.f, 0.f, 0.f};

    for (int ic = 0; ic < IC; ++ic) {
        for (int dz = 0; dz < 7; ++dz) {
            const int zin = zo + dz - 3;
            if (zin < 0 || zin >= 8) continue;   // block-uniform z padding skip
            __syncthreads();
            if (tid < 49) {
                int r = tid / 7, c = tid - r * 7;
                wl[r * 8 + c] = wgt[((oc * IC + ic) * 7 + dz) * 49 + tid];
            }
            const float* src = in + (((size_t)((b * IC + ic) * 8 + zin)) << 14);
            for (int idx = tid; idx < 22 * 70; idx += 128) {
                int r = idx / 70, c = idx - r * 70;
                int gy = y0 + r - 3, gx = x0 + c - 3;
                float v = 0.f;
                if (gy >= 0 && gy < 128 && gx >= 0 && gx < 128) v = src[(gy << 7) + gx];
                lds[r * 72 + c] = v;
            }
            __syncthreads();

            const float* lrow = &lds[(ty << 1) * 72 + colo];
            float wo[8], wn[8];
            // ir = 0 : feeds acc0 only (dy=0)
            {
                float rr[12];
                #pragma unroll
                for (int i = 0; i < 3; ++i) ((float4*)rr)[i] = ((const float4*)lrow)[i];
                #pragma unroll
                for (int i = 0; i < 2; ++i) ((float4*)wn)[i] = ((const float4*)wl)[i];
                #pragma unroll
                for (int dx = 0; dx < 7; ++dx) {
                    float wv = wn[dx];
                    #pragma unroll
                    for (int k = 0; k < 4; ++k) acc0[k] += rr[dx + k] * wv;
                }
                #pragma unroll
                for (int i = 0; i < 8; ++i) wo[i] = wn[i];
            }
            #pragma unroll
            for (int ir = 1; ir <= 6; ++ir) {
                float rr[12];
                const float* lp = lrow + ir * 72;
                #pragma unroll
                for (int i = 0; i < 3; ++i) ((float4*)rr)[i] = ((const float4*)lp)[i];
                #pragma unroll
                for (int i = 0; i < 2; ++i) ((float4*)wn)[i] = ((const float4*)&wl[ir * 8])[i];
                #pragma unroll
                for (int dx = 0; dx < 7; ++dx) {
                    float w0 = wn[dx], w1 = wo[dx];
                    #pragma unroll
                    for (int k = 0; k < 4; ++k) {
                        acc0[k] += rr[dx + k] * w0;
                        acc1[k] += rr[dx + k] * w1;
                    }
                }
                #pragma unroll
                for (int i = 0; i < 8; ++i) wo[i] = wn[i];
            }
            // ir = 7 : feeds acc1 only (dy=6)
            {
                float rr[12];
                const float* lp = lrow + 7 * 72;
                #pragma unroll
                for (int i = 0; i < 3; ++i) ((float4*)rr)[i] = ((const float4*)lp)[i];
                #pragma unroll
                for (int dx = 0; dx < 7; ++dx) {
                    float wv = wo[dx];
                    #pragma unroll
                    for (int k = 0; k < 4; ++k) acc1[k] += rr[dx + k] * wv;
                }
            }
        }
    }
    if (BIAS_SQ) {
        float bv = bias[oc];
        #pragma unroll
        for (int k = 0; k < 4; ++k) {
            acc0[k] += bv; acc0[k] *= acc0[k];
            acc1[k] += bv; acc1[k] *= acc1[k];
        }
    }
    const int oy = y0 + (ty << 1), ox = x0 + colo;
    float* op = out + (((size_t)((b * OC + oc) * 8 + zo)) << 14) + (oy << 7) + ox;
    *(float4*)op         = make_float4(acc0[0], acc0[1], acc0[2], acc0[3]);
    *(float4*)(op + 128) = make_float4(acc1[0], acc1[1], acc1[2], acc1[3]);
}

// ---------------- 2D conv 15x15, pad 7, 25ch -> 25ch ----------------
// 128 threads; tile 64 cols x 16 rows; thread = 4 cols x 2 rows, sliding window.
// grid: x = tile (0..15), y = oc (0..24), z = b (0..1)
__global__ __launch_bounds__(128) void conv2d15_kernel(
    const float* __restrict__ in, const float* __restrict__ wgt, float* __restrict__ out)
{
    const int tile = blockIdx.x;
    const int oc = blockIdx.y;
    const int b  = blockIdx.z;
    const int x0 = (tile & 1) * 64;
    const int y0 = (tile >> 1) * 16;

    __shared__ __align__(16) float lds[30 * 80];   // rows y0-7..y0+22, cols x0-7..x0+70
    __shared__ __align__(16) float wl[15 * 16];

    const int tid  = threadIdx.x;
    const int tx   = tid & 15;
    const int ty   = tid >> 4;          // 0..7
    const int colo = tx << 2;

    float acc0[4] = {0.f, 0.f, 0.f, 0.f};
    float acc1[4] = {0.f, 0.f, 0.f, 0.f};

    for (int ic = 0; ic < 25; ++ic) {
        __syncthreads();
        for (int i = tid; i < 225; i += 128) {
            int r = i / 15, c = i - r * 15;
            wl[r * 16 + c] = wgt[(oc * 25 + ic) * 225 + i];
        }
        const float* src = in + (((size_t)(b * 25 + ic)) << 14);
        for (int idx = tid; idx < 30 * 78; idx += 128) {
            int r = idx / 78, c = idx - r * 78;
            int gy = y0 + r - 7, gx = x0 + c - 7;
            float v = 0.f;
            if (gy >= 0 && gy < 128 && gx >= 0 && gx < 128) v = src[(gy << 7) + gx];
            lds[r * 80 + c] = v;
        }
        __syncthreads();

        const float* lrow = &lds[(ty << 1) * 80 + colo];
        float wo[16], wn[16];
        // ir = 0 : acc0 only (dy=0)
        {
            float rr[20];
            #pragma unroll
            for (int i = 0; i < 5; ++i) ((float4*)rr)[i] = ((const float4*)lrow)[i];
            #pragma unroll
            for (int i = 0; i < 4; ++i) ((float4*)wn)[i] = ((const float4*)wl)[i];
            #pragma unroll
            for (int dx = 0; dx < 15; ++dx) {
                float wv = wn[dx];
                #pragma unroll
                for (int k = 0; k < 4; ++k) acc0[k] += rr[dx + k] * wv;
            }
            #pragma unroll
            for (int i = 0; i < 16; ++i) wo[i] = wn[i];
        }
        #pragma unroll
        for (int ir = 1; ir <= 14; ++ir) {
            float rr[20];
            const float* lp = lrow + ir * 80;
            #pragma unroll
            for (int i = 0; i < 5; ++i) ((float4*)rr)[i] = ((const float4*)lp)[i];
            #pragma unroll
            for (int i = 0; i < 4; ++i) ((float4*)wn)[i] = ((const float4*)&wl[ir * 16])[i];
            #pragma unroll
            for (int dx = 0; dx < 15; ++dx) {
                float w0 = wn[dx], w1 = wo[dx];
                #pragma unroll
                for (int k = 0; k < 4; ++k) {
                    acc0[k] += rr[dx + k] * w0;
                    acc1[k] += rr[dx + k] * w1;
                }
            }
            #pragma unroll
            for (int i = 0; i < 16; ++i) wo[i] = wn[i];
        }
        // ir = 15 : acc1 only (dy=14)
        {
            float rr[20];
            const float* lp = lrow + 15 * 80;
            #pragma unroll
            for (int i = 0; i < 5; ++i) ((float4*)rr)[i] = ((const float4*)lp)[i];
            #pragma unroll
            for (int dx = 0; dx < 15; ++dx) {
                float wv = wo[dx];
                #pragma unroll
                for (int k = 0; k < 4; ++k) acc1[k] += rr[dx + k] * wv;
            }
        }
    }
    const int oy = y0 + (ty << 1), ox = x0 + colo;
    float* op = out + (((size_t)(b * 25 + oc)) << 14) + (oy << 7) + ox;
    *(float4*)op         = make_float4(acc0[0], acc0[1], acc0[2], acc0[3]);
    *(float4*)(op + 128) = make_float4(acc1[0], acc1[1], acc1[2], acc1[3]);
}

// ---------------- 1x1 "gate" conv: sigmoid(W h + b); optionally h*g ----------------
template<bool WRITE_G, bool WRITE_PROD>
__global__ __launch_bounds__(256) void gate_kernel(
    const float* __restrict__ hin, const float* __restrict__ w,
    const float* __restrict__ bias, float* __restrict__ gout, float* __restrict__ prod)
{
    const int p = blockIdx.x * 256 + threadIdx.x;   // < 32768
    const int b = p >> 14, pix = p & (HW - 1);
    const float* hp = hin + (((size_t)b * 25) << 14) + pix;
    float hv[25];
    #pragma unroll
    for (int ic = 0; ic < 25; ++ic) hv[ic] = hp[(size_t)ic << 14];
    #pragma unroll
    for (int oc = 0; oc < 25; ++oc) {
        float acc = bias[oc];
        #pragma unroll
        for (int ic = 0; ic < 25; ++ic) acc += w[oc * 25 + ic] * hv[ic];
        const float g = sig_f(acc);
        const size_t off = (((size_t)(b * 25 + oc)) << 14) + pix;
        if (WRITE_G)    gout[off] = g;
        if (WRITE_PROD) prod[off] = hv[oc] * g;
    }
}

// ---------------- BN batch-stats: per-channel scale/shift ----------------
__global__ __launch_bounds__(1024) void bnstats_kernel(
    const float* __restrict__ x, const float* __restrict__ gw, const float* __restrict__ gb,
    float* __restrict__ scale, float* __restrict__ shift)
{
    const int c = blockIdx.x, tid = threadIdx.x;
    float s1 = 0.f, s2 = 0.f;
    const float4* p0 = (const float4*)(x + ((size_t)c << 14));
    const float4* p1 = (const float4*)(x + ((size_t)(25 + c) << 14));
    for (int i = tid; i < 4096; i += 1024) {
        float4 v = p0[i];
        s1 += v.x + v.y + v.z + v.w;
        s2 += v.x * v.x + v.y * v.y + v.z * v.z + v.w * v.w;
        float4 u = p1[i];
        s1 += u.x + u.y + u.z + u.w;
        s2 += u.x * u.x + u.y * u.y + u.z * u.z + u.w * u.w;
    }
    #pragma unroll
    for (int off = 32; off; off >>= 1) { s1 += __shfl_down(s1, off); s2 += __shfl_down(s2, off); }
    __shared__ float a1[16], a2[16];
    if ((tid & 63) == 0) { a1[tid >> 6] = s1; a2[tid >> 6] = s2; }
    __syncthreads();
    if (tid == 0) {
        float t1 = 0.f, t2 = 0.f;
        #pragma unroll
        for (int i = 0; i < 16; ++i) { t1 += a1[i]; t2 += a2[i]; }
        const float m = t1 * (1.f / 32768.f);
        const float var = fmaxf(t2 * (1.f / 32768.f) - m * m, 0.f);
        const float sc = gw[c] * rsqrtf(var + 1e-3f);
        scale[c] = sc;
        shift[c] = gb[c] - m * sc;
    }
}

// ---------------- ns1 = sp(y_t - sp(bn(c1) * (alpha*h + mu))) ----------------
__global__ __launch_bounds__(256) void ns1_kernel(
    const float* __restrict__ y, const float* __restrict__ h,
    const float* __restrict__ c1, const float* __restrict__ scale,
    const float* __restrict__ shift, const float* __restrict__ alpha,
    const float* __restrict__ mu, float* __restrict__ ns1, int t)
{
    const int idx = blockIdx.x * 256 + threadIdx.x;   // < NELEM
    const int bc = idx >> 14;
    const int c = bc >= 25 ? bc - 25 : bc;
    const int pix = idx & (HW - 1);
    const float yv = y[((size_t)bc << 17) + ((size_t)t << 14) + pix];
    const float c1n = c1[idx] * scale[c] + shift[c];
    const float pre = c1n * (alpha[c] * h[idx] + mu[c]);
    ns1[idx] = sp_f(yv - sp_f(pre));
}

// ---------------- h = sp((1-g2)*h + g2 * sp(kappa*n + gp*c2n + wmix*n*c2n)) ----------------
__global__ __launch_bounds__(256) void hnew_kernel(
    float* __restrict__ h, const float* __restrict__ g2,
    const float* __restrict__ ns1, const float* __restrict__ c2,
    const float* __restrict__ scale, const float* __restrict__ shift,
    const float* __restrict__ kappa, const float* __restrict__ gp,
    const float* __restrict__ wmix)
{
    const int idx = blockIdx.x * 256 + threadIdx.x;
    const int bc = idx >> 14;
    const int c = bc >= 25 ? bc - 25 : bc;
    const float c2n = c2[idx] * scale[c] + shift[c];
    const float n = ns1[idx];
    const float h2 = sp_f(kappa[c] * n + gp[c] * c2n + wmix[c] * n * c2n);
    const float g = g2[idx];
    h[idx] = sp_f((1.f - g) * h[idx] + g * h2);
}

// ---------------- fused bn_out + avgpool2 + fc partial dot ----------------
__global__ __launch_bounds__(256) void fc1_kernel(
    const float* __restrict__ h, const float* __restrict__ scale,
    const float* __restrict__ shift, const float* __restrict__ fcw,
    float2* __restrict__ part)
{
    const int tid = threadIdx.x;
    const int i = blockIdx.x * 256 + tid;   // < 204800, i = ((b*25+c)*64+py)*64+px
    int px = i & 63;
    int t = i >> 6;
    int py = t & 63; t >>= 6;               // t = b*25 + c
    int c = t >= 25 ? t - 25 : t;
    const float* hp = h + ((size_t)t << 14);
    const int y0 = py << 1, xg = px << 1;
    float s = hp[(y0 << 7) + xg] + hp[(y0 << 7) + xg + 1]
            + hp[((y0 + 1) << 7) + xg] + hp[((y0 + 1) << 7) + xg + 1];
    const float o = 0.25f * s * scale[c] + shift[c];
    float p0 = o * fcw[i];
    float p1 = o * fcw[204800 + i];
    #pragma unroll
    for (int off = 32; off; off >>= 1) { p0 += __shfl_down(p0, off); p1 += __shfl_down(p1, off); }
    __shared__ float a0[4], a1[4];
    if ((tid & 63) == 0) { a0[tid >> 6] = p0; a1[tid >> 6] = p1; }
    __syncthreads();
    if (tid == 0)
        part[blockIdx.x] = make_float2(a0[0] + a0[1] + a0[2] + a0[3],
                                       a1[0] + a1[1] + a1[2] + a1[3]);
}

__global__ __launch_bounds__(256) void fc2_kernel(
    const float2* __restrict__ part, const float* __restrict__ fcb, float* __restrict__ out)
{
    const int tid = threadIdx.x;
    float s0 = 0.f, s1 = 0.f;
    for (int i = tid; i < 800; i += 256) { float2 v = part[i]; s0 += v.x; s1 += v.y; }
    #pragma unroll
    for (int off = 32; off; off >>= 1) { s0 += __shfl_down(s0, off); s1 += __shfl_down(s1, off); }
    __shared__ float a0[4], a1[4];
    if ((tid & 63) == 0) { a0[tid >> 6] = s0; a1[tid >> 6] = s1; }
    __syncthreads();
    if (tid == 0) {
        out[0] = sig_f(a0[0] + a0[1] + a0[2] + a0[3] + fcb[0]);
        out[1] = sig_f(a1[0] + a1[1] + a1[2] + a1[3] + fcb[1]);
    }
}

extern "C" void kernel_launch(void* const* d_in, const int* in_sizes, int n_in,
                              void* d_out, int out_size, void* d_ws, size_t ws_size,
                              hipStream_t stream)
{
    const float* x        = (const float*)d_in[0];
    const float* conv00_w = (const float*)d_in[1];
    const float* conv0_w  = (const float*)d_in[2];
    const float* conv1_w  = (const float*)d_in[3];
    const float* conv1_b  = (const float*)d_in[4];
    const float* u1_w     = (const float*)d_in[5];
    const float* u1_b     = (const float*)d_in[6];
    const float* u2_w     = (const float*)d_in[7];
    const float* u2_b     = (const float*)d_in[8];
    const float* w_inh    = (const float*)d_in[9];
    const float* w_exc    = (const float*)d_in[10];
    const float* alpha    = (const float*)d_in[11];
    const float* mu       = (const float*)d_in[12];
    const float* gamma_p  = (const float*)d_in[13];
    const float* kappa    = (const float*)d_in[14];
    const float* w_mix    = (const float*)d_in[15];
    const float* bn1_w    = (const float*)d_in[16];
    const float* bn1_b    = (const float*)d_in[17];
    const float* bn3_w    = (const float*)d_in[18];
    const float* bn3_b    = (const float*)d_in[19];
    const float* bn_out_w = (const float*)d_in[20];
    const float* bn_out_b = (const float*)d_in[21];
    const float* fc4_w    = (const float*)d_in[22];
    const float* fc4_b    = (const float*)d_in[23];

    float* ws = (float*)d_ws;
    float* Y    = ws;                    // 6,553,600  [2,25,8,128,128]
    float* A    = ws + 6553600;          // 6,553,600  conv00 out; recycled as step buffers
    float* B0   = ws + 13107200;         //   262,144  conv0 out [2,1,8,128,128]
    float* SC1  = ws + 13369344;
    float* SH1  = SC1 + 32;
    float* SC2  = SH1 + 32;
    float* SH2  = SC2 + 32;
    float* PART = SH2 + 32;              // 1600 (800 x float2)

    float* H    = A;
    float* HG1  = A + 1 * 819200;
    float* NS1  = A + 2 * 819200;
    float* G2   = A + 3 * 819200;
    float* C1   = A + 4 * 819200;
    float* C2   = A + 5 * 819200;

    // 3D conv front-end
    conv3d7_kernel<3,  false><<<dim3(16, 25, 16), 128, 0, stream>>>(x,  conv00_w, nullptr, A);
    conv3d7_kernel<25, false><<<dim3(16, 1,  16), 128, 0, stream>>>(A,  conv0_w,  nullptr, B0);
    conv3d7_kernel<1,  true ><<<dim3(16, 25, 16), 128, 0, stream>>>(B0, conv1_w,  conv1_b, Y);

    (void)hipMemsetAsync(H, 0, 819200 * sizeof(float), stream);

    for (int t = 0; t < 8; ++t) {
        gate_kernel<false, true><<<128, 256, 0, stream>>>(H, u1_w, u1_b, nullptr, HG1);
        conv2d15_kernel<<<dim3(16, 25, 2), 128, 0, stream>>>(HG1, w_inh, C1);
        bnstats_kernel<<<25, 1024, 0, stream>>>(C1, bn1_w, bn1_b, SC1, SH1);
        ns1_kernel<<<3200, 256, 0, stream>>>(Y, H, C1, SC1, SH1, alpha, mu, NS1, t);
        gate_kernel<true, false><<<128, 256, 0, stream>>>(NS1, u2_w, u2_b, G2, nullptr);
        conv2d15_kernel<<<dim3(16, 25, 2), 128, 0, stream>>>(NS1, w_exc, C2);
        bnstats_kernel<<<25, 1024, 0, stream>>>(C2, bn3_w, bn3_b, SC2, SH2);
        hnew_kernel<<<3200, 256, 0, stream>>>(H, G2, NS1, C2, SC2, SH2, kappa, gamma_p, w_mix);
    }

    bnstats_kernel<<<25, 1024, 0, stream>>>(H, bn_out_w, bn_out_b, SC1, SH1);
    fc1_kernel<<<800, 256, 0, stream>>>(H, SC1, SH1, fc4_w, (float2*)PART);
    fc2_kernel<<<1, 256, 0, stream>>>((const float2*)PART, fc4_b, (float*)d_out);
}

// Round 3
// 4222.563 us; speedup vs baseline: 2.0341x; 1.5156x over previous
//
#include <hip/hip_runtime.h>
#include <cstddef>

#define HW 16384           // 128*128
#define NELEM 819200       // 2*25*HW

__device__ __forceinline__ float sp_f(float x) {
    return fmaxf(x, 0.f) + log1pf(expf(-fabsf(x)));
}
__device__ __forceinline__ float sig_f(float x) {
    return 1.f / (1.f + expf(-x));
}

// ---------------- 3D conv 7x7x7, pad 3, NCDHW ----------------
// 128 threads; tile 128 cols x 16 rows; thread = 8 cols x 2 rows (sliding window).
// Weights via block-uniform (scalar) global loads. Optional ic-group split (NICG)
// writing partials, and optional NSUM-way partial-sum on input staging.
// grid: x = ytile (0..7); y = oc*NICG+icg; z = b*8+zo
template<int ICTOT, int ICG, int NICG, int OC, int NSUM, bool BIAS_SQ>
__global__ __launch_bounds__(128) void conv3d7_kernel(
    const float* __restrict__ in, const float* __restrict__ wgt,
    const float* __restrict__ bias, float* __restrict__ out)
{
    const int y0  = blockIdx.x * 16;
    const int by  = blockIdx.y;
    const int oc  = by / NICG;
    const int icg = by % NICG;
    const int b   = blockIdx.z >> 3;
    const int zo  = blockIdx.z & 7;

    __shared__ __align__(16) float lds[22 * 136];   // rows y0-3..y0+18, cols -3..130

    const int tid = threadIdx.x;
    const int tx  = tid & 15;          // 8 cols each
    const int ty  = tid >> 4;          // 0..7, 2 rows each

    float acc0[8] = {0,0,0,0,0,0,0,0};
    float acc1[8] = {0,0,0,0,0,0,0,0};

    for (int ic = icg * ICG; ic < icg * ICG + ICG; ++ic) {
        for (int dz = 0; dz < 7; ++dz) {
            const int zin = zo + dz - 3;
            if (zin < 0 || zin >= 8) continue;       // block-uniform skip
            __syncthreads();
            const float* src = in + (((size_t)((b * ICTOT + ic) * 8 + zin)) << 14);
            for (int idx = tid; idx < 22 * 134; idx += 128) {
                int r = idx / 134, c = idx - r * 134;
                int gy = y0 + r - 3, gx = c - 3;
                float v = 0.f;
                if ((unsigned)gy < 128u && (unsigned)gx < 128u) {
                    if (NSUM == 1) v = src[(gy << 7) + gx];
                    else {
                        #pragma unroll
                        for (int g = 0; g < NSUM; ++g) v += src[(size_t)g * 262144 + (gy << 7) + gx];
                    }
                }
                lds[r * 136 + c] = v;
            }
            __syncthreads();

            const float* wbase = wgt + ((size_t)(oc * ICTOT + ic) * 7 + dz) * 49;
            const float* lrow  = &lds[(ty << 1) * 136 + (tx << 3)];
            float wn[7], wo[7];
            {   // j = 0 : acc0 only (dy=0)
                float rr[16];
                #pragma unroll
                for (int i = 0; i < 4; ++i) ((float4*)rr)[i] = ((const float4*)lrow)[i];
                #pragma unroll
                for (int d = 0; d < 7; ++d) wn[d] = wbase[d];
                #pragma unroll
                for (int dx = 0; dx < 7; ++dx) {
                    float wv = wn[dx];
                    #pragma unroll
                    for (int k = 0; k < 8; ++k) acc0[k] += rr[dx + k] * wv;
                }
                #pragma unroll
                for (int d = 0; d < 7; ++d) wo[d] = wn[d];
            }
            #pragma unroll
            for (int j = 1; j <= 6; ++j) {
                float rr[16];
                const float* lp = lrow + j * 136;
                #pragma unroll
                for (int i = 0; i < 4; ++i) ((float4*)rr)[i] = ((const float4*)lp)[i];
                #pragma unroll
                for (int d = 0; d < 7; ++d) wn[d] = wbase[j * 7 + d];
                #pragma unroll
                for (int dx = 0; dx < 7; ++dx) {
                    float w0 = wn[dx], w1 = wo[dx];
                    #pragma unroll
                    for (int k = 0; k < 8; ++k) {
                        acc0[k] += rr[dx + k] * w0;
                        acc1[k] += rr[dx + k] * w1;
                    }
                }
                #pragma unroll
                for (int d = 0; d < 7; ++d) wo[d] = wn[d];
            }
            {   // j = 7 : acc1 only (dy=6)
                float rr[16];
                const float* lp = lrow + 7 * 136;
                #pragma unroll
                for (int i = 0; i < 4; ++i) ((float4*)rr)[i] = ((const float4*)lp)[i];
                #pragma unroll
                for (int dx = 0; dx < 7; ++dx) {
                    float wv = wo[dx];
                    #pragma unroll
                    for (int k = 0; k < 8; ++k) acc1[k] += rr[dx + k] * wv;
                }
            }
        }
    }
    if (BIAS_SQ) {
        float bv = bias[oc];
        #pragma unroll
        for (int k = 0; k < 8; ++k) {
            acc0[k] += bv; acc0[k] *= acc0[k];
            acc1[k] += bv; acc1[k] *= acc1[k];
        }
    }
    const int oy = y0 + (ty << 1), ox = tx << 3;
    float* op = out + (size_t)icg * (2 * OC * 8 * HW)
              + (((size_t)((b * OC + oc) * 8 + zo)) << 14) + (oy << 7) + ox;
    *(float4*)op         = make_float4(acc0[0], acc0[1], acc0[2], acc0[3]);
    *(float4*)(op + 4)   = make_float4(acc0[4], acc0[5], acc0[6], acc0[7]);
    *(float4*)(op + 128) = make_float4(acc1[0], acc1[1], acc1[2], acc1[3]);
    *(float4*)(op + 132) = make_float4(acc1[4], acc1[5], acc1[6], acc1[7]);
}

// ---------------- 2D conv 15x15, pad 7, 25ch -> 25ch, split-K over ic ----------------
// 128 threads; tile 128 cols x 16 rows; thread = 8 cols x 2 rows (sliding window).
// Weights via scalar loads; register-prefetch of next ic tile overlaps compute.
// grid: x = ytile (0..7), y = oc (0..24), z = b*2 + kg; kg0: ic[0,13), kg1: ic[13,25)
// writes partial to out + kg*NELEM.
__global__ __launch_bounds__(128) void conv2d15_kernel(
    const float* __restrict__ in, const float* __restrict__ wgt, float* __restrict__ out)
{
    const int y0 = blockIdx.x * 16;
    const int oc = blockIdx.y;
    const int b  = blockIdx.z >> 1;
    const int kg = blockIdx.z & 1;
    const int ic0 = kg ? 13 : 0;
    const int ic1 = kg ? 25 : 13;

    __shared__ __align__(16) float lds[30 * 144];   // rows y0-7..y0+22, cols -7..134

    const int tid = threadIdx.x;
    const int tx  = tid & 15;          // 8 cols each
    const int ty  = tid >> 4;          // 0..7, 2 rows each

    float acc0[8] = {0,0,0,0,0,0,0,0};
    float acc1[8] = {0,0,0,0,0,0,0,0};
    float st[34];

    // prefetch first tile
    {
        const float* src = in + (((size_t)(b * 25 + ic0)) << 14);
        #pragma unroll
        for (int i = 0; i < 34; ++i) {
            int idx = i * 128 + tid;
            int r = idx / 142, c = idx - r * 142;
            int gy = y0 + r - 7, gx = c - 7;
            float v = 0.f;
            if (idx < 4260 && (unsigned)gy < 128u && (unsigned)gx < 128u)
                v = src[(gy << 7) + gx];
            st[i] = v;
        }
    }

    for (int ic = ic0; ic < ic1; ++ic) {
        __syncthreads();
        #pragma unroll
        for (int i = 0; i < 34; ++i) {
            int idx = i * 128 + tid;
            if (idx < 4260) {
                int r = idx / 142, c = idx - r * 142;
                lds[r * 144 + c] = st[i];
            }
        }
        __syncthreads();
        if (ic + 1 < ic1) {   // issue next tile's global loads; waited on at next stage
            const float* src = in + (((size_t)(b * 25 + ic + 1)) << 14);
            #pragma unroll
            for (int i = 0; i < 34; ++i) {
                int idx = i * 128 + tid;
                int r = idx / 142, c = idx - r * 142;
                int gy = y0 + r - 7, gx = c - 7;
                float v = 0.f;
                if (idx < 4260 && (unsigned)gy < 128u && (unsigned)gx < 128u)
                    v = src[(gy << 7) + gx];
                st[i] = v;
            }
        }

        const float* wbase = wgt + (size_t)(oc * 25 + ic) * 225;
        const float* lrow  = &lds[(ty << 1) * 144 + (tx << 3)];
        float wn[15], wo[15];
        {   // j = 0 : acc0 only
            float rr[24];
            #pragma unroll
            for (int i = 0; i < 6; ++i) ((float4*)rr)[i] = ((const float4*)lrow)[i];
            #pragma unroll
            for (int d = 0; d < 15; ++d) wn[d] = wbase[d];
            #pragma unroll
            for (int dx = 0; dx < 15; ++dx) {
                float wv = wn[dx];
                #pragma unroll
                for (int k = 0; k < 8; ++k) acc0[k] += rr[dx + k] * wv;
            }
            #pragma unroll
            for (int d = 0; d < 15; ++d) wo[d] = wn[d];
        }
        for (int j = 1; j <= 14; ++j) {
            float rr[24];
            const float* lp = lrow + j * 144;
            #pragma unroll
            for (int i = 0; i < 6; ++i) ((float4*)rr)[i] = ((const float4*)lp)[i];
            #pragma unroll
            for (int d = 0; d < 15; ++d) wn[d] = wbase[j * 15 + d];
            #pragma unroll
            for (int dx = 0; dx < 15; ++dx) {
                float w0 = wn[dx], w1 = wo[dx];
                #pragma unroll
                for (int k = 0; k < 8; ++k) {
                    acc0[k] += rr[dx + k] * w0;
                    acc1[k] += rr[dx + k] * w1;
                }
            }
            #pragma unroll
            for (int d = 0; d < 15; ++d) wo[d] = wn[d];
        }
        {   // j = 15 : acc1 only
            float rr[24];
            const float* lp = lrow + 15 * 144;
            #pragma unroll
            for (int i = 0; i < 6; ++i) ((float4*)rr)[i] = ((const float4*)lp)[i];
            #pragma unroll
            for (int dx = 0; dx < 15; ++dx) {
                float wv = wo[dx];
                #pragma unroll
                for (int k = 0; k < 8; ++k) acc1[k] += rr[dx + k] * wv;
            }
        }
    }
    const int oy = y0 + (ty << 1), ox = tx << 3;
    float* op = out + (size_t)kg * NELEM
              + (((size_t)(b * 25 + oc)) << 14) + (oy << 7) + ox;
    *(float4*)op         = make_float4(acc0[0], acc0[1], acc0[2], acc0[3]);
    *(float4*)(op + 4)   = make_float4(acc0[4], acc0[5], acc0[6], acc0[7]);
    *(float4*)(op + 128) = make_float4(acc1[0], acc1[1], acc1[2], acc1[3]);
    *(float4*)(op + 132) = make_float4(acc1[4], acc1[5], acc1[6], acc1[7]);
}

// ---------------- 1x1 "gate" conv: sigmoid(W h + b); optionally h*g ----------------
template<bool WRITE_G, bool WRITE_PROD>
__global__ __launch_bounds__(256) void gate_kernel(
    const float* __restrict__ hin, const float* __restrict__ w,
    const float* __restrict__ bias, float* __restrict__ gout, float* __restrict__ prod)
{
    const int p = blockIdx.x * 256 + threadIdx.x;   // < 32768
    const int b = p >> 14, pix = p & (HW - 1);
    const float* hp = hin + (((size_t)b * 25) << 14) + pix;
    float hv[25];
    #pragma unroll
    for (int ic = 0; ic < 25; ++ic) hv[ic] = hp[(size_t)ic << 14];
    #pragma unroll
    for (int oc = 0; oc < 25; ++oc) {
        float acc = bias[oc];
        #pragma unroll
        for (int ic = 0; ic < 25; ++ic) acc += w[oc * 25 + ic] * hv[ic];
        const float g = sig_f(acc);
        const size_t off = (((size_t)(b * 25 + oc)) << 14) + pix;
        if (WRITE_G)    gout[off] = g;
        if (WRITE_PROD) prod[off] = hv[oc] * g;
    }
}

// ---------------- BN batch-stats (optionally summing split-K partial pair) ----------------
template<bool PAIR>
__global__ __launch_bounds__(1024) void bnstats_kernel(
    const float* __restrict__ x, const float* __restrict__ gw, const float* __restrict__ gb,
    float* __restrict__ scale, float* __restrict__ shift)
{
    const int c = blockIdx.x, tid = threadIdx.x;
    float s1 = 0.f, s2 = 0.f;
    const float4* p0 = (const float4*)(x + ((size_t)c << 14));
    const float4* p1 = (const float4*)(x + ((size_t)(25 + c) << 14));
    const float4* q0 = (const float4*)(x + NELEM + ((size_t)c << 14));
    const float4* q1 = (const float4*)(x + NELEM + ((size_t)(25 + c) << 14));
    for (int i = tid; i < 4096; i += 1024) {
        float4 v = p0[i];
        if (PAIR) { float4 w = q0[i]; v.x += w.x; v.y += w.y; v.z += w.z; v.w += w.w; }
        s1 += v.x + v.y + v.z + v.w;
        s2 += v.x * v.x + v.y * v.y + v.z * v.z + v.w * v.w;
        float4 u = p1[i];
        if (PAIR) { float4 w = q1[i]; u.x += w.x; u.y += w.y; u.z += w.z; u.w += w.w; }
        s1 += u.x + u.y + u.z + u.w;
        s2 += u.x * u.x + u.y * u.y + u.z * u.z + u.w * u.w;
    }
    #pragma unroll
    for (int off = 32; off; off >>= 1) { s1 += __shfl_down(s1, off); s2 += __shfl_down(s2, off); }
    __shared__ float a1[16], a2[16];
    if ((tid & 63) == 0) { a1[tid >> 6] = s1; a2[tid >> 6] = s2; }
    __syncthreads();
    if (tid == 0) {
        float t1 = 0.f, t2 = 0.f;
        #pragma unroll
        for (int i = 0; i < 16; ++i) { t1 += a1[i]; t2 += a2[i]; }
        const float m = t1 * (1.f / 32768.f);
        const float var = fmaxf(t2 * (1.f / 32768.f) - m * m, 0.f);
        const float sc = gw[c] * rsqrtf(var + 1e-3f);
        scale[c] = sc;
        shift[c] = gb[c] - m * sc;
    }
}

// ---------------- ns1 = sp(y_t - sp(bn(c1a+c1b) * (alpha*h + mu))) ----------------
__global__ __launch_bounds__(256) void ns1_kernel(
    const float* __restrict__ y, const float* __restrict__ h,
    const float* __restrict__ c1, const float* __restrict__ scale,
    const float* __restrict__ shift, const float* __restrict__ alpha,
    const float* __restrict__ mu, float* __restrict__ ns1, int t)
{
    const int idx = blockIdx.x * 256 + threadIdx.x;   // < NELEM
    const int bc = idx >> 14;
    const int c = bc >= 25 ? bc - 25 : bc;
    const int pix = idx & (HW - 1);
    const float yv = y[((size_t)bc << 17) + ((size_t)t << 14) + pix];
    const float c1v = c1[idx] + c1[NELEM + idx];
    const float c1n = c1v * scale[c] + shift[c];
    const float pre = c1n * (alpha[c] * h[idx] + mu[c]);
    ns1[idx] = sp_f(yv - sp_f(pre));
}

// ---------------- h = sp((1-g2)*h + g2 * sp(kappa*n + gp*c2n + wmix*n*c2n)) ----------------
__global__ __launch_bounds__(256) void hnew_kernel(
    float* __restrict__ h, const float* __restrict__ g2,
    const float* __restrict__ ns1, const float* __restrict__ c2,
    const float* __restrict__ scale, const float* __restrict__ shift,
    const float* __restrict__ kappa, const float* __restrict__ gp,
    const float* __restrict__ wmix)
{
    const int idx = blockIdx.x * 256 + threadIdx.x;
    const int bc = idx >> 14;
    const int c = bc >= 25 ? bc - 25 : bc;
    const float c2v = c2[idx] + c2[NELEM + idx];
    const float c2n = c2v * scale[c] + shift[c];
    const float n = ns1[idx];
    const float h2 = sp_f(kappa[c] * n + gp[c] * c2n + wmix[c] * n * c2n);
    const float g = g2[idx];
    h[idx] = sp_f((1.f - g) * h[idx] + g * h2);
}

// ---------------- fused bn_out + avgpool2 + fc partial dot ----------------
__global__ __launch_bounds__(256) void fc1_kernel(
    const float* __restrict__ h, const float* __restrict__ scale,
    const float* __restrict__ shift, const float* __restrict__ fcw,
    float2* __restrict__ part)
{
    const int tid = threadIdx.x;
    const int i = blockIdx.x * 256 + tid;   // < 204800
    int px = i & 63;
    int t = i >> 6;
    int py = t & 63; t >>= 6;               // t = b*25 + c
    int c = t >= 25 ? t - 25 : t;
    const float* hp = h + ((size_t)t << 14);
    const int y0 = py << 1, xg = px << 1;
    float s = hp[(y0 << 7) + xg] + hp[(y0 << 7) + xg + 1]
            + hp[((y0 + 1) << 7) + xg] + hp[((y0 + 1) << 7) + xg + 1];
    const float o = 0.25f * s * scale[c] + shift[c];
    float p0 = o * fcw[i];
    float p1 = o * fcw[204800 + i];
    #pragma unroll
    for (int off = 32; off; off >>= 1) { p0 += __shfl_down(p0, off); p1 += __shfl_down(p1, off); }
    __shared__ float a0[4], a1[4];
    if ((tid & 63) == 0) { a0[tid >> 6] = p0; a1[tid >> 6] = p1; }
    __syncthreads();
    if (tid == 0)
        part[blockIdx.x] = make_float2(a0[0] + a0[1] + a0[2] + a0[3],
                                       a1[0] + a1[1] + a1[2] + a1[3]);
}

__global__ __launch_bounds__(256) void fc2_kernel(
    const float2* __restrict__ part, const float* __restrict__ fcb, float* __restrict__ out)
{
    const int tid = threadIdx.x;
    float s0 = 0.f, s1 = 0.f;
    for (int i = tid; i < 800; i += 256) { float2 v = part[i]; s0 += v.x; s1 += v.y; }
    #pragma unroll
    for (int off = 32; off; off >>= 1) { s0 += __shfl_down(s0, off); s1 += __shfl_down(s1, off); }
    __shared__ float a0[4], a1[4];
    if ((tid & 63) == 0) { a0[tid >> 6] = s0; a1[tid >> 6] = s1; }
    __syncthreads();
    if (tid == 0) {
        out[0] = sig_f(a0[0] + a0[1] + a0[2] + a0[3] + fcb[0]);
        out[1] = sig_f(a1[0] + a1[1] + a1[2] + a1[3] + fcb[1]);
    }
}

extern "C" void kernel_launch(void* const* d_in, const int* in_sizes, int n_in,
                              void* d_out, int out_size, void* d_ws, size_t ws_size,
                              hipStream_t stream)
{
    const float* x        = (const float*)d_in[0];
    const float* conv00_w = (const float*)d_in[1];
    const float* conv0_w  = (const float*)d_in[2];
    const float* conv1_w  = (const float*)d_in[3];
    const float* conv1_b  = (const float*)d_in[4];
    const float* u1_w     = (const float*)d_in[5];
    const float* u1_b     = (const float*)d_in[6];
    const float* u2_w     = (const float*)d_in[7];
    const float* u2_b     = (const float*)d_in[8];
    const float* w_inh    = (const float*)d_in[9];
    const float* w_exc    = (const float*)d_in[10];
    const float* alpha    = (const float*)d_in[11];
    const float* mu       = (const float*)d_in[12];
    const float* gamma_p  = (const float*)d_in[13];
    const float* kappa    = (const float*)d_in[14];
    const float* w_mix    = (const float*)d_in[15];
    const float* bn1_w    = (const float*)d_in[16];
    const float* bn1_b    = (const float*)d_in[17];
    const float* bn3_w    = (const float*)d_in[18];
    const float* bn3_b    = (const float*)d_in[19];
    const float* bn_out_w = (const float*)d_in[20];
    const float* bn_out_b = (const float*)d_in[21];
    const float* fc4_w    = (const float*)d_in[22];
    const float* fc4_b    = (const float*)d_in[23];

    float* ws = (float*)d_ws;
    // layout (floats):
    float* Y    = ws;                    // 6,553,600  [2,25,8,128,128]
    float* A    = ws + 6553600;          // 6,553,600  conv00 out; recycled as 8 step buffers
    float* B0p  = ws + 13107200;         // 1,310,720  conv0 partials [5][2,1,8,128,128]
    float* SC1  = ws + 14417920;
    float* SH1  = SC1 + 32;
    float* SC2  = SH1 + 32;
    float* SH2  = SC2 + 32;
    float* PART = SH2 + 32;              // 1600 (800 x float2)

    float* H    = A;
    float* HG1  = A + 1 * NELEM;
    float* NS1  = A + 2 * NELEM;
    float* G2   = A + 3 * NELEM;
    float* C1   = A + 4 * NELEM;         // pair: kg0 at C1, kg1 at C1+NELEM
    float* C2   = A + 6 * NELEM;         // pair

    // 3D conv front-end
    conv3d7_kernel<3, 3, 1, 25, 1, false><<<dim3(8, 25, 16), 128, 0, stream>>>(x,   conv00_w, nullptr, A);
    conv3d7_kernel<25, 5, 5, 1, 1, false><<<dim3(8, 5, 16), 128, 0, stream>>>(A,   conv0_w,  nullptr, B0p);
    conv3d7_kernel<1, 1, 1, 25, 5, true ><<<dim3(8, 25, 16), 128, 0, stream>>>(B0p, conv1_w,  conv1_b, Y);

    (void)hipMemsetAsync(H, 0, NELEM * sizeof(float), stream);

    for (int t = 0; t < 8; ++t) {
        gate_kernel<false, true><<<128, 256, 0, stream>>>(H, u1_w, u1_b, nullptr, HG1);
        conv2d15_kernel<<<dim3(8, 25, 4), 128, 0, stream>>>(HG1, w_inh, C1);
        bnstats_kernel<true><<<25, 1024, 0, stream>>>(C1, bn1_w, bn1_b, SC1, SH1);
        ns1_kernel<<<3200, 256, 0, stream>>>(Y, H, C1, SC1, SH1, alpha, mu, NS1, t);
        gate_kernel<true, false><<<128, 256, 0, stream>>>(NS1, u2_w, u2_b, G2, nullptr);
        conv2d15_kernel<<<dim3(8, 25, 4), 128, 0, stream>>>(NS1, w_exc, C2);
        bnstats_kernel<true><<<25, 1024, 0, stream>>>(C2, bn3_w, bn3_b, SC2, SH2);
        hnew_kernel<<<3200, 256, 0, stream>>>(H, G2, NS1, C2, SC2, SH2, kappa, gamma_p, w_mix);
    }

    bnstats_kernel<false><<<25, 1024, 0, stream>>>(H, bn_out_w, bn_out_b, SC1, SH1);
    fc1_kernel<<<800, 256, 0, stream>>>(H, SC1, SH1, fc4_w, (float2*)PART);
    fc2_kernel<<<1, 256, 0, stream>>>((const float2*)PART, fc4_b, (float*)d_out);
}

// Round 4
// 2222.719 us; speedup vs baseline: 3.8642x; 1.8997x over previous
//
#include <hip/hip_runtime.h>
#include <cstddef>

#define HW 16384           // 128*128
#define NELEM 819200       // 2*25*HW

typedef _Float16 f16x8 __attribute__((ext_vector_type(8)));
typedef float    f32x16 __attribute__((ext_vector_type(16)));

__device__ __forceinline__ float sp_f(float x) {
    return fmaxf(x, 0.f) + log1pf(expf(-fabsf(x)));
}
__device__ __forceinline__ float sig_f(float x) {
    return 1.f / (1.f + expf(-x));
}

// ---------------- 3D conv 7x7x7, pad 3, NCDHW (fp32 VALU path) ----------------
// 128 threads; tile 128 cols x 16 rows; thread = 8 cols x 2 rows (sliding window).
template<int ICTOT, int ICG, int NICG, int OC, int NSUM, bool BIAS_SQ>
__global__ __launch_bounds__(128) void conv3d7_kernel(
    const float* __restrict__ in, const float* __restrict__ wgt,
    const float* __restrict__ bias, float* __restrict__ out)
{
    const int y0  = blockIdx.x * 16;
    const int by  = blockIdx.y;
    const int oc  = by / NICG;
    const int icg = by % NICG;
    const int b   = blockIdx.z >> 3;
    const int zo  = blockIdx.z & 7;

    __shared__ __align__(16) float lds[22 * 136];

    const int tid = threadIdx.x;
    const int tx  = tid & 15;
    const int ty  = tid >> 4;

    float acc0[8] = {0,0,0,0,0,0,0,0};
    float acc1[8] = {0,0,0,0,0,0,0,0};

    for (int ic = icg * ICG; ic < icg * ICG + ICG; ++ic) {
        for (int dz = 0; dz < 7; ++dz) {
            const int zin = zo + dz - 3;
            if (zin < 0 || zin >= 8) continue;
            __syncthreads();
            const float* src = in + (((size_t)((b * ICTOT + ic) * 8 + zin)) << 14);
            for (int idx = tid; idx < 22 * 134; idx += 128) {
                int r = idx / 134, c = idx - r * 134;
                int gy = y0 + r - 3, gx = c - 3;
                float v = 0.f;
                if ((unsigned)gy < 128u && (unsigned)gx < 128u) {
                    if (NSUM == 1) v = src[(gy << 7) + gx];
                    else {
                        #pragma unroll
                        for (int g = 0; g < NSUM; ++g) v += src[(size_t)g * 262144 + (gy << 7) + gx];
                    }
                }
                lds[r * 136 + c] = v;
            }
            __syncthreads();

            const float* wbase = wgt + ((size_t)(oc * ICTOT + ic) * 7 + dz) * 49;
            const float* lrow  = &lds[(ty << 1) * 136 + (tx << 3)];
            float wn[7], wo[7];
            {
                float rr[16];
                #pragma unroll
                for (int i = 0; i < 4; ++i) ((float4*)rr)[i] = ((const float4*)lrow)[i];
                #pragma unroll
                for (int d = 0; d < 7; ++d) wn[d] = wbase[d];
                #pragma unroll
                for (int dx = 0; dx < 7; ++dx) {
                    float wv = wn[dx];
                    #pragma unroll
                    for (int k = 0; k < 8; ++k) acc0[k] += rr[dx + k] * wv;
                }
                #pragma unroll
                for (int d = 0; d < 7; ++d) wo[d] = wn[d];
            }
            #pragma unroll
            for (int j = 1; j <= 6; ++j) {
                float rr[16];
                const float* lp = lrow + j * 136;
                #pragma unroll
                for (int i = 0; i < 4; ++i) ((float4*)rr)[i] = ((const float4*)lp)[i];
                #pragma unroll
                for (int d = 0; d < 7; ++d) wn[d] = wbase[j * 7 + d];
                #pragma unroll
                for (int dx = 0; dx < 7; ++dx) {
                    float w0 = wn[dx], w1 = wo[dx];
                    #pragma unroll
                    for (int k = 0; k < 8; ++k) {
                        acc0[k] += rr[dx + k] * w0;
                        acc1[k] += rr[dx + k] * w1;
                    }
                }
                #pragma unroll
                for (int d = 0; d < 7; ++d) wo[d] = wn[d];
            }
            {
                float rr[16];
                const float* lp = lrow + 7 * 136;
                #pragma unroll
                for (int i = 0; i < 4; ++i) ((float4*)rr)[i] = ((const float4*)lp)[i];
                #pragma unroll
                for (int dx = 0; dx < 7; ++dx) {
                    float wv = wo[dx];
                    #pragma unroll
                    for (int k = 0; k < 8; ++k) acc1[k] += rr[dx + k] * wv;
                }
            }
        }
    }
    if (BIAS_SQ) {
        float bv = bias[oc];
        #pragma unroll
        for (int k = 0; k < 8; ++k) {
            acc0[k] += bv; acc0[k] *= acc0[k];
            acc1[k] += bv; acc1[k] *= acc1[k];
        }
    }
    const int oy = y0 + (ty << 1), ox = tx << 3;
    float* op = out + (size_t)icg * (2 * OC * 8 * HW)
              + (((size_t)((b * OC + oc) * 8 + zo)) << 14) + (oy << 7) + ox;
    *(float4*)op         = make_float4(acc0[0], acc0[1], acc0[2], acc0[3]);
    *(float4*)(op + 4)   = make_float4(acc0[4], acc0[5], acc0[6], acc0[7]);
    *(float4*)(op + 128) = make_float4(acc1[0], acc1[1], acc1[2], acc1[3]);
    *(float4*)(op + 132) = make_float4(acc1[4], acc1[5], acc1[6], acc1[7]);
}

// ---------------- weight repack: [25,25,15,15] fp32 -> MFMA A-fragment f16 ----------------
// layout idx = t*1024 + ks*512 + half*256 + m*8 + j ; ic = ks*16 + half*8 + j
__global__ __launch_bounds__(256) void repack_w_kernel(
    const float* __restrict__ w, _Float16* __restrict__ wt)
{
    const int idx = blockIdx.x * 256 + threadIdx.x;   // < 230400
    const int j    = idx & 7;
    const int m    = (idx >> 3) & 31;
    const int half = (idx >> 8) & 1;
    const int ks   = (idx >> 9) & 1;
    const int t    = idx >> 10;                       // < 225
    const int ic   = ks * 16 + half * 8 + j;
    float v = 0.f;
    if (m < 25 && ic < 25) v = w[(m * 25 + ic) * 225 + t];
    wt[idx] = (_Float16)v;
}

// ---------------- 2D conv 15x15 via MFMA 32x32x16 f16, tap-decomposed ----------------
// XT: f16 [2][142][144][32] channel-last, 7-halo zero-padded. WT: repacked f16.
// 128 threads = 2 waves; wave computes 25 oc x 64 px (2 N-tiles of 32) of one row y.
// grid: x = b*128+y (0..255), y = kg (ky-split 2) -> partial out at kg*NELEM.
__global__ __launch_bounds__(128) void conv2d15_mfma(
    const _Float16* __restrict__ xt, const _Float16* __restrict__ wt,
    float* __restrict__ out)
{
    const int g  = blockIdx.x;
    const int b  = g >> 7;
    const int y  = g & 127;
    const int kg = blockIdx.y;
    const int ky0 = kg ? 8 : 0, ky1 = kg ? 15 : 8;

    const int tid  = threadIdx.x;
    const int wv   = tid >> 6;
    const int lane = tid & 63;
    const int n    = lane & 31;          // B: column (pixel); A: row m (oc)
    const int half = lane >> 5;          // k-half
    const int x0   = wv << 6;            // 64 px per wave

    f32x16 acc0; f32x16 acc1;
    #pragma unroll
    for (int i = 0; i < 16; ++i) { acc0[i] = 0.f; acc1[i] = 0.f; }

    const _Float16* xrow = xt + ((size_t)(b * 142 + y) * 144) * 32;
    for (int ky = ky0; ky < ky1; ++ky) {
        const _Float16* xr = xrow + (size_t)ky * (144 * 32);
        const _Float16* wr = wt + (size_t)(ky * 15) * 1024 + half * 256 + n * 8;
        #pragma unroll
        for (int kx = 0; kx < 15; ++kx) {
            const _Float16* wp = wr + kx * 1024;
            f16x8 a0 = *(const f16x8*)(wp);          // ic 0..15 slice
            f16x8 a1 = *(const f16x8*)(wp + 512);    // ic 16..31 slice
            const _Float16* bp = xr + (size_t)(x0 + n + kx) * 32 + half * 8;
            f16x8 b00 = *(const f16x8*)(bp);
            f16x8 b01 = *(const f16x8*)(bp + 16);
            f16x8 b10 = *(const f16x8*)(bp + 1024);
            f16x8 b11 = *(const f16x8*)(bp + 1024 + 16);
            acc0 = __builtin_amdgcn_mfma_f32_32x32x16_f16(a0, b00, acc0, 0, 0, 0);
            acc1 = __builtin_amdgcn_mfma_f32_32x32x16_f16(a0, b10, acc1, 0, 0, 0);
            acc0 = __builtin_amdgcn_mfma_f32_32x32x16_f16(a1, b01, acc0, 0, 0, 0);
            acc1 = __builtin_amdgcn_mfma_f32_32x32x16_f16(a1, b11, acc1, 0, 0, 0);
        }
    }
    // C/D layout (m74/m101): col = lane&31, row = (reg&3) + 8*(reg>>2) + 4*(lane>>5)
    float* obase = out + (size_t)kg * NELEM + (((size_t)b * 25) << 14) + (y << 7) + x0 + n;
    #pragma unroll
    for (int r = 0; r < 16; ++r) {
        const int row = (r & 3) + 8 * (r >> 2) + 4 * half;
        if (row < 25) {
            obase[(size_t)row << 14]        = acc0[r];
            obase[((size_t)row << 14) + 32] = acc1[r];
        }
    }
}

// ---------------- 1x1 gate conv + XT (channel-last f16 halo-padded) writer ----------------
// G2MODE=false: XT = f16(h*g)            (inhibition path input)
// G2MODE=true : gout = g (fp32 planes), XT = f16(h)   (excitation path: h==ns1)
template<bool G2MODE>
__global__ __launch_bounds__(256) void gate_kernel(
    const float* __restrict__ hin, const float* __restrict__ w,
    const float* __restrict__ bias, float* __restrict__ gout,
    _Float16* __restrict__ xt)
{
    const int p = blockIdx.x * 256 + threadIdx.x;   // < 32768
    const int b = p >> 14, pix = p & (HW - 1);
    const float* hp = hin + (((size_t)b * 25) << 14) + pix;
    float hv[25];
    #pragma unroll
    for (int ic = 0; ic < 25; ++ic) hv[ic] = hp[(size_t)ic << 14];
    __align__(16) _Float16 xv[32];
    #pragma unroll
    for (int oc = 0; oc < 25; ++oc) {
        float acc = bias[oc];
        #pragma unroll
        for (int ic = 0; ic < 25; ++ic) acc += w[oc * 25 + ic] * hv[ic];
        const float g = sig_f(acc);
        if (G2MODE) {
            gout[(((size_t)(b * 25 + oc)) << 14) + pix] = g;
            xv[oc] = (_Float16)hv[oc];
        } else {
            xv[oc] = (_Float16)(hv[oc] * g);
        }
    }
    #pragma unroll
    for (int oc = 25; oc < 32; ++oc) xv[oc] = (_Float16)0.f;
    const int y = pix >> 7, x = pix & 127;
    _Float16* xp = xt + (((size_t)(b * 142 + y + 7)) * 144 + (x + 7)) * 32;
    #pragma unroll
    for (int i = 0; i < 4; ++i) ((float4*)xp)[i] = ((const float4*)xv)[i];
}

// ---------------- BN batch-stats (optionally summing split-K partial pair) ----------------
template<bool PAIR>
__global__ __launch_bounds__(1024) void bnstats_kernel(
    const float* __restrict__ x, const float* __restrict__ gw, const float* __restrict__ gb,
    float* __restrict__ scale, float* __restrict__ shift)
{
    const int c = blockIdx.x, tid = threadIdx.x;
    float s1 = 0.f, s2 = 0.f;
    const float4* p0 = (const float4*)(x + ((size_t)c << 14));
    const float4* p1 = (const float4*)(x + ((size_t)(25 + c) << 14));
    const float4* q0 = (const float4*)(x + NELEM + ((size_t)c << 14));
    const float4* q1 = (const float4*)(x + NELEM + ((size_t)(25 + c) << 14));
    for (int i = tid; i < 4096; i += 1024) {
        float4 v = p0[i];
        if (PAIR) { float4 w = q0[i]; v.x += w.x; v.y += w.y; v.z += w.z; v.w += w.w; }
        s1 += v.x + v.y + v.z + v.w;
        s2 += v.x * v.x + v.y * v.y + v.z * v.z + v.w * v.w;
        float4 u = p1[i];
        if (PAIR) { float4 w = q1[i]; u.x += w.x; u.y += w.y; u.z += w.z; u.w += w.w; }
        s1 += u.x + u.y + u.z + u.w;
        s2 += u.x * u.x + u.y * u.y + u.z * u.z + u.w * u.w;
    }
    #pragma unroll
    for (int off = 32; off; off >>= 1) { s1 += __shfl_down(s1, off); s2 += __shfl_down(s2, off); }
    __shared__ float a1[16], a2[16];
    if ((tid & 63) == 0) { a1[tid >> 6] = s1; a2[tid >> 6] = s2; }
    __syncthreads();
    if (tid == 0) {
        float t1 = 0.f, t2 = 0.f;
        #pragma unroll
        for (int i = 0; i < 16; ++i) { t1 += a1[i]; t2 += a2[i]; }
        const float m = t1 * (1.f / 32768.f);
        const float var = fmaxf(t2 * (1.f / 32768.f) - m * m, 0.f);
        const float sc = gw[c] * rsqrtf(var + 1e-3f);
        scale[c] = sc;
        shift[c] = gb[c] - m * sc;
    }
}

// ---------------- ns1 = sp(y_t - sp(bn(c1a+c1b) * (alpha*h + mu))) ----------------
__global__ __launch_bounds__(256) void ns1_kernel(
    const float* __restrict__ y, const float* __restrict__ h,
    const float* __restrict__ c1, const float* __restrict__ scale,
    const float* __restrict__ shift, const float* __restrict__ alpha,
    const float* __restrict__ mu, float* __restrict__ ns1, int t)
{
    const int idx = blockIdx.x * 256 + threadIdx.x;   // < NELEM
    const int bc = idx >> 14;
    const int c = bc >= 25 ? bc - 25 : bc;
    const int pix = idx & (HW - 1);
    const float yv = y[((size_t)bc << 17) + ((size_t)t << 14) + pix];
    const float c1v = c1[idx] + c1[NELEM + idx];
    const float c1n = c1v * scale[c] + shift[c];
    const float pre = c1n * (alpha[c] * h[idx] + mu[c]);
    ns1[idx] = sp_f(yv - sp_f(pre));
}

// ---------------- h = sp((1-g2)*h + g2 * sp(kappa*n + gp*c2n + wmix*n*c2n)) ----------------
__global__ __launch_bounds__(256) void hnew_kernel(
    float* __restrict__ h, const float* __restrict__ g2,
    const float* __restrict__ ns1, const float* __restrict__ c2,
    const float* __restrict__ scale, const float* __restrict__ shift,
    const float* __restrict__ kappa, const float* __restrict__ gp,
    const float* __restrict__ wmix)
{
    const int idx = blockIdx.x * 256 + threadIdx.x;
    const int bc = idx >> 14;
    const int c = bc >= 25 ? bc - 25 : bc;
    const float c2v = c2[idx] + c2[NELEM + idx];
    const float c2n = c2v * scale[c] + shift[c];
    const float n = ns1[idx];
    const float h2 = sp_f(kappa[c] * n + gp[c] * c2n + wmix[c] * n * c2n);
    const float g = g2[idx];
    h[idx] = sp_f((1.f - g) * h[idx] + g * h2);
}

// ---------------- fused bn_out + avgpool2 + fc partial dot ----------------
__global__ __launch_bounds__(256) void fc1_kernel(
    const float* __restrict__ h, const float* __restrict__ scale,
    const float* __restrict__ shift, const float* __restrict__ fcw,
    float2* __restrict__ part)
{
    const int tid = threadIdx.x;
    const int i = blockIdx.x * 256 + tid;   // < 204800
    int px = i & 63;
    int t = i >> 6;
    int py = t & 63; t >>= 6;               // t = b*25 + c
    int c = t >= 25 ? t - 25 : t;
    const float* hp = h + ((size_t)t << 14);
    const int y0 = py << 1, xg = px << 1;
    float s = hp[(y0 << 7) + xg] + hp[(y0 << 7) + xg + 1]
            + hp[((y0 + 1) << 7) + xg] + hp[((y0 + 1) << 7) + xg + 1];
    const float o = 0.25f * s * scale[c] + shift[c];
    float p0 = o * fcw[i];
    float p1 = o * fcw[204800 + i];
    #pragma unroll
    for (int off = 32; off; off >>= 1) { p0 += __shfl_down(p0, off); p1 += __shfl_down(p1, off); }
    __shared__ float a0[4], a1[4];
    if ((tid & 63) == 0) { a0[tid >> 6] = p0; a1[tid >> 6] = p1; }
    __syncthreads();
    if (tid == 0)
        part[blockIdx.x] = make_float2(a0[0] + a0[1] + a0[2] + a0[3],
                                       a1[0] + a1[1] + a1[2] + a1[3]);
}

__global__ __launch_bounds__(256) void fc2_kernel(
    const float2* __restrict__ part, const float* __restrict__ fcb, float* __restrict__ out)
{
    const int tid = threadIdx.x;
    float s0 = 0.f, s1 = 0.f;
    for (int i = tid; i < 800; i += 256) { float2 v = part[i]; s0 += v.x; s1 += v.y; }
    #pragma unroll
    for (int off = 32; off; off >>= 1) { s0 += __shfl_down(s0, off); s1 += __shfl_down(s1, off); }
    __shared__ float a0[4], a1[4];
    if ((tid & 63) == 0) { a0[tid >> 6] = s0; a1[tid >> 6] = s1; }
    __syncthreads();
    if (tid == 0) {
        out[0] = sig_f(a0[0] + a0[1] + a0[2] + a0[3] + fcb[0]);
        out[1] = sig_f(a1[0] + a1[1] + a1[2] + a1[3] + fcb[1]);
    }
}

extern "C" void kernel_launch(void* const* d_in, const int* in_sizes, int n_in,
                              void* d_out, int out_size, void* d_ws, size_t ws_size,
                              hipStream_t stream)
{
    const float* x        = (const float*)d_in[0];
    const float* conv00_w = (const float*)d_in[1];
    const float* conv0_w  = (const float*)d_in[2];
    const float* conv1_w  = (const float*)d_in[3];
    const float* conv1_b  = (const float*)d_in[4];
    const float* u1_w     = (const float*)d_in[5];
    const float* u1_b     = (const float*)d_in[6];
    const float* u2_w     = (const float*)d_in[7];
    const float* u2_b     = (const float*)d_in[8];
    const float* w_inh    = (const float*)d_in[9];
    const float* w_exc    = (const float*)d_in[10];
    const float* alpha    = (const float*)d_in[11];
    const float* mu       = (const float*)d_in[12];
    const float* gamma_p  = (const float*)d_in[13];
    const float* kappa    = (const float*)d_in[14];
    const float* w_mix    = (const float*)d_in[15];
    const float* bn1_w    = (const float*)d_in[16];
    const float* bn1_b    = (const float*)d_in[17];
    const float* bn3_w    = (const float*)d_in[18];
    const float* bn3_b    = (const float*)d_in[19];
    const float* bn_out_w = (const float*)d_in[20];
    const float* bn_out_b = (const float*)d_in[21];
    const float* fc4_w    = (const float*)d_in[22];
    const float* fc4_b    = (const float*)d_in[23];

    float* ws = (float*)d_ws;
    // layout (floats):
    float* Y    = ws;                    // 6,553,600  [2,25,8,128,128]
    float* S    = ws + 6553600;          // 6,553,600  conv00 out; then 7 step buffers
    float* B0p  = ws + 13107200;         // 1,310,720  conv0 partials; then XT/WT (f16)
    float* SC1  = ws + 14417920;
    float* SH1  = SC1 + 32;
    float* SC2  = SH1 + 32;
    float* SH2  = SC2 + 32;
    float* PART = SH2 + 32;              // 1600 (800 x float2)

    float* H    = S;                     // step buffers (7*NELEM = 5,734,400 <= 6,553,600)
    float* NS1  = S + 1 * NELEM;
    float* G2   = S + 2 * NELEM;
    float* C1   = S + 3 * NELEM;         // pair
    float* C2   = S + 5 * NELEM;         // pair

    _Float16* XT  = (_Float16*)B0p;              // 1,308,672 f16 (654,336 fl)
    _Float16* WT1 = (_Float16*)(B0p + 654336);   // 230,400 f16 (115,200 fl)
    _Float16* WT2 = (_Float16*)(B0p + 769536);   // 230,400 f16 -> ends 884,736 fl

    // 3D conv front-end (uses S then B0p before they are recycled)
    conv3d7_kernel<3, 3, 1, 25, 1, false><<<dim3(8, 25, 16), 128, 0, stream>>>(x,   conv00_w, nullptr, S);
    conv3d7_kernel<25, 5, 5, 1, 1, false><<<dim3(8, 5, 16), 128, 0, stream>>>(S,   conv0_w,  nullptr, B0p);
    conv3d7_kernel<1, 1, 1, 25, 5, true ><<<dim3(8, 25, 16), 128, 0, stream>>>(B0p, conv1_w,  conv1_b, Y);

    // XT halo zeros + weight repack + h0 (stream-ordered after front-end reads)
    (void)hipMemsetAsync(XT, 0, (size_t)1308672 * sizeof(_Float16), stream);
    repack_w_kernel<<<900, 256, 0, stream>>>(w_inh, WT1);
    repack_w_kernel<<<900, 256, 0, stream>>>(w_exc, WT2);
    (void)hipMemsetAsync(H, 0, (size_t)NELEM * sizeof(float), stream);

    for (int t = 0; t < 8; ++t) {
        gate_kernel<false><<<128, 256, 0, stream>>>(H, u1_w, u1_b, nullptr, XT);
        conv2d15_mfma<<<dim3(256, 2), 128, 0, stream>>>(XT, WT1, C1);
        bnstats_kernel<true><<<25, 1024, 0, stream>>>(C1, bn1_w, bn1_b, SC1, SH1);
        ns1_kernel<<<3200, 256, 0, stream>>>(Y, H, C1, SC1, SH1, alpha, mu, NS1, t);
        gate_kernel<true><<<128, 256, 0, stream>>>(NS1, u2_w, u2_b, G2, XT);
        conv2d15_mfma<<<dim3(256, 2), 128, 0, stream>>>(XT, WT2, C2);
        bnstats_kernel<true><<<25, 1024, 0, stream>>>(C2, bn3_w, bn3_b, SC2, SH2);
        hnew_kernel<<<3200, 256, 0, stream>>>(H, G2, NS1, C2, SC2, SH2, kappa, gamma_p, w_mix);
    }

    bnstats_kernel<false><<<25, 1024, 0, stream>>>(H, bn_out_w, bn_out_b, SC1, SH1);
    fc1_kernel<<<800, 256, 0, stream>>>(H, SC1, SH1, fc4_w, (float2*)PART);
    fc2_kernel<<<1, 256, 0, stream>>>((const float2*)PART, fc4_b, (float*)d_out);
}

// Round 5
// 1724.332 us; speedup vs baseline: 4.9811x; 1.2890x over previous
//
#include <hip/hip_runtime.h>
#include <cstddef>

#define HW 16384           // 128*128
#define NELEM 819200       // 2*25*HW

typedef _Float16 f16x8 __attribute__((ext_vector_type(8)));
typedef _Float16 f16x4 __attribute__((ext_vector_type(4)));
typedef float    f32x16 __attribute__((ext_vector_type(16)));

#define MFMA32(a, b, c) __builtin_amdgcn_mfma_f32_32x32x16_f16((a), (b), (c), 0, 0, 0)

__device__ __forceinline__ float sp_f(float x) {
    return fmaxf(x, 0.f) + log1pf(expf(-fabsf(x)));
}
__device__ __forceinline__ float sig_f(float x) {
    return 1.f / (1.f + expf(-x));
}

// ---------------- 3D conv 7x7x7 fp32 VALU (kept for conv0: 25ch -> 1ch) ----------------
template<int ICTOT, int ICG, int NICG, int OC, bool BIAS_SQ>
__global__ __launch_bounds__(128) void conv3d7_kernel(
    const float* __restrict__ in, const float* __restrict__ wgt,
    const float* __restrict__ bias, float* __restrict__ out)
{
    const int y0  = blockIdx.x * 16;
    const int by  = blockIdx.y;
    const int oc  = by / NICG;
    const int icg = by % NICG;
    const int b   = blockIdx.z >> 3;
    const int zo  = blockIdx.z & 7;

    __shared__ __align__(16) float lds[22 * 136];

    const int tid = threadIdx.x;
    const int tx  = tid & 15;
    const int ty  = tid >> 4;

    float acc0[8] = {0,0,0,0,0,0,0,0};
    float acc1[8] = {0,0,0,0,0,0,0,0};

    for (int ic = icg * ICG; ic < icg * ICG + ICG; ++ic) {
        for (int dz = 0; dz < 7; ++dz) {
            const int zin = zo + dz - 3;
            if (zin < 0 || zin >= 8) continue;
            __syncthreads();
            const float* src = in + (((size_t)((b * ICTOT + ic) * 8 + zin)) << 14);
            for (int idx = tid; idx < 22 * 134; idx += 128) {
                int r = idx / 134, c = idx - r * 134;
                int gy = y0 + r - 3, gx = c - 3;
                float v = 0.f;
                if ((unsigned)gy < 128u && (unsigned)gx < 128u) v = src[(gy << 7) + gx];
                lds[r * 136 + c] = v;
            }
            __syncthreads();

            const float* wbase = wgt + ((size_t)(oc * ICTOT + ic) * 7 + dz) * 49;
            const float* lrow  = &lds[(ty << 1) * 136 + (tx << 3)];
            float wn[7], wo[7];
            {
                float rr[16];
                #pragma unroll
                for (int i = 0; i < 4; ++i) ((float4*)rr)[i] = ((const float4*)lrow)[i];
                #pragma unroll
                for (int d = 0; d < 7; ++d) wn[d] = wbase[d];
                #pragma unroll
                for (int dx = 0; dx < 7; ++dx) {
                    float wv = wn[dx];
                    #pragma unroll
                    for (int k = 0; k < 8; ++k) acc0[k] += rr[dx + k] * wv;
                }
                #pragma unroll
                for (int d = 0; d < 7; ++d) wo[d] = wn[d];
            }
            #pragma unroll
            for (int j = 1; j <= 6; ++j) {
                float rr[16];
                const float* lp = lrow + j * 136;
                #pragma unroll
                for (int i = 0; i < 4; ++i) ((float4*)rr)[i] = ((const float4*)lp)[i];
                #pragma unroll
                for (int d = 0; d < 7; ++d) wn[d] = wbase[j * 7 + d];
                #pragma unroll
                for (int dx = 0; dx < 7; ++dx) {
                    float w0 = wn[dx], w1 = wo[dx];
                    #pragma unroll
                    for (int k = 0; k < 8; ++k) {
                        acc0[k] += rr[dx + k] * w0;
                        acc1[k] += rr[dx + k] * w1;
                    }
                }
                #pragma unroll
                for (int d = 0; d < 7; ++d) wo[d] = wn[d];
            }
            {
                float rr[16];
                const float* lp = lrow + 7 * 136;
                #pragma unroll
                for (int i = 0; i < 4; ++i) ((float4*)rr)[i] = ((const float4*)lp)[i];
                #pragma unroll
                for (int dx = 0; dx < 7; ++dx) {
                    float wv = wo[dx];
                    #pragma unroll
                    for (int k = 0; k < 8; ++k) acc1[k] += rr[dx + k] * wv;
                }
            }
        }
    }
    if (BIAS_SQ) {
        float bv = bias[oc];
        #pragma unroll
        for (int k = 0; k < 8; ++k) {
            acc0[k] += bv; acc0[k] *= acc0[k];
            acc1[k] += bv; acc1[k] *= acc1[k];
        }
    }
    const int oy = y0 + (ty << 1), ox = tx << 3;
    float* op = out + (size_t)icg * (2 * OC * 8 * HW)
              + (((size_t)((b * OC + oc) * 8 + zo)) << 14) + (oy << 7) + ox;
    *(float4*)op         = make_float4(acc0[0], acc0[1], acc0[2], acc0[3]);
    *(float4*)(op + 4)   = make_float4(acc0[4], acc0[5], acc0[6], acc0[7]);
    *(float4*)(op + 128) = make_float4(acc1[0], acc1[1], acc1[2], acc1[3]);
    *(float4*)(op + 132) = make_float4(acc1[4], acc1[5], acc1[6], acc1[7]);
}

// ---------------- front-end prepack kernels ----------------
// X0: f16 [2][8][134][136][4]   (ic 3->4 pad, halo 3, zero borders via memset)
__global__ __launch_bounds__(256) void xpack0_kernel(
    const float* __restrict__ x, _Float16* __restrict__ x0)
{
    const int p = blockIdx.x * 256 + threadIdx.x;   // < 262144
    const int b = p >> 17, rem = p & 131071;
    const int z = rem >> 14, pix = rem & 16383;
    const int y = pix >> 7, xx = pix & 127;
    const size_t sb = ((size_t)b * 3 * 8 + z) << 14;
    f16x4 v;
    v[0] = (_Float16)x[sb + pix];
    v[1] = (_Float16)x[sb + (8ull << 14) + pix];
    v[2] = (_Float16)x[sb + (16ull << 14) + pix];
    v[3] = (_Float16)0.f;
    *(f16x4*)(x0 + (((size_t)(b * 8 + z) * 134 + y + 3) * 136 + xx + 3) * 4) = v;
}

// WT0: A-frag repack of conv00_w (25,3,7,7,7): off=(tapb*2+kk)*512 + h*256 + m*8 + j
__global__ __launch_bounds__(256) void repack_w00_kernel(
    const float* __restrict__ w, _Float16* __restrict__ wt)
{
    const int idx = blockIdx.x * 256 + threadIdx.x;   // < 50176 (=196*256)
    const int j  = idx & 7;
    const int m  = (idx >> 3) & 31;
    const int h  = (idx >> 8) & 1;
    const int kk = (idx >> 9) & 1;
    const int tapb = idx >> 10;                       // dz*7+dy, < 49
    const int dz = tapb / 7, dy = tapb - dz * 7;
    const int ic = j & 3, dxl = j >> 2;
    const int dx = kk * 4 + h * 2 + dxl;
    float v = 0.f;
    if (m < 25 && ic < 3 && dx < 7)
        v = w[(((m * 3 + ic) * 7 + dz) * 7 + dy) * 7 + dx];
    wt[idx] = (_Float16)v;
}

// X1: f16 [2][8][134][136][2]  (channel (val,0), halo 3); sums 25 conv0 partials
__global__ __launch_bounds__(256) void xpack1_kernel(
    const float* __restrict__ b0p, _Float16* __restrict__ x1)
{
    const int p = blockIdx.x * 256 + threadIdx.x;   // < 262144
    const int b = p >> 17, rem = p & 131071;
    const int z = rem >> 14, pix = rem & 16383;
    const int y = pix >> 7, xx = pix & 127;
    float s = 0.f;
    #pragma unroll
    for (int g = 0; g < 25; ++g) s += b0p[(size_t)g * 262144 + p];
    x1[(((size_t)(b * 8 + z) * 134 + y + 3) * 136 + xx + 3) * 2] = (_Float16)s;
}

// WT1c: A-frag repack of conv1_w (25,1,7,7,7): off = tapb*512 + h*256 + m*8 + j
__global__ __launch_bounds__(256) void repack_w1_kernel(
    const float* __restrict__ w, _Float16* __restrict__ wt)
{
    const int idx = blockIdx.x * 256 + threadIdx.x;   // < 25088 (=98*256)
    const int j = idx & 7;
    const int m = (idx >> 3) & 31;
    const int h = (idx >> 8) & 1;
    const int tapb = idx >> 9;                        // < 49
    const int dz = tapb / 7, dy = tapb - dz * 7;
    const int c2 = j & 1, dx = h * 4 + (j >> 1);
    float v = 0.f;
    if (m < 25 && c2 == 0 && dx < 7)
        v = w[((m * 7 + dz) * 7 + dy) * 7 + dx];
    wt[idx] = (_Float16)v;
}

// ---------------- conv00 via MFMA: 3ch -> 25ch, 7^3 taps ----------------
// grid: 2048 blocks (b*1024 + zo*128 + y), 128 thr = 2 waves x 64 px
__global__ __launch_bounds__(128) void conv3d00_mfma(
    const _Float16* __restrict__ x0, const _Float16* __restrict__ wt0,
    float* __restrict__ out)
{
    const int g = blockIdx.x;
    const int b = g >> 10;
    const int zo = (g >> 7) & 7;
    const int y = g & 127;
    const int tid = threadIdx.x;
    const int wv = tid >> 6;
    const int lane = tid & 63;
    const int n = lane & 31;
    const int h = lane >> 5;
    const int xc = wv << 6;

    f32x16 acc0, acc1;
    #pragma unroll
    for (int i = 0; i < 16; ++i) { acc0[i] = 0.f; acc1[i] = 0.f; }

    for (int dz = 0; dz < 7; ++dz) {
        const int zin = zo + dz - 3;
        if (zin < 0 || zin >= 8) continue;
        const _Float16* xpl = x0 + (size_t)(b * 8 + zin) * (134 * 136 * 4);
        #pragma unroll
        for (int dy = 0; dy < 7; ++dy) {
            const _Float16* xr = xpl + (size_t)(y + dy) * (136 * 4);
            const _Float16* wb = wt0 + (size_t)((dz * 7 + dy) * 2) * 512 + h * 256 + n * 8;
            f16x8 a0 = *(const f16x8*)(wb);
            f16x8 a1 = *(const f16x8*)(wb + 512);
            const _Float16* bp = xr + (size_t)(xc + n + 2 * h) * 4;
            f16x8 b00 = *(const f16x8*)(bp);          // kk0 nt0
            f16x8 b01 = *(const f16x8*)(bp + 16);     // kk1 nt0
            f16x8 b10 = *(const f16x8*)(bp + 128);    // kk0 nt1
            f16x8 b11 = *(const f16x8*)(bp + 144);    // kk1 nt1
            acc0 = MFMA32(a0, b00, acc0);
            acc1 = MFMA32(a0, b10, acc1);
            acc0 = MFMA32(a1, b01, acc0);
            acc1 = MFMA32(a1, b11, acc1);
        }
    }
    float* ob = out + ((((size_t)b * 25) * 8 + zo) << 14) + (y << 7) + xc + n;
    #pragma unroll
    for (int r = 0; r < 16; ++r) {
        const int row = (r & 3) + 8 * (r >> 2) + 4 * h;
        if (row < 25) {
            ob[(size_t)row * 131072]      = acc0[r];
            ob[(size_t)row * 131072 + 32] = acc1[r];
        }
    }
}

// ---------------- conv1 via MFMA: 1ch -> 25ch, 7^3 taps, bias+square fused ----------------
__global__ __launch_bounds__(128) void conv3d1_mfma(
    const _Float16* __restrict__ x1, const _Float16* __restrict__ wt1,
    const float* __restrict__ bias, float* __restrict__ out)
{
    const int g = blockIdx.x;
    const int b = g >> 10;
    const int zo = (g >> 7) & 7;
    const int y = g & 127;
    const int tid = threadIdx.x;
    const int wv = tid >> 6;
    const int lane = tid & 63;
    const int n = lane & 31;
    const int h = lane >> 5;
    const int xc = wv << 6;

    f32x16 acc0, acc1;
    #pragma unroll
    for (int i = 0; i < 16; ++i) { acc0[i] = 0.f; acc1[i] = 0.f; }

    for (int dz = 0; dz < 7; ++dz) {
        const int zin = zo + dz - 3;
        if (zin < 0 || zin >= 8) continue;
        const _Float16* xpl = x1 + (size_t)(b * 8 + zin) * (134 * 136 * 2);
        #pragma unroll
        for (int dy = 0; dy < 7; ++dy) {
            const _Float16* wb = wt1 + (size_t)(dz * 7 + dy) * 512 + h * 256 + n * 8;
            f16x8 a0 = *(const f16x8*)(wb);
            const _Float16* bp = xpl + ((size_t)(y + dy) * 136 + xc + n) * 2 + h * 8;
            f16x8 b0 = *(const f16x8*)(bp);
            f16x8 b1 = *(const f16x8*)(bp + 64);      // nt1: +32 cols
            acc0 = MFMA32(a0, b0, acc0);
            acc1 = MFMA32(a0, b1, acc1);
        }
    }
    const float bv0 = bias ? 0.f : 0.f;  (void)bv0;
    float* ob = out + ((((size_t)b * 25) * 8 + zo) << 14) + (y << 7) + xc + n;
    #pragma unroll
    for (int r = 0; r < 16; ++r) {
        const int row = (r & 3) + 8 * (r >> 2) + 4 * h;
        if (row < 25) {
            float v0 = acc0[r] + bias[row];
            float v1 = acc1[r] + bias[row];
            ob[(size_t)row * 131072]      = v0 * v0;
            ob[(size_t)row * 131072 + 32] = v1 * v1;
        }
    }
}

// ---------------- weight repack for 15x15 (A-frag, as R3) ----------------
__global__ __launch_bounds__(256) void repack_w_kernel(
    const float* __restrict__ w, _Float16* __restrict__ wt)
{
    const int idx = blockIdx.x * 256 + threadIdx.x;   // < 230400
    const int j    = idx & 7;
    const int m    = (idx >> 3) & 31;
    const int half = (idx >> 8) & 1;
    const int ks   = (idx >> 9) & 1;
    const int t    = idx >> 10;                       // < 225
    const int ic   = ks * 16 + half * 8 + j;
    float v = 0.f;
    if (m < 25 && ic < 25) v = w[(m * 25 + ic) * 225 + t];
    wt[idx] = (_Float16)v;
}

// ---------------- 2D conv 15x15 via MFMA, tap-decomposed, ky-split 2 ----------------
// 256 thr = 4 waves x 32 px. grid: x = b*128+y (0..255), y = kg.
__global__ __launch_bounds__(256) void conv2d15_mfma(
    const _Float16* __restrict__ xt, const _Float16* __restrict__ wt,
    float* __restrict__ out)
{
    const int g  = blockIdx.x;
    const int b  = g >> 7;
    const int y  = g & 127;
    const int kg = blockIdx.y;
    const int ky0 = kg ? 8 : 0, ky1 = kg ? 15 : 8;

    const int tid  = threadIdx.x;
    const int wv   = tid >> 6;
    const int lane = tid & 63;
    const int n    = lane & 31;
    const int half = lane >> 5;
    const int xc   = wv << 5;            // 32 px per wave

    f32x16 acc;
    #pragma unroll
    for (int i = 0; i < 16; ++i) acc[i] = 0.f;

    const _Float16* xrow = xt + ((size_t)(b * 142 + y) * 144) * 32;
    for (int ky = ky0; ky < ky1; ++ky) {
        const _Float16* xr = xrow + (size_t)ky * (144 * 32);
        const _Float16* wr = wt + (size_t)(ky * 15) * 1024 + half * 256 + n * 8;
        #pragma unroll
        for (int kx = 0; kx < 15; ++kx) {
            const _Float16* wp = wr + kx * 1024;
            f16x8 a0 = *(const f16x8*)(wp);
            f16x8 a1 = *(const f16x8*)(wp + 512);
            const _Float16* bp = xr + (size_t)(xc + n + kx) * 32 + half * 8;
            f16x8 b0 = *(const f16x8*)(bp);
            f16x8 b1 = *(const f16x8*)(bp + 16);
            acc = MFMA32(a0, b0, acc);
            acc = MFMA32(a1, b1, acc);
        }
    }
    float* obase = out + (size_t)kg * NELEM + (((size_t)b * 25) << 14) + (y << 7) + xc + n;
    #pragma unroll
    for (int r = 0; r < 16; ++r) {
        const int row = (r & 3) + 8 * (r >> 2) + 4 * half;
        if (row < 25) obase[(size_t)row << 14] = acc[r];
    }
}

// ---------------- BN batch-stats (optionally summing split-K partial pair) ----------------
template<bool PAIR>
__global__ __launch_bounds__(1024) void bnstats_kernel(
    const float* __restrict__ x, const float* __restrict__ gw, const float* __restrict__ gb,
    float* __restrict__ scale, float* __restrict__ shift)
{
    const int c = blockIdx.x, tid = threadIdx.x;
    float s1 = 0.f, s2 = 0.f;
    const float4* p0 = (const float4*)(x + ((size_t)c << 14));
    const float4* p1 = (const float4*)(x + ((size_t)(25 + c) << 14));
    const float4* q0 = (const float4*)(x + NELEM + ((size_t)c << 14));
    const float4* q1 = (const float4*)(x + NELEM + ((size_t)(25 + c) << 14));
    for (int i = tid; i < 4096; i += 1024) {
        float4 v = p0[i];
        if (PAIR) { float4 w = q0[i]; v.x += w.x; v.y += w.y; v.z += w.z; v.w += w.w; }
        s1 += v.x + v.y + v.z + v.w;
        s2 += v.x * v.x + v.y * v.y + v.z * v.z + v.w * v.w;
        float4 u = p1[i];
        if (PAIR) { float4 w = q1[i]; u.x += w.x; u.y += w.y; u.z += w.z; u.w += w.w; }
        s1 += u.x + u.y + u.z + u.w;
        s2 += u.x * u.x + u.y * u.y + u.z * u.z + u.w * u.w;
    }
    #pragma unroll
    for (int off = 32; off; off >>= 1) { s1 += __shfl_down(s1, off); s2 += __shfl_down(s2, off); }
    __shared__ float a1[16], a2[16];
    if ((tid & 63) == 0) { a1[tid >> 6] = s1; a2[tid >> 6] = s2; }
    __syncthreads();
    if (tid == 0) {
        float t1 = 0.f, t2 = 0.f;
        #pragma unroll
        for (int i = 0; i < 16; ++i) { t1 += a1[i]; t2 += a2[i]; }
        const float m = t1 * (1.f / 32768.f);
        const float var = fmaxf(t2 * (1.f / 32768.f) - m * m, 0.f);
        const float sc = gw[c] * rsqrtf(var + 1e-3f);
        scale[c] = sc;
        shift[c] = gb[c] - m * sc;
    }
}

// ---------------- fused ns1 + gate2: NS1, G2, XT = f16(ns1) ----------------
__global__ __launch_bounds__(256) void nsg_kernel(
    const float* __restrict__ y, const float* __restrict__ h,
    const float* __restrict__ c1, const float* __restrict__ scale,
    const float* __restrict__ shift, const float* __restrict__ alpha,
    const float* __restrict__ mu, const float* __restrict__ u2w,
    const float* __restrict__ u2b, float* __restrict__ ns1,
    float* __restrict__ g2, _Float16* __restrict__ xt, int t)
{
    const int p = blockIdx.x * 256 + threadIdx.x;   // < 32768
    const int b = p >> 14, pix = p & (HW - 1);
    const size_t base = (((size_t)b * 25) << 14) + pix;
    float nv[25];
    #pragma unroll
    for (int c = 0; c < 25; ++c) {
        const size_t idx = base + ((size_t)c << 14);
        const float yv = y[(((size_t)(b * 25 + c) * 8 + t) << 14) + pix];
        const float c1v = c1[idx] + c1[NELEM + idx];
        const float c1n = c1v * scale[c] + shift[c];
        const float pre = c1n * (alpha[c] * h[idx] + mu[c]);
        const float n = sp_f(yv - sp_f(pre));
        nv[c] = n;
        ns1[idx] = n;
    }
    __align__(16) _Float16 xv[32];
    #pragma unroll
    for (int oc = 0; oc < 25; ++oc) {
        float acc = u2b[oc];
        #pragma unroll
        for (int ic = 0; ic < 25; ++ic) acc += u2w[oc * 25 + ic] * nv[ic];
        g2[base + ((size_t)oc << 14)] = sig_f(acc);
        xv[oc] = (_Float16)nv[oc];
    }
    #pragma unroll
    for (int oc = 25; oc < 32; ++oc) xv[oc] = (_Float16)0.f;
    const int yy = pix >> 7, xx = pix & 127;
    _Float16* xp = xt + (((size_t)(b * 142 + yy + 7)) * 144 + (xx + 7)) * 32;
    #pragma unroll
    for (int i = 0; i < 4; ++i) ((float4*)xp)[i] = ((const float4*)xv)[i];
}

// ---------------- fused hnew + gate1: H, XT = f16(h*g1) ----------------
__global__ __launch_bounds__(256) void hg_kernel(
    float* __restrict__ h, const float* __restrict__ g2,
    const float* __restrict__ ns1, const float* __restrict__ c2,
    const float* __restrict__ scale, const float* __restrict__ shift,
    const float* __restrict__ kappa, const float* __restrict__ gp,
    const float* __restrict__ wmix, const float* __restrict__ u1w,
    const float* __restrict__ u1b, _Float16* __restrict__ xt)
{
    const int p = blockIdx.x * 256 + threadIdx.x;   // < 32768
    const int b = p >> 14, pix = p & (HW - 1);
    const size_t base = (((size_t)b * 25) << 14) + pix;
    float hv[25];
    #pragma unroll
    for (int c = 0; c < 25; ++c) {
        const size_t idx = base + ((size_t)c << 14);
        const float c2v = c2[idx] + c2[NELEM + idx];
        const float c2n = c2v * scale[c] + shift[c];
        const float n = ns1[idx];
        const float h2 = sp_f(kappa[c] * n + gp[c] * c2n + wmix[c] * n * c2n);
        const float g = g2[idx];
        const float hn = sp_f((1.f - g) * h[idx] + g * h2);
        hv[c] = hn;
        h[idx] = hn;
    }
    __align__(16) _Float16 xv[32];
    #pragma unroll
    for (int oc = 0; oc < 25; ++oc) {
        float acc = u1b[oc];
        #pragma unroll
        for (int ic = 0; ic < 25; ++ic) acc += u1w[oc * 25 + ic] * hv[ic];
        xv[oc] = (_Float16)(hv[oc] * sig_f(acc));
    }
    #pragma unroll
    for (int oc = 25; oc < 32; ++oc) xv[oc] = (_Float16)0.f;
    const int yy = pix >> 7, xx = pix & 127;
    _Float16* xp = xt + (((size_t)(b * 142 + yy + 7)) * 144 + (xx + 7)) * 32;
    #pragma unroll
    for (int i = 0; i < 4; ++i) ((float4*)xp)[i] = ((const float4*)xv)[i];
}

// ---------------- fused bn_out + avgpool2 + fc partial dot ----------------
__global__ __launch_bounds__(256) void fc1_kernel(
    const float* __restrict__ h, const float* __restrict__ scale,
    const float* __restrict__ shift, const float* __restrict__ fcw,
    float2* __restrict__ part)
{
    const int tid = threadIdx.x;
    const int i = blockIdx.x * 256 + tid;   // < 204800
    int px = i & 63;
    int t = i >> 6;
    int py = t & 63; t >>= 6;               // t = b*25 + c
    int c = t >= 25 ? t - 25 : t;
    const float* hp = h + ((size_t)t << 14);
    const int y0 = py << 1, xg = px << 1;
    float s = hp[(y0 << 7) + xg] + hp[(y0 << 7) + xg + 1]
            + hp[((y0 + 1) << 7) + xg] + hp[((y0 + 1) << 7) + xg + 1];
    const float o = 0.25f * s * scale[c] + shift[c];
    float p0 = o * fcw[i];
    float p1 = o * fcw[204800 + i];
    #pragma unroll
    for (int off = 32; off; off >>= 1) { p0 += __shfl_down(p0, off); p1 += __shfl_down(p1, off); }
    __shared__ float a0[4], a1[4];
    if ((tid & 63) == 0) { a0[tid >> 6] = p0; a1[tid >> 6] = p1; }
    __syncthreads();
    if (tid == 0)
        part[blockIdx.x] = make_float2(a0[0] + a0[1] + a0[2] + a0[3],
                                       a1[0] + a1[1] + a1[2] + a1[3]);
}

__global__ __launch_bounds__(256) void fc2_kernel(
    const float2* __restrict__ part, const float* __restrict__ fcb, float* __restrict__ out)
{
    const int tid = threadIdx.x;
    float s0 = 0.f, s1 = 0.f;
    for (int i = tid; i < 800; i += 256) { float2 v = part[i]; s0 += v.x; s1 += v.y; }
    #pragma unroll
    for (int off = 32; off; off >>= 1) { s0 += __shfl_down(s0, off); s1 += __shfl_down(s1, off); }
    __shared__ float a0[4], a1[4];
    if ((tid & 63) == 0) { a0[tid >> 6] = s0; a1[tid >> 6] = s1; }
    __syncthreads();
    if (tid == 0) {
        out[0] = sig_f(a0[0] + a0[1] + a0[2] + a0[3] + fcb[0]);
        out[1] = sig_f(a1[0] + a1[1] + a1[2] + a1[3] + fcb[1]);
    }
}

extern "C" void kernel_launch(void* const* d_in, const int* in_sizes, int n_in,
                              void* d_out, int out_size, void* d_ws, size_t ws_size,
                              hipStream_t stream)
{
    const float* x        = (const float*)d_in[0];
    const float* conv00_w = (const float*)d_in[1];
    const float* conv0_w  = (const float*)d_in[2];
    const float* conv1_w  = (const float*)d_in[3];
    const float* conv1_b  = (const float*)d_in[4];
    const float* u1_w     = (const float*)d_in[5];
    const float* u1_b     = (const float*)d_in[6];
    const float* u2_w     = (const float*)d_in[7];
    const float* u2_b     = (const float*)d_in[8];
    const float* w_inh    = (const float*)d_in[9];
    const float* w_exc    = (const float*)d_in[10];
    const float* alpha    = (const float*)d_in[11];
    const float* mu       = (const float*)d_in[12];
    const float* gamma_p  = (const float*)d_in[13];
    const float* kappa    = (const float*)d_in[14];
    const float* w_mix    = (const float*)d_in[15];
    const float* bn1_w    = (const float*)d_in[16];
    const float* bn1_b    = (const float*)d_in[17];
    const float* bn3_w    = (const float*)d_in[18];
    const float* bn3_b    = (const float*)d_in[19];
    const float* bn_out_w = (const float*)d_in[20];
    const float* bn_out_b = (const float*)d_in[21];
    const float* fc4_w    = (const float*)d_in[22];
    const float* fc4_b    = (const float*)d_in[23];

    float* ws = (float*)d_ws;
    // layout (float offsets):
    float* Y    = ws;                        // [0, 6,553,600): Y; B0p during front-end
    float* R    = ws + 6553600;              // [6.55M, 12.288M): 7 step buffers
    float* A    = ws + 6553600;              // front-end: conv00 out (6.55M, spills to 13.1072M)
    float* X0f  = ws + 13107200;             // X0: 1,166,848 f16 = 583,424 fl
    float* X1f  = ws + 13690624;             // X1: 583,424 f16 = 291,712 fl
    float* WT0f = ws + 13982336;             // 50,176 f16 = 25,088 fl
    float* WT1cf= ws + 14007424;             // 25,088 f16 = 12,544 fl
    float* WT1f = ws + 14019968;             // 230,400 f16 = 115,200 fl
    float* WT2f = ws + 14135168;             // 230,400 f16 = 115,200 fl
    float* XTf  = ws + 14250368;             // 1,308,672 f16 = 654,336 fl
    float* SC1  = ws + 14904704;
    float* SH1  = SC1 + 32;
    float* SC2  = SH1 + 32;
    float* SH2  = SC2 + 32;
    float* PART = SH2 + 32;

    float* B0p  = Y;                         // 25 partials x 262,144 = 6,553,600
    float* H    = R;
    float* NS1  = R + 1 * NELEM;
    float* G2   = R + 2 * NELEM;
    float* C1   = R + 3 * NELEM;             // pair
    float* C2   = R + 5 * NELEM;             // pair

    _Float16* X0  = (_Float16*)X0f;
    _Float16* X1  = (_Float16*)X1f;
    _Float16* WT0 = (_Float16*)WT0f;
    _Float16* WT1c= (_Float16*)WT1cf;
    _Float16* WT1 = (_Float16*)WT1f;
    _Float16* WT2 = (_Float16*)WT2f;
    _Float16* XT  = (_Float16*)XTf;

    // ---- front-end ----
    (void)hipMemsetAsync(X0, 0, (size_t)1166848 * sizeof(_Float16), stream);
    (void)hipMemsetAsync(X1, 0, (size_t)583424 * sizeof(_Float16), stream);
    (void)hipMemsetAsync(XT, 0, (size_t)1308672 * sizeof(_Float16), stream);
    xpack0_kernel<<<1024, 256, 0, stream>>>(x, X0);
    repack_w00_kernel<<<196, 256, 0, stream>>>(conv00_w, WT0);
    repack_w1_kernel<<<98, 256, 0, stream>>>(conv1_w, WT1c);
    repack_w_kernel<<<900, 256, 0, stream>>>(w_inh, WT1);
    repack_w_kernel<<<900, 256, 0, stream>>>(w_exc, WT2);

    conv3d00_mfma<<<2048, 128, 0, stream>>>(X0, WT0, A);
    conv3d7_kernel<25, 1, 25, 1, false><<<dim3(8, 25, 16), 128, 0, stream>>>(A, conv0_w, nullptr, B0p);
    xpack1_kernel<<<1024, 256, 0, stream>>>(B0p, X1);
    conv3d1_mfma<<<2048, 128, 0, stream>>>(X1, WT1c, conv1_b, Y);

    // ---- recurrence ----
    (void)hipMemsetAsync(H, 0, (size_t)NELEM * sizeof(float), stream);
    for (int t = 0; t < 8; ++t) {
        conv2d15_mfma<<<dim3(256, 2), 256, 0, stream>>>(XT, WT1, C1);
        bnstats_kernel<true><<<25, 1024, 0, stream>>>(C1, bn1_w, bn1_b, SC1, SH1);
        nsg_kernel<<<128, 256, 0, stream>>>(Y, H, C1, SC1, SH1, alpha, mu,
                                            u2_w, u2_b, NS1, G2, XT, t);
        conv2d15_mfma<<<dim3(256, 2), 256, 0, stream>>>(XT, WT2, C2);
        bnstats_kernel<true><<<25, 1024, 0, stream>>>(C2, bn3_w, bn3_b, SC2, SH2);
        hg_kernel<<<128, 256, 0, stream>>>(H, G2, NS1, C2, SC2, SH2,
                                           kappa, gamma_p, w_mix, u1_w, u1_b, XT);
    }

    // ---- head ----
    bnstats_kernel<false><<<25, 1024, 0, stream>>>(H, bn_out_w, bn_out_b, SC1, SH1);
    fc1_kernel<<<800, 256, 0, stream>>>(H, SC1, SH1, fc4_w, (float2*)PART);
    fc2_kernel<<<1, 256, 0, stream>>>((const float2*)PART, fc4_b, (float*)d_out);
}

// Round 6
// 1675.241 us; speedup vs baseline: 5.1270x; 1.0293x over previous
//
#include <hip/hip_runtime.h>
#include <cstddef>

#define HW 16384           // 128*128
#define NELEM 819200       // 2*25*HW

typedef _Float16 f16x8 __attribute__((ext_vector_type(8)));
typedef _Float16 f16x4 __attribute__((ext_vector_type(4)));
typedef float    f32x16 __attribute__((ext_vector_type(16)));

#define MFMA32(a, b, c) __builtin_amdgcn_mfma_f32_32x32x16_f16((a), (b), (c), 0, 0, 0)

__device__ __forceinline__ float sp_f(float x) {
    return fmaxf(x, 0.f) + log1pf(expf(-fabsf(x)));
}
__device__ __forceinline__ float sig_f(float x) {
    return 1.f / (1.f + expf(-x));
}

// ---------------- 3D conv 7x7x7 fp32 VALU (conv0: 25ch -> 1ch, ic-split) ----------------
template<int ICTOT, int ICG, int NICG, int OC, bool BIAS_SQ>
__global__ __launch_bounds__(128) void conv3d7_kernel(
    const float* __restrict__ in, const float* __restrict__ wgt,
    const float* __restrict__ bias, float* __restrict__ out)
{
    const int y0  = blockIdx.x * 16;
    const int by  = blockIdx.y;
    const int oc  = by / NICG;
    const int icg = by % NICG;
    const int b   = blockIdx.z >> 3;
    const int zo  = blockIdx.z & 7;

    __shared__ __align__(16) float lds[22 * 136];

    const int tid = threadIdx.x;
    const int tx  = tid & 15;
    const int ty  = tid >> 4;

    float acc0[8] = {0,0,0,0,0,0,0,0};
    float acc1[8] = {0,0,0,0,0,0,0,0};

    for (int ic = icg * ICG; ic < icg * ICG + ICG; ++ic) {
        for (int dz = 0; dz < 7; ++dz) {
            const int zin = zo + dz - 3;
            if (zin < 0 || zin >= 8) continue;
            __syncthreads();
            const float* src = in + (((size_t)((b * ICTOT + ic) * 8 + zin)) << 14);
            for (int idx = tid; idx < 22 * 134; idx += 128) {
                int r = idx / 134, c = idx - r * 134;
                int gy = y0 + r - 3, gx = c - 3;
                float v = 0.f;
                if ((unsigned)gy < 128u && (unsigned)gx < 128u) v = src[(gy << 7) + gx];
                lds[r * 136 + c] = v;
            }
            __syncthreads();

            const float* wbase = wgt + ((size_t)(oc * ICTOT + ic) * 7 + dz) * 49;
            const float* lrow  = &lds[(ty << 1) * 136 + (tx << 3)];
            float wn[7], wo[7];
            {
                float rr[16];
                #pragma unroll
                for (int i = 0; i < 4; ++i) ((float4*)rr)[i] = ((const float4*)lrow)[i];
                #pragma unroll
                for (int d = 0; d < 7; ++d) wn[d] = wbase[d];
                #pragma unroll
                for (int dx = 0; dx < 7; ++dx) {
                    float wv = wn[dx];
                    #pragma unroll
                    for (int k = 0; k < 8; ++k) acc0[k] += rr[dx + k] * wv;
                }
                #pragma unroll
                for (int d = 0; d < 7; ++d) wo[d] = wn[d];
            }
            #pragma unroll
            for (int j = 1; j <= 6; ++j) {
                float rr[16];
                const float* lp = lrow + j * 136;
                #pragma unroll
                for (int i = 0; i < 4; ++i) ((float4*)rr)[i] = ((const float4*)lp)[i];
                #pragma unroll
                for (int d = 0; d < 7; ++d) wn[d] = wbase[j * 7 + d];
                #pragma unroll
                for (int dx = 0; dx < 7; ++dx) {
                    float w0 = wn[dx], w1 = wo[dx];
                    #pragma unroll
                    for (int k = 0; k < 8; ++k) {
                        acc0[k] += rr[dx + k] * w0;
                        acc1[k] += rr[dx + k] * w1;
                    }
                }
                #pragma unroll
                for (int d = 0; d < 7; ++d) wo[d] = wn[d];
            }
            {
                float rr[16];
                const float* lp = lrow + 7 * 136;
                #pragma unroll
                for (int i = 0; i < 4; ++i) ((float4*)rr)[i] = ((const float4*)lp)[i];
                #pragma unroll
                for (int dx = 0; dx < 7; ++dx) {
                    float wv = wo[dx];
                    #pragma unroll
                    for (int k = 0; k < 8; ++k) acc1[k] += rr[dx + k] * wv;
                }
            }
        }
    }
    if (BIAS_SQ) {
        float bv = bias[oc];
        #pragma unroll
        for (int k = 0; k < 8; ++k) {
            acc0[k] += bv; acc0[k] *= acc0[k];
            acc1[k] += bv; acc1[k] *= acc1[k];
        }
    }
    const int oy = y0 + (ty << 1), ox = tx << 3;
    float* op = out + (size_t)icg * (2 * OC * 8 * HW)
              + (((size_t)((b * OC + oc) * 8 + zo)) << 14) + (oy << 7) + ox;
    *(float4*)op         = make_float4(acc0[0], acc0[1], acc0[2], acc0[3]);
    *(float4*)(op + 4)   = make_float4(acc0[4], acc0[5], acc0[6], acc0[7]);
    *(float4*)(op + 128) = make_float4(acc1[0], acc1[1], acc1[2], acc1[3]);
    *(float4*)(op + 132) = make_float4(acc1[4], acc1[5], acc1[6], acc1[7]);
}

// ---------------- front-end prepack kernels ----------------
__global__ __launch_bounds__(256) void xpack0_kernel(
    const float* __restrict__ x, _Float16* __restrict__ x0)
{
    const int p = blockIdx.x * 256 + threadIdx.x;   // < 262144
    const int b = p >> 17, rem = p & 131071;
    const int z = rem >> 14, pix = rem & 16383;
    const int y = pix >> 7, xx = pix & 127;
    const size_t sb = ((size_t)b * 3 * 8 + z) << 14;
    f16x4 v;
    v[0] = (_Float16)x[sb + pix];
    v[1] = (_Float16)x[sb + (8ull << 14) + pix];
    v[2] = (_Float16)x[sb + (16ull << 14) + pix];
    v[3] = (_Float16)0.f;
    *(f16x4*)(x0 + (((size_t)(b * 8 + z) * 134 + y + 3) * 136 + xx + 3) * 4) = v;
}

__global__ __launch_bounds__(256) void repack_w00_kernel(
    const float* __restrict__ w, _Float16* __restrict__ wt)
{
    const int idx = blockIdx.x * 256 + threadIdx.x;   // < 50176
    const int j  = idx & 7;
    const int m  = (idx >> 3) & 31;
    const int h  = (idx >> 8) & 1;
    const int kk = (idx >> 9) & 1;
    const int tapb = idx >> 10;                       // dz*7+dy, < 49
    const int dz = tapb / 7, dy = tapb - dz * 7;
    const int ic = j & 3, dxl = j >> 2;
    const int dx = kk * 4 + h * 2 + dxl;
    float v = 0.f;
    if (m < 25 && ic < 3 && dx < 7)
        v = w[(((m * 3 + ic) * 7 + dz) * 7 + dy) * 7 + dx];
    wt[idx] = (_Float16)v;
}

__global__ __launch_bounds__(256) void xpack1_kernel(
    const float* __restrict__ b0p, _Float16* __restrict__ x1)
{
    const int p = blockIdx.x * 256 + threadIdx.x;   // < 262144
    const int b = p >> 17, rem = p & 131071;
    const int z = rem >> 14, pix = rem & 16383;
    const int y = pix >> 7, xx = pix & 127;
    float s = 0.f;
    #pragma unroll
    for (int g = 0; g < 25; ++g) s += b0p[(size_t)g * 262144 + p];
    x1[(((size_t)(b * 8 + z) * 134 + y + 3) * 136 + xx + 3) * 2] = (_Float16)s;
}

__global__ __launch_bounds__(256) void repack_w1_kernel(
    const float* __restrict__ w, _Float16* __restrict__ wt)
{
    const int idx = blockIdx.x * 256 + threadIdx.x;   // < 25088
    const int j = idx & 7;
    const int m = (idx >> 3) & 31;
    const int h = (idx >> 8) & 1;
    const int tapb = idx >> 9;                        // < 49
    const int dz = tapb / 7, dy = tapb - dz * 7;
    const int c2 = j & 1, dx = h * 4 + (j >> 1);
    float v = 0.f;
    if (m < 25 && c2 == 0 && dx < 7)
        v = w[((m * 7 + dz) * 7 + dy) * 7 + dx];
    wt[idx] = (_Float16)v;
}

// ---------------- conv00 via MFMA: 3ch -> 25ch ----------------
__global__ __launch_bounds__(128) void conv3d00_mfma(
    const _Float16* __restrict__ x0, const _Float16* __restrict__ wt0,
    float* __restrict__ out)
{
    const int g = blockIdx.x;
    const int b = g >> 10;
    const int zo = (g >> 7) & 7;
    const int y = g & 127;
    const int tid = threadIdx.x;
    const int wv = tid >> 6;
    const int lane = tid & 63;
    const int n = lane & 31;
    const int h = lane >> 5;
    const int xc = wv << 6;

    f32x16 acc0, acc1;
    #pragma unroll
    for (int i = 0; i < 16; ++i) { acc0[i] = 0.f; acc1[i] = 0.f; }

    for (int dz = 0; dz < 7; ++dz) {
        const int zin = zo + dz - 3;
        if (zin < 0 || zin >= 8) continue;
        const _Float16* xpl = x0 + (size_t)(b * 8 + zin) * (134 * 136 * 4);
        #pragma unroll
        for (int dy = 0; dy < 7; ++dy) {
            const _Float16* xr = xpl + (size_t)(y + dy) * (136 * 4);
            const _Float16* wb = wt0 + (size_t)((dz * 7 + dy) * 2) * 512 + h * 256 + n * 8;
            f16x8 a0 = *(const f16x8*)(wb);
            f16x8 a1 = *(const f16x8*)(wb + 512);
            const _Float16* bp = xr + (size_t)(xc + n + 2 * h) * 4;
            f16x8 b00 = *(const f16x8*)(bp);
            f16x8 b01 = *(const f16x8*)(bp + 16);
            f16x8 b10 = *(const f16x8*)(bp + 128);
            f16x8 b11 = *(const f16x8*)(bp + 144);
            acc0 = MFMA32(a0, b00, acc0);
            acc1 = MFMA32(a0, b10, acc1);
            acc0 = MFMA32(a1, b01, acc0);
            acc1 = MFMA32(a1, b11, acc1);
        }
    }
    float* ob = out + ((((size_t)b * 25) * 8 + zo) << 14) + (y << 7) + xc + n;
    #pragma unroll
    for (int r = 0; r < 16; ++r) {
        const int row = (r & 3) + 8 * (r >> 2) + 4 * h;
        if (row < 25) {
            ob[(size_t)row * 131072]      = acc0[r];
            ob[(size_t)row * 131072 + 32] = acc1[r];
        }
    }
}

// ---------------- conv1 via MFMA: 1ch -> 25ch, bias+square fused ----------------
__global__ __launch_bounds__(128) void conv3d1_mfma(
    const _Float16* __restrict__ x1, const _Float16* __restrict__ wt1,
    const float* __restrict__ bias, float* __restrict__ out)
{
    const int g = blockIdx.x;
    const int b = g >> 10;
    const int zo = (g >> 7) & 7;
    const int y = g & 127;
    const int tid = threadIdx.x;
    const int wv = tid >> 6;
    const int lane = tid & 63;
    const int n = lane & 31;
    const int h = lane >> 5;
    const int xc = wv << 6;

    f32x16 acc0, acc1;
    #pragma unroll
    for (int i = 0; i < 16; ++i) { acc0[i] = 0.f; acc1[i] = 0.f; }

    for (int dz = 0; dz < 7; ++dz) {
        const int zin = zo + dz - 3;
        if (zin < 0 || zin >= 8) continue;
        const _Float16* xpl = x1 + (size_t)(b * 8 + zin) * (134 * 136 * 2);
        #pragma unroll
        for (int dy = 0; dy < 7; ++dy) {
            const _Float16* wb = wt1 + (size_t)(dz * 7 + dy) * 512 + h * 256 + n * 8;
            f16x8 a0 = *(const f16x8*)(wb);
            const _Float16* bp = xpl + ((size_t)(y + dy) * 136 + xc + n) * 2 + h * 8;
            f16x8 b0 = *(const f16x8*)(bp);
            f16x8 b1 = *(const f16x8*)(bp + 64);
            acc0 = MFMA32(a0, b0, acc0);
            acc1 = MFMA32(a0, b1, acc1);
        }
    }
    float* ob = out + ((((size_t)b * 25) * 8 + zo) << 14) + (y << 7) + xc + n;
    #pragma unroll
    for (int r = 0; r < 16; ++r) {
        const int row = (r & 3) + 8 * (r >> 2) + 4 * h;
        if (row < 25) {
            float v0 = acc0[r] + bias[row];
            float v1 = acc1[r] + bias[row];
            ob[(size_t)row * 131072]      = v0 * v0;
            ob[(size_t)row * 131072 + 32] = v1 * v1;
        }
    }
}

// ---------------- weight repack for 15x15 (A-frag) ----------------
__global__ __launch_bounds__(256) void repack_w_kernel(
    const float* __restrict__ w, _Float16* __restrict__ wt)
{
    const int idx = blockIdx.x * 256 + threadIdx.x;   // < 230400
    const int j    = idx & 7;
    const int m    = (idx >> 3) & 31;
    const int half = (idx >> 8) & 1;
    const int ks   = (idx >> 9) & 1;
    const int t    = idx >> 10;                       // < 225
    const int ic   = ks * 16 + half * 8 + j;
    float v = 0.f;
    if (m < 25 && ic < 25) v = w[(m * 25 + ic) * 225 + t];
    wt[idx] = (_Float16)v;
}

// ---------------- 2D conv 15x15 via MFMA, A-reuse over row pairs ----------------
// 256 thr = 4 waves x 32 px. Wave computes 2 output rows (y0, y0+1):
// at k-step ky', B-row XT[y0+ky'] feeds row y0 with A(ky') and row y0+1 with
// A(ky'-1) held in registers -> per-row load count halves.
// grid: x = b*64 + rowpair (0..127), y = kg (kx 0-7 / 8-14) -> partial at kg*NELEM.
__global__ __launch_bounds__(256) void conv2d15_mfma(
    const _Float16* __restrict__ xt, const _Float16* __restrict__ wt,
    float* __restrict__ out)
{
    const int blk = blockIdx.x;
    const int b   = blk >> 6;
    const int y0  = (blk & 63) << 1;
    const int kg  = blockIdx.y;
    const int kx0 = kg ? 8 : 0;
    const int kx1 = kg ? 15 : 8;

    const int tid  = threadIdx.x;
    const int wv   = tid >> 6;
    const int lane = tid & 63;
    const int n    = lane & 31;
    const int half = lane >> 5;
    const int xc   = wv << 5;

    f32x16 acc0, acc1;
    #pragma unroll
    for (int i = 0; i < 16; ++i) { acc0[i] = 0.f; acc1[i] = 0.f; }

    // lane's B base: row y0, px (xc+n), ch half*8; row stride 144*32=4608 f16
    const _Float16* xbase = xt + (((size_t)(b * 142 + y0) * 144 + xc + n) * 32) + half * 8;

    for (int kx = kx0; kx < kx1; ++kx) {
        const _Float16* bp = xbase + kx * 32;
        const _Float16* wp = wt + (size_t)kx * 1024 + half * 256 + n * 8;  // ky stride 15360
        f16x8 ap0, ap1;
        #pragma unroll
        for (int kyp = 0; kyp < 16; ++kyp) {
            f16x8 b0 = *(const f16x8*)(bp + (size_t)kyp * 4608);
            f16x8 b1 = *(const f16x8*)(bp + (size_t)kyp * 4608 + 16);
            f16x8 an0, an1;
            if (kyp <= 14) {
                an0 = *(const f16x8*)(wp + (size_t)kyp * 15360);
                an1 = *(const f16x8*)(wp + (size_t)kyp * 15360 + 512);
                acc0 = MFMA32(an0, b0, acc0);
                acc0 = MFMA32(an1, b1, acc0);
            }
            if (kyp >= 1) {
                acc1 = MFMA32(ap0, b0, acc1);
                acc1 = MFMA32(ap1, b1, acc1);
            }
            ap0 = an0; ap1 = an1;
        }
    }
    float* ob = out + (size_t)kg * NELEM + (((size_t)b * 25) << 14) + (y0 << 7) + xc + n;
    #pragma unroll
    for (int r = 0; r < 16; ++r) {
        const int oc = (r & 3) + 8 * (r >> 2) + 4 * half;
        if (oc < 25) {
            ob[(size_t)oc << 14]         = acc0[r];   // row y0
            ob[((size_t)oc << 14) + 128] = acc1[r];   // row y0+1
        }
    }
}

// ---------------- BN batch-stats, 2-stage ----------------
template<bool PAIR>
__global__ __launch_bounds__(256) void bnstats1_kernel(
    const float* __restrict__ x, float2* __restrict__ ps)
{
    const int c = blockIdx.x;     // 25
    const int s = blockIdx.y;     // 8
    const int tid = threadIdx.x;
    const float4* p0 = (const float4*)(x + ((size_t)c << 14)) + s * 512;
    const float4* p1 = (const float4*)(x + ((size_t)(25 + c) << 14)) + s * 512;
    const float4* q0 = (const float4*)(x + NELEM + ((size_t)c << 14)) + s * 512;
    const float4* q1 = (const float4*)(x + NELEM + ((size_t)(25 + c) << 14)) + s * 512;
    float s1 = 0.f, s2 = 0.f;
    #pragma unroll
    for (int i = 0; i < 2; ++i) {
        const int idx = tid + i * 256;
        float4 v = p0[idx];
        if (PAIR) { float4 w = q0[idx]; v.x += w.x; v.y += w.y; v.z += w.z; v.w += w.w; }
        s1 += v.x + v.y + v.z + v.w;
        s2 += v.x * v.x + v.y * v.y + v.z * v.z + v.w * v.w;
        float4 u = p1[idx];
        if (PAIR) { float4 w = q1[idx]; u.x += w.x; u.y += w.y; u.z += w.z; u.w += w.w; }
        s1 += u.x + u.y + u.z + u.w;
        s2 += u.x * u.x + u.y * u.y + u.z * u.z + u.w * u.w;
    }
    #pragma unroll
    for (int off = 32; off; off >>= 1) { s1 += __shfl_down(s1, off); s2 += __shfl_down(s2, off); }
    __shared__ float a1[4], a2[4];
    if ((tid & 63) == 0) { a1[tid >> 6] = s1; a2[tid >> 6] = s2; }
    __syncthreads();
    if (tid == 0)
        ps[c * 8 + s] = make_float2(a1[0] + a1[1] + a1[2] + a1[3],
                                    a2[0] + a2[1] + a2[2] + a2[3]);
}

__global__ __launch_bounds__(64) void bnstats2_kernel(
    const float2* __restrict__ ps, const float* __restrict__ gw,
    const float* __restrict__ gb, float* __restrict__ scale, float* __restrict__ shift)
{
    const int c = threadIdx.x;
    if (c < 25) {
        float s1 = 0.f, s2 = 0.f;
        #pragma unroll
        for (int s = 0; s < 8; ++s) { float2 v = ps[c * 8 + s]; s1 += v.x; s2 += v.y; }
        const float m = s1 * (1.f / 32768.f);
        const float var = fmaxf(s2 * (1.f / 32768.f) - m * m, 0.f);
        const float sc = gw[c] * rsqrtf(var + 1e-3f);
        scale[c] = sc;
        shift[c] = gb[c] - m * sc;
    }
}

// ---------------- fused ns1: NS1, XT = f16(ns1) ----------------
__global__ __launch_bounds__(256) void nsg_kernel(
    const float* __restrict__ y, const float* __restrict__ h,
    const float* __restrict__ c1, const float* __restrict__ scale,
    const float* __restrict__ shift, const float* __restrict__ alpha,
    const float* __restrict__ mu, float* __restrict__ ns1,
    _Float16* __restrict__ xt, int t)
{
    const int p = blockIdx.x * 256 + threadIdx.x;   // < 32768
    const int b = p >> 14, pix = p & (HW - 1);
    const size_t base = (((size_t)b * 25) << 14) + pix;
    __align__(16) _Float16 xv[32];
    #pragma unroll
    for (int c = 0; c < 25; ++c) {
        const size_t idx = base + ((size_t)c << 14);
        const float yv = y[(((size_t)(b * 25 + c) * 8 + t) << 14) + pix];
        const float c1v = c1[idx] + c1[NELEM + idx];
        const float c1n = c1v * scale[c] + shift[c];
        const float pre = c1n * (alpha[c] * h[idx] + mu[c]);
        const float n = sp_f(yv - sp_f(pre));
        ns1[idx] = n;
        xv[c] = (_Float16)n;
    }
    #pragma unroll
    for (int c = 25; c < 32; ++c) xv[c] = (_Float16)0.f;
    const int yy = pix >> 7, xx = pix & 127;
    _Float16* xp = xt + (((size_t)(b * 142 + yy + 7)) * 144 + (xx + 7)) * 32;
    #pragma unroll
    for (int i = 0; i < 4; ++i) ((float4*)xp)[i] = ((const float4*)xv)[i];
}

// ---------------- fused hnew + both gates: H, XT = f16(h*g1) ----------------
__global__ __launch_bounds__(256) void hg_kernel(
    float* __restrict__ h, const float* __restrict__ ns1,
    const float* __restrict__ c2, const float* __restrict__ scale,
    const float* __restrict__ shift, const float* __restrict__ kappa,
    const float* __restrict__ gp, const float* __restrict__ wmix,
    const float* __restrict__ u1w, const float* __restrict__ u1b,
    const float* __restrict__ u2w, const float* __restrict__ u2b,
    _Float16* __restrict__ xt)
{
    const int p = blockIdx.x * 256 + threadIdx.x;   // < 32768
    const int b = p >> 14, pix = p & (HW - 1);
    const size_t base = (((size_t)b * 25) << 14) + pix;
    float nv[25];
    #pragma unroll
    for (int c = 0; c < 25; ++c) nv[c] = ns1[base + ((size_t)c << 14)];
    float g2v[25];
    #pragma unroll
    for (int oc = 0; oc < 25; ++oc) {
        float acc = u2b[oc];
        #pragma unroll
        for (int ic = 0; ic < 25; ++ic) acc += u2w[oc * 25 + ic] * nv[ic];
        g2v[oc] = sig_f(acc);
    }
    float hv[25];
    #pragma unroll
    for (int c = 0; c < 25; ++c) {
        const size_t idx = base + ((size_t)c << 14);
        const float c2v = c2[idx] + c2[NELEM + idx];
        const float c2n = c2v * scale[c] + shift[c];
        const float n = nv[c];
        const float h2 = sp_f(kappa[c] * n + gp[c] * c2n + wmix[c] * n * c2n);
        const float g = g2v[c];
        const float hn = sp_f((1.f - g) * h[idx] + g * h2);
        hv[c] = hn;
        h[idx] = hn;
    }
    __align__(16) _Float16 xv[32];
    #pragma unroll
    for (int oc = 0; oc < 25; ++oc) {
        float acc = u1b[oc];
        #pragma unroll
        for (int ic = 0; ic < 25; ++ic) acc += u1w[oc * 25 + ic] * hv[ic];
        xv[oc] = (_Float16)(hv[oc] * sig_f(acc));
    }
    #pragma unroll
    for (int oc = 25; oc < 32; ++oc) xv[oc] = (_Float16)0.f;
    const int yy = pix >> 7, xx = pix & 127;
    _Float16* xp = xt + (((size_t)(b * 142 + yy + 7)) * 144 + (xx + 7)) * 32;
    #pragma unroll
    for (int i = 0; i < 4; ++i) ((float4*)xp)[i] = ((const float4*)xv)[i];
}

// ---------------- fused bn_out + avgpool2 + fc partial dot ----------------
__global__ __launch_bounds__(256) void fc1_kernel(
    const float* __restrict__ h, const float* __restrict__ scale,
    const float* __restrict__ shift, const float* __restrict__ fcw,
    float2* __restrict__ part)
{
    const int tid = threadIdx.x;
    const int i = blockIdx.x * 256 + tid;   // < 204800
    int px = i & 63;
    int t = i >> 6;
    int py = t & 63; t >>= 6;               // t = b*25 + c
    int c = t >= 25 ? t - 25 : t;
    const float* hp = h + ((size_t)t << 14);
    const int y0 = py << 1, xg = px << 1;
    float s = hp[(y0 << 7) + xg] + hp[(y0 << 7) + xg + 1]
            + hp[((y0 + 1) << 7) + xg] + hp[((y0 + 1) << 7) + xg + 1];
    const float o = 0.25f * s * scale[c] + shift[c];
    float p0 = o * fcw[i];
    float p1 = o * fcw[204800 + i];
    #pragma unroll
    for (int off = 32; off; off >>= 1) { p0 += __shfl_down(p0, off); p1 += __shfl_down(p1, off); }
    __shared__ float a0[4], a1[4];
    if ((tid & 63) == 0) { a0[tid >> 6] = p0; a1[tid >> 6] = p1; }
    __syncthreads();
    if (tid == 0)
        part[blockIdx.x] = make_float2(a0[0] + a0[1] + a0[2] + a0[3],
                                       a1[0] + a1[1] + a1[2] + a1[3]);
}

__global__ __launch_bounds__(256) void fc2_kernel(
    const float2* __restrict__ part, const float* __restrict__ fcb, float* __restrict__ out)
{
    const int tid = threadIdx.x;
    float s0 = 0.f, s1 = 0.f;
    for (int i = tid; i < 800; i += 256) { float2 v = part[i]; s0 += v.x; s1 += v.y; }
    #pragma unroll
    for (int off = 32; off; off >>= 1) { s0 += __shfl_down(s0, off); s1 += __shfl_down(s1, off); }
    __shared__ float a0[4], a1[4];
    if ((tid & 63) == 0) { a0[tid >> 6] = s0; a1[tid >> 6] = s1; }
    __syncthreads();
    if (tid == 0) {
        out[0] = sig_f(a0[0] + a0[1] + a0[2] + a0[3] + fcb[0]);
        out[1] = sig_f(a1[0] + a1[1] + a1[2] + a1[3] + fcb[1]);
    }
}

extern "C" void kernel_launch(void* const* d_in, const int* in_sizes, int n_in,
                              void* d_out, int out_size, void* d_ws, size_t ws_size,
                              hipStream_t stream)
{
    const float* x        = (const float*)d_in[0];
    const float* conv00_w = (const float*)d_in[1];
    const float* conv0_w  = (const float*)d_in[2];
    const float* conv1_w  = (const float*)d_in[3];
    const float* conv1_b  = (const float*)d_in[4];
    const float* u1_w     = (const float*)d_in[5];
    const float* u1_b     = (const float*)d_in[6];
    const float* u2_w     = (const float*)d_in[7];
    const float* u2_b     = (const float*)d_in[8];
    const float* w_inh    = (const float*)d_in[9];
    const float* w_exc    = (const float*)d_in[10];
    const float* alpha    = (const float*)d_in[11];
    const float* mu       = (const float*)d_in[12];
    const float* gamma_p  = (const float*)d_in[13];
    const float* kappa    = (const float*)d_in[14];
    const float* w_mix    = (const float*)d_in[15];
    const float* bn1_w    = (const float*)d_in[16];
    const float* bn1_b    = (const float*)d_in[17];
    const float* bn3_w    = (const float*)d_in[18];
    const float* bn3_b    = (const float*)d_in[19];
    const float* bn_out_w = (const float*)d_in[20];
    const float* bn_out_b = (const float*)d_in[21];
    const float* fc4_w    = (const float*)d_in[22];
    const float* fc4_b    = (const float*)d_in[23];

    float* ws = (float*)d_ws;
    // layout (float offsets):
    float* Y    = ws;                        // [0, 6,553,600): Y; conv0 partials early
    float* R    = ws + 6553600;              // 6 step buffers (4,915,200)
    float* A    = ws + 6553600;              // front-end: conv00 out (ends 13,107,200)
    float* X0f  = ws + 13107200;             // X0: 583,424 fl
    float* X1f  = ws + 13690624;             // X1: 291,712 fl
    float* WT0f = ws + 13982336;             // 25,088 fl
    float* WT1cf= ws + 14007424;             // 12,544 fl
    float* WT1f = ws + 14019968;             // 115,200 fl
    float* WT2f = ws + 14135168;             // 115,200 fl
    float* XTf  = ws + 14250368;             // 654,336 fl
    float* SC1  = ws + 14904704;
    float* SH1  = SC1 + 32;
    float* SC2  = SH1 + 32;
    float* SH2  = SC2 + 32;
    float* PART = SH2 + 32;                  // 1600 (800 x float2)
    float* PS   = PART + 1600;               // 400 (200 x float2)

    float* B0p  = Y;                         // 25 partials x 262,144
    float* H    = R;
    float* NS1  = R + 1 * NELEM;
    float* C1   = R + 2 * NELEM;             // pair
    float* C2   = R + 4 * NELEM;             // pair

    _Float16* X0  = (_Float16*)X0f;
    _Float16* X1  = (_Float16*)X1f;
    _Float16* WT0 = (_Float16*)WT0f;
    _Float16* WT1c= (_Float16*)WT1cf;
    _Float16* WT1 = (_Float16*)WT1f;
    _Float16* WT2 = (_Float16*)WT2f;
    _Float16* XT  = (_Float16*)XTf;

    // ---- front-end ----
    (void)hipMemsetAsync(X0, 0, (size_t)1166848 * sizeof(_Float16), stream);
    (void)hipMemsetAsync(X1, 0, (size_t)583424 * sizeof(_Float16), stream);
    (void)hipMemsetAsync(XT, 0, (size_t)1308672 * sizeof(_Float16), stream);
    xpack0_kernel<<<1024, 256, 0, stream>>>(x, X0);
    repack_w00_kernel<<<196, 256, 0, stream>>>(conv00_w, WT0);
    repack_w1_kernel<<<98, 256, 0, stream>>>(conv1_w, WT1c);
    repack_w_kernel<<<900, 256, 0, stream>>>(w_inh, WT1);
    repack_w_kernel<<<900, 256, 0, stream>>>(w_exc, WT2);

    conv3d00_mfma<<<2048, 128, 0, stream>>>(X0, WT0, A);
    conv3d7_kernel<25, 1, 25, 1, false><<<dim3(8, 25, 16), 128, 0, stream>>>(A, conv0_w, nullptr, B0p);
    xpack1_kernel<<<1024, 256, 0, stream>>>(B0p, X1);
    conv3d1_mfma<<<2048, 128, 0, stream>>>(X1, WT1c, conv1_b, Y);

    // ---- recurrence ----
    (void)hipMemsetAsync(H, 0, (size_t)NELEM * sizeof(float), stream);
    for (int t = 0; t < 8; ++t) {
        conv2d15_mfma<<<dim3(128, 2), 256, 0, stream>>>(XT, WT1, C1);
        bnstats1_kernel<true><<<dim3(25, 8), 256, 0, stream>>>(C1, (float2*)PS);
        bnstats2_kernel<<<1, 64, 0, stream>>>((const float2*)PS, bn1_w, bn1_b, SC1, SH1);
        nsg_kernel<<<128, 256, 0, stream>>>(Y, H, C1, SC1, SH1, alpha, mu, NS1, XT, t);
        conv2d15_mfma<<<dim3(128, 2), 256, 0, stream>>>(XT, WT2, C2);
        bnstats1_kernel<true><<<dim3(25, 8), 256, 0, stream>>>(C2, (float2*)PS);
        bnstats2_kernel<<<1, 64, 0, stream>>>((const float2*)PS, bn3_w, bn3_b, SC2, SH2);
        hg_kernel<<<128, 256, 0, stream>>>(H, NS1, C2, SC2, SH2,
                                           kappa, gamma_p, w_mix, u1_w, u1_b, u2_w, u2_b, XT);
    }

    // ---- head ----
    bnstats1_kernel<false><<<dim3(25, 8), 256, 0, stream>>>(H, (float2*)PS);
    bnstats2_kernel<<<1, 64, 0, stream>>>((const float2*)PS, bn_out_w, bn_out_b, SC1, SH1);
    fc1_kernel<<<800, 256, 0, stream>>>(H, SC1, SH1, fc4_w, (float2*)PART);
    fc2_kernel<<<1, 256, 0, stream>>>((const float2*)PART, fc4_b, (float*)d_out);
}

// Round 7
// 1535.300 us; speedup vs baseline: 5.5944x; 1.0911x over previous
//
#include <hip/hip_runtime.h>
#include <cstddef>

#define HW 16384           // 128*128
#define NELEM 819200       // 2*25*HW

typedef _Float16 f16x8 __attribute__((ext_vector_type(8)));
typedef _Float16 f16x4 __attribute__((ext_vector_type(4)));
typedef float    f32x16 __attribute__((ext_vector_type(16)));

#define MFMA32(a, b, c) __builtin_amdgcn_mfma_f32_32x32x16_f16((a), (b), (c), 0, 0, 0)

__device__ __forceinline__ float sp_f(float x) {
    return fmaxf(x, 0.f) + log1pf(expf(-fabsf(x)));
}
__device__ __forceinline__ float sig_f(float x) {
    return 1.f / (1.f + expf(-x));
}

// ---------------- front-end prepack kernels ----------------
__global__ __launch_bounds__(256) void xpack0_kernel(
    const float* __restrict__ x, _Float16* __restrict__ x0)
{
    const int p = blockIdx.x * 256 + threadIdx.x;   // < 262144
    const int b = p >> 17, rem = p & 131071;
    const int z = rem >> 14, pix = rem & 16383;
    const int y = pix >> 7, xx = pix & 127;
    const size_t sb = ((size_t)b * 3 * 8 + z) << 14;
    f16x4 v;
    v[0] = (_Float16)x[sb + pix];
    v[1] = (_Float16)x[sb + (8ull << 14) + pix];
    v[2] = (_Float16)x[sb + (16ull << 14) + pix];
    v[3] = (_Float16)0.f;
    *(f16x4*)(x0 + (((size_t)(b * 8 + z) * 134 + y + 3) * 136 + xx + 3) * 4) = v;
}

__global__ __launch_bounds__(256) void repack_w00_kernel(
    const float* __restrict__ w, _Float16* __restrict__ wt)
{
    const int idx = blockIdx.x * 256 + threadIdx.x;   // < 50176
    const int j  = idx & 7;
    const int m  = (idx >> 3) & 31;
    const int h  = (idx >> 8) & 1;
    const int kk = (idx >> 9) & 1;
    const int tapb = idx >> 10;                       // dz*7+dy, < 49
    const int dz = tapb / 7, dy = tapb - dz * 7;
    const int ic = j & 3, dxl = j >> 2;
    const int dx = kk * 4 + h * 2 + dxl;
    float v = 0.f;
    if (m < 25 && ic < 3 && dx < 7)
        v = w[(((m * 3 + ic) * 7 + dz) * 7 + dy) * 7 + dx];
    wt[idx] = (_Float16)v;
}

__global__ __launch_bounds__(256) void xpack1_kernel(
    const float* __restrict__ b0p, _Float16* __restrict__ x1)
{
    const int p = blockIdx.x * 256 + threadIdx.x;   // < 262144
    const int b = p >> 17, rem = p & 131071;
    const int z = rem >> 14, pix = rem & 16383;
    const int y = pix >> 7, xx = pix & 127;
    float s = 0.f;
    #pragma unroll
    for (int g = 0; g < 25; ++g) s += b0p[(size_t)g * 262144 + p];
    x1[(((size_t)(b * 8 + z) * 134 + y + 3) * 136 + xx + 3) * 2] = (_Float16)s;
}

__global__ __launch_bounds__(256) void repack_w1_kernel(
    const float* __restrict__ w, _Float16* __restrict__ wt)
{
    const int idx = blockIdx.x * 256 + threadIdx.x;   // < 25088
    const int j = idx & 7;
    const int m = (idx >> 3) & 31;
    const int h = (idx >> 8) & 1;
    const int tapb = idx >> 9;                        // < 49
    const int dz = tapb / 7, dy = tapb - dz * 7;
    const int c2 = j & 1, dx = h * 4 + (j >> 1);
    float v = 0.f;
    if (m < 25 && c2 == 0 && dx < 7)
        v = w[((m * 7 + dz) * 7 + dy) * 7 + dx];
    wt[idx] = (_Float16)v;
}

// ---------------- conv00 via MFMA: 3ch -> 25ch ----------------
// Epilogue writes halo-4-padded f16 planes APAD[2*25][8][136][136] (pre-zeroed).
__global__ __launch_bounds__(128) void conv3d00_mfma(
    const _Float16* __restrict__ x0, const _Float16* __restrict__ wt0,
    _Float16* __restrict__ apad)
{
    const int g = blockIdx.x;
    const int b = g >> 10;
    const int zo = (g >> 7) & 7;
    const int y = g & 127;
    const int tid = threadIdx.x;
    const int wv = tid >> 6;
    const int lane = tid & 63;
    const int n = lane & 31;
    const int h = lane >> 5;
    const int xc = wv << 6;

    f32x16 acc0, acc1;
    #pragma unroll
    for (int i = 0; i < 16; ++i) { acc0[i] = 0.f; acc1[i] = 0.f; }

    for (int dz = 0; dz < 7; ++dz) {
        const int zin = zo + dz - 3;
        if (zin < 0 || zin >= 8) continue;
        const _Float16* xpl = x0 + (size_t)(b * 8 + zin) * (134 * 136 * 4);
        #pragma unroll
        for (int dy = 0; dy < 7; ++dy) {
            const _Float16* xr = xpl + (size_t)(y + dy) * (136 * 4);
            const _Float16* wb = wt0 + (size_t)((dz * 7 + dy) * 2) * 512 + h * 256 + n * 8;
            f16x8 a0 = *(const f16x8*)(wb);
            f16x8 a1 = *(const f16x8*)(wb + 512);
            const _Float16* bp = xr + (size_t)(xc + n + 2 * h) * 4;
            f16x8 b00 = *(const f16x8*)(bp);
            f16x8 b01 = *(const f16x8*)(bp + 16);
            f16x8 b10 = *(const f16x8*)(bp + 128);
            f16x8 b11 = *(const f16x8*)(bp + 144);
            acc0 = MFMA32(a0, b00, acc0);
            acc1 = MFMA32(a0, b10, acc1);
            acc0 = MFMA32(a1, b01, acc0);
            acc1 = MFMA32(a1, b11, acc1);
        }
    }
    // padded plane write: plane stride 136*136=18496, oc-stride 8*18496=147968
    _Float16* ob = apad + (size_t)((b * 25) * 8 + zo) * 18496
                 + (size_t)(y + 4) * 136 + 4 + xc + n;
    #pragma unroll
    for (int r = 0; r < 16; ++r) {
        const int row = (r & 3) + 8 * (r >> 2) + 4 * h;
        if (row < 25) {
            ob[(size_t)row * 147968]      = (_Float16)acc0[r];
            ob[(size_t)row * 147968 + 32] = (_Float16)acc1[r];
        }
    }
}

// ---------------- conv0: 25ch -> 1ch, direct-global f16 reads, fp32 acc ----------------
// No LDS, no barriers, no bounds checks (halo-padded input).
// grid: (8 ytiles, 25 ic, b*8+zo), 128 thr; thread = 8 cols x 2 rows.
__global__ __launch_bounds__(128) void conv3d0_direct(
    const _Float16* __restrict__ apad, const float* __restrict__ wgt,
    float* __restrict__ out)
{
    const int y0 = blockIdx.x * 16;
    const int ic = blockIdx.y;
    const int b  = blockIdx.z >> 3;
    const int zo = blockIdx.z & 7;
    const int tid = threadIdx.x, tx = tid & 15, ty = tid >> 4;

    float acc0[8] = {0,0,0,0,0,0,0,0};
    float acc1[8] = {0,0,0,0,0,0,0,0};
    const float* wb0 = wgt + ic * 343;

    for (int dz = 0; dz < 7; ++dz) {
        const int zin = zo + dz - 3;
        if (zin < 0 || zin >= 8) continue;
        // row j=0 is input row gy = y0+2ty-3 -> padded row y0+2ty+1
        const _Float16* pl = apad + (size_t)((b * 25 + ic) * 8 + zin) * 18496
                           + (size_t)(y0 + (ty << 1) + 1) * 136 + (tx << 3);
        const float* wb = wb0 + dz * 49;
        float wn[7], wo[7];
        #pragma unroll
        for (int j = 0; j <= 7; ++j) {
            f16x8 r0 = *(const f16x8*)(pl + (size_t)j * 136);
            f16x8 r1 = *(const f16x8*)(pl + (size_t)j * 136 + 8);
            float rrf[16];
            #pragma unroll
            for (int i = 0; i < 8; ++i) { rrf[i] = (float)r0[i]; rrf[8 + i] = (float)r1[i]; }
            if (j <= 6) {
                #pragma unroll
                for (int d = 0; d < 7; ++d) wn[d] = wb[j * 7 + d];
            }
            #pragma unroll
            for (int dx = 0; dx < 7; ++dx) {
                if (j <= 6) {
                    float w0 = wn[dx];
                    #pragma unroll
                    for (int k = 0; k < 8; ++k) acc0[k] = fmaf(rrf[dx + k + 1], w0, acc0[k]);
                }
                if (j >= 1) {
                    float w1 = wo[dx];
                    #pragma unroll
                    for (int k = 0; k < 8; ++k) acc1[k] = fmaf(rrf[dx + k + 1], w1, acc1[k]);
                }
            }
            #pragma unroll
            for (int d = 0; d < 7; ++d) wo[d] = wn[d];
        }
    }
    float* op = out + (size_t)ic * 262144
              + (((size_t)(b * 8 + zo)) << 14) + ((size_t)(y0 + (ty << 1)) << 7) + (tx << 3);
    *(float4*)op         = make_float4(acc0[0], acc0[1], acc0[2], acc0[3]);
    *(float4*)(op + 4)   = make_float4(acc0[4], acc0[5], acc0[6], acc0[7]);
    *(float4*)(op + 128) = make_float4(acc1[0], acc1[1], acc1[2], acc1[3]);
    *(float4*)(op + 132) = make_float4(acc1[4], acc1[5], acc1[6], acc1[7]);
}

// ---------------- conv1 via MFMA: 1ch -> 25ch, bias+square fused ----------------
__global__ __launch_bounds__(128) void conv3d1_mfma(
    const _Float16* __restrict__ x1, const _Float16* __restrict__ wt1,
    const float* __restrict__ bias, float* __restrict__ out)
{
    const int g = blockIdx.x;
    const int b = g >> 10;
    const int zo = (g >> 7) & 7;
    const int y = g & 127;
    const int tid = threadIdx.x;
    const int wv = tid >> 6;
    const int lane = tid & 63;
    const int n = lane & 31;
    const int h = lane >> 5;
    const int xc = wv << 6;

    f32x16 acc0, acc1;
    #pragma unroll
    for (int i = 0; i < 16; ++i) { acc0[i] = 0.f; acc1[i] = 0.f; }

    for (int dz = 0; dz < 7; ++dz) {
        const int zin = zo + dz - 3;
        if (zin < 0 || zin >= 8) continue;
        const _Float16* xpl = x1 + (size_t)(b * 8 + zin) * (134 * 136 * 2);
        #pragma unroll
        for (int dy = 0; dy < 7; ++dy) {
            const _Float16* wb = wt1 + (size_t)(dz * 7 + dy) * 512 + h * 256 + n * 8;
            f16x8 a0 = *(const f16x8*)(wb);
            const _Float16* bp = xpl + ((size_t)(y + dy) * 136 + xc + n) * 2 + h * 8;
            f16x8 b0 = *(const f16x8*)(bp);
            f16x8 b1 = *(const f16x8*)(bp + 64);
            acc0 = MFMA32(a0, b0, acc0);
            acc1 = MFMA32(a0, b1, acc1);
        }
    }
    float* ob = out + ((((size_t)b * 25) * 8 + zo) << 14) + (y << 7) + xc + n;
    #pragma unroll
    for (int r = 0; r < 16; ++r) {
        const int row = (r & 3) + 8 * (r >> 2) + 4 * h;
        if (row < 25) {
            float v0 = acc0[r] + bias[row];
            float v1 = acc1[r] + bias[row];
            ob[(size_t)row * 131072]      = v0 * v0;
            ob[(size_t)row * 131072 + 32] = v1 * v1;
        }
    }
}

// ---------------- weight repack for 15x15 (A-frag) ----------------
__global__ __launch_bounds__(256) void repack_w_kernel(
    const float* __restrict__ w, _Float16* __restrict__ wt)
{
    const int idx = blockIdx.x * 256 + threadIdx.x;   // < 230400
    const int j    = idx & 7;
    const int m    = (idx >> 3) & 31;
    const int half = (idx >> 8) & 1;
    const int ks   = (idx >> 9) & 1;
    const int t    = idx >> 10;                       // t = ky*15+kx, < 225
    const int ic   = ks * 16 + half * 8 + j;
    float v = 0.f;
    if (m < 25 && ic < 25) v = w[(m * 25 + ic) * 225 + t];
    wt[idx] = (_Float16)v;
}

// ---------------- 2D conv 15x15 via MFMA: LDS-staged A, kx-outer, rowpair A-reuse ----
// Block 256 thr = 4 waves x 32 px, rowpair (y0,y0+1). Per kx the block stages the
// NKY ky-slices of A (16 KB) into LDS once; waves ds_read A, global-load B.
// grid: x = b*64 + rowpair (0..127), y = kg (ky 0-7 / 8-14) -> partial at kg*NELEM.
template<int KY0, int NKY>
__device__ __forceinline__ void conv15_core(
    const _Float16* __restrict__ xbase, const _Float16* __restrict__ wt,
    _Float16* lA, int tid, int n, int half, f32x16& acc0, f32x16& acc1)
{
    for (int kx = 0; kx < 15; ++kx) {
        __syncthreads();
        #pragma unroll
        for (int p = 0; p < 4; ++p) {
            const int g = p * 256 + tid;
            if (g < NKY * 128) {
                const int ky_l = g >> 7, off = (g & 127) << 3;
                *(f16x8*)(lA + (size_t)g * 8) =
                    *(const f16x8*)(wt + (size_t)((KY0 + ky_l) * 15 + kx) * 1024 + off);
            }
        }
        __syncthreads();
        const _Float16* bp = xbase + kx * 32;
        f16x8 ap0, ap1;
        #pragma unroll
        for (int kl = 0; kl <= NKY; ++kl) {
            const int kyp = KY0 + kl;
            f16x8 b0 = *(const f16x8*)(bp + (size_t)kyp * 4608);
            f16x8 b1 = *(const f16x8*)(bp + (size_t)kyp * 4608 + 16);
            f16x8 an0, an1;
            if (kl < NKY) {
                an0 = *(const f16x8*)(lA + kl * 1024 + half * 256 + n * 8);
                an1 = *(const f16x8*)(lA + kl * 1024 + 512 + half * 256 + n * 8);
                acc0 = MFMA32(an0, b0, acc0);
                acc0 = MFMA32(an1, b1, acc0);
            }
            if (kl >= 1) {
                acc1 = MFMA32(ap0, b0, acc1);
                acc1 = MFMA32(ap1, b1, acc1);
            }
            ap0 = an0; ap1 = an1;
        }
    }
}

__global__ __launch_bounds__(256) void conv2d15_mfma(
    const _Float16* __restrict__ xt, const _Float16* __restrict__ wt,
    float* __restrict__ out)
{
    const int blk = blockIdx.x;
    const int b   = blk >> 6;
    const int y0  = (blk & 63) << 1;
    const int kg  = blockIdx.y;

    __shared__ __align__(16) _Float16 lA[8192];   // 16 KB

    const int tid  = threadIdx.x;
    const int wv   = tid >> 6;
    const int lane = tid & 63;
    const int n    = lane & 31;
    const int half = lane >> 5;
    const int xc   = wv << 5;

    f32x16 acc0, acc1;
    #pragma unroll
    for (int i = 0; i < 16; ++i) { acc0[i] = 0.f; acc1[i] = 0.f; }

    const _Float16* xbase = xt + (((size_t)(b * 142 + y0) * 144 + xc + n) * 32) + half * 8;

    if (kg == 0) conv15_core<0, 8>(xbase, wt, lA, tid, n, half, acc0, acc1);
    else         conv15_core<8, 7>(xbase, wt, lA, tid, n, half, acc0, acc1);

    float* ob = out + (size_t)kg * NELEM + (((size_t)b * 25) << 14) + (y0 << 7) + xc + n;
    #pragma unroll
    for (int r = 0; r < 16; ++r) {
        const int oc = (r & 3) + 8 * (r >> 2) + 4 * half;
        if (oc < 25) {
            ob[(size_t)oc << 14]         = acc0[r];   // row y0
            ob[((size_t)oc << 14) + 128] = acc1[r];   // row y0+1
        }
    }
}

// ---------------- BN batch-stats, 2-stage ----------------
template<bool PAIR>
__global__ __launch_bounds__(256) void bnstats1_kernel(
    const float* __restrict__ x, float2* __restrict__ ps)
{
    const int c = blockIdx.x;     // 25
    const int s = blockIdx.y;     // 8
    const int tid = threadIdx.x;
    const float4* p0 = (const float4*)(x + ((size_t)c << 14)) + s * 512;
    const float4* p1 = (const float4*)(x + ((size_t)(25 + c) << 14)) + s * 512;
    const float4* q0 = (const float4*)(x + NELEM + ((size_t)c << 14)) + s * 512;
    const float4* q1 = (const float4*)(x + NELEM + ((size_t)(25 + c) << 14)) + s * 512;
    float s1 = 0.f, s2 = 0.f;
    #pragma unroll
    for (int i = 0; i < 2; ++i) {
        const int idx = tid + i * 256;
        float4 v = p0[idx];
        if (PAIR) { float4 w = q0[idx]; v.x += w.x; v.y += w.y; v.z += w.z; v.w += w.w; }
        s1 += v.x + v.y + v.z + v.w;
        s2 += v.x * v.x + v.y * v.y + v.z * v.z + v.w * v.w;
        float4 u = p1[idx];
        if (PAIR) { float4 w = q1[idx]; u.x += w.x; u.y += w.y; u.z += w.z; u.w += w.w; }
        s1 += u.x + u.y + u.z + u.w;
        s2 += u.x * u.x + u.y * u.y + u.z * u.z + u.w * u.w;
    }
    #pragma unroll
    for (int off = 32; off; off >>= 1) { s1 += __shfl_down(s1, off); s2 += __shfl_down(s2, off); }
    __shared__ float a1[4], a2[4];
    if ((tid & 63) == 0) { a1[tid >> 6] = s1; a2[tid >> 6] = s2; }
    __syncthreads();
    if (tid == 0)
        ps[c * 8 + s] = make_float2(a1[0] + a1[1] + a1[2] + a1[3],
                                    a2[0] + a2[1] + a2[2] + a2[3]);
}

__global__ __launch_bounds__(64) void bnstats2_kernel(
    const float2* __restrict__ ps, const float* __restrict__ gw,
    const float* __restrict__ gb, float* __restrict__ scale, float* __restrict__ shift)
{
    const int c = threadIdx.x;
    if (c < 25) {
        float s1 = 0.f, s2 = 0.f;
        #pragma unroll
        for (int s = 0; s < 8; ++s) { float2 v = ps[c * 8 + s]; s1 += v.x; s2 += v.y; }
        const float m = s1 * (1.f / 32768.f);
        const float var = fmaxf(s2 * (1.f / 32768.f) - m * m, 0.f);
        const float sc = gw[c] * rsqrtf(var + 1e-3f);
        scale[c] = sc;
        shift[c] = gb[c] - m * sc;
    }
}

// ---------------- fused ns1: NS1, XT = f16(ns1) ----------------
__global__ __launch_bounds__(256) void nsg_kernel(
    const float* __restrict__ y, const float* __restrict__ h,
    const float* __restrict__ c1, const float* __restrict__ scale,
    const float* __restrict__ shift, const float* __restrict__ alpha,
    const float* __restrict__ mu, float* __restrict__ ns1,
    _Float16* __restrict__ xt, int t)
{
    const int p = blockIdx.x * 256 + threadIdx.x;   // < 32768
    const int b = p >> 14, pix = p & (HW - 1);
    const size_t base = (((size_t)b * 25) << 14) + pix;
    __align__(16) _Float16 xv[32];
    #pragma unroll
    for (int c = 0; c < 25; ++c) {
        const size_t idx = base + ((size_t)c << 14);
        const float yv = y[(((size_t)(b * 25 + c) * 8 + t) << 14) + pix];
        const float c1v = c1[idx] + c1[NELEM + idx];
        const float c1n = c1v * scale[c] + shift[c];
        const float pre = c1n * (alpha[c] * h[idx] + mu[c]);
        const float n = sp_f(yv - sp_f(pre));
        ns1[idx] = n;
        xv[c] = (_Float16)n;
    }
    #pragma unroll
    for (int c = 25; c < 32; ++c) xv[c] = (_Float16)0.f;
    const int yy = pix >> 7, xx = pix & 127;
    _Float16* xp = xt + (((size_t)(b * 142 + yy + 7)) * 144 + (xx + 7)) * 32;
    #pragma unroll
    for (int i = 0; i < 4; ++i) ((float4*)xp)[i] = ((const float4*)xv)[i];
}

// ---------------- fused hnew + both gates: H, XT = f16(h*g1) ----------------
__global__ __launch_bounds__(256) void hg_kernel(
    float* __restrict__ h, const float* __restrict__ ns1,
    const float* __restrict__ c2, const float* __restrict__ scale,
    const float* __restrict__ shift, const float* __restrict__ kappa,
    const float* __restrict__ gp, const float* __restrict__ wmix,
    const float* __restrict__ u1w, const float* __restrict__ u1b,
    const float* __restrict__ u2w, const float* __restrict__ u2b,
    _Float16* __restrict__ xt)
{
    const int p = blockIdx.x * 256 + threadIdx.x;   // < 32768
    const int b = p >> 14, pix = p & (HW - 1);
    const size_t base = (((size_t)b * 25) << 14) + pix;
    float nv[25];
    #pragma unroll
    for (int c = 0; c < 25; ++c) nv[c] = ns1[base + ((size_t)c << 14)];
    float g2v[25];
    #pragma unroll
    for (int oc = 0; oc < 25; ++oc) {
        float acc = u2b[oc];
        #pragma unroll
        for (int ic = 0; ic < 25; ++ic) acc += u2w[oc * 25 + ic] * nv[ic];
        g2v[oc] = sig_f(acc);
    }
    float hv[25];
    #pragma unroll
    for (int c = 0; c < 25; ++c) {
        const size_t idx = base + ((size_t)c << 14);
        const float c2v = c2[idx] + c2[NELEM + idx];
        const float c2n = c2v * scale[c] + shift[c];
        const float n = nv[c];
        const float h2 = sp_f(kappa[c] * n + gp[c] * c2n + wmix[c] * n * c2n);
        const float g = g2v[c];
        const float hn = sp_f((1.f - g) * h[idx] + g * h2);
        hv[c] = hn;
        h[idx] = hn;
    }
    __align__(16) _Float16 xv[32];
    #pragma unroll
    for (int oc = 0; oc < 25; ++oc) {
        float acc = u1b[oc];
        #pragma unroll
        for (int ic = 0; ic < 25; ++ic) acc += u1w[oc * 25 + ic] * hv[ic];
        xv[oc] = (_Float16)(hv[oc] * sig_f(acc));
    }
    #pragma unroll
    for (int oc = 25; oc < 32; ++oc) xv[oc] = (_Float16)0.f;
    const int yy = pix >> 7, xx = pix & 127;
    _Float16* xp = xt + (((size_t)(b * 142 + yy + 7)) * 144 + (xx + 7)) * 32;
    #pragma unroll
    for (int i = 0; i < 4; ++i) ((float4*)xp)[i] = ((const float4*)xv)[i];
}

// ---------------- fused bn_out + avgpool2 + fc partial dot ----------------
__global__ __launch_bounds__(256) void fc1_kernel(
    const float* __restrict__ h, const float* __restrict__ scale,
    const float* __restrict__ shift, const float* __restrict__ fcw,
    float2* __restrict__ part)
{
    const int tid = threadIdx.x;
    const int i = blockIdx.x * 256 + tid;   // < 204800
    int px = i & 63;
    int t = i >> 6;
    int py = t & 63; t >>= 6;               // t = b*25 + c
    int c = t >= 25 ? t - 25 : t;
    const float* hp = h + ((size_t)t << 14);
    const int y0 = py << 1, xg = px << 1;
    float s = hp[(y0 << 7) + xg] + hp[(y0 << 7) + xg + 1]
            + hp[((y0 + 1) << 7) + xg] + hp[((y0 + 1) << 7) + xg + 1];
    const float o = 0.25f * s * scale[c] + shift[c];
    float p0 = o * fcw[i];
    float p1 = o * fcw[204800 + i];
    #pragma unroll
    for (int off = 32; off; off >>= 1) { p0 += __shfl_down(p0, off); p1 += __shfl_down(p1, off); }
    __shared__ float a0[4], a1[4];
    if ((tid & 63) == 0) { a0[tid >> 6] = p0; a1[tid >> 6] = p1; }
    __syncthreads();
    if (tid == 0)
        part[blockIdx.x] = make_float2(a0[0] + a0[1] + a0[2] + a0[3],
                                       a1[0] + a1[1] + a1[2] + a1[3]);
}

__global__ __launch_bounds__(256) void fc2_kernel(
    const float2* __restrict__ part, const float* __restrict__ fcb, float* __restrict__ out)
{
    const int tid = threadIdx.x;
    float s0 = 0.f, s1 = 0.f;
    for (int i = tid; i < 800; i += 256) { float2 v = part[i]; s0 += v.x; s1 += v.y; }
    #pragma unroll
    for (int off = 32; off; off >>= 1) { s0 += __shfl_down(s0, off); s1 += __shfl_down(s1, off); }
    __shared__ float a0[4], a1[4];
    if ((tid & 63) == 0) { a0[tid >> 6] = s0; a1[tid >> 6] = s1; }
    __syncthreads();
    if (tid == 0) {
        out[0] = sig_f(a0[0] + a0[1] + a0[2] + a0[3] + fcb[0]);
        out[1] = sig_f(a1[0] + a1[1] + a1[2] + a1[3] + fcb[1]);
    }
}

extern "C" void kernel_launch(void* const* d_in, const int* in_sizes, int n_in,
                              void* d_out, int out_size, void* d_ws, size_t ws_size,
                              hipStream_t stream)
{
    const float* x        = (const float*)d_in[0];
    const float* conv00_w = (const float*)d_in[1];
    const float* conv0_w  = (const float*)d_in[2];
    const float* conv1_w  = (const float*)d_in[3];
    const float* conv1_b  = (const float*)d_in[4];
    const float* u1_w     = (const float*)d_in[5];
    const float* u1_b     = (const float*)d_in[6];
    const float* u2_w     = (const float*)d_in[7];
    const float* u2_b     = (const float*)d_in[8];
    const float* w_inh    = (const float*)d_in[9];
    const float* w_exc    = (const float*)d_in[10];
    const float* alpha    = (const float*)d_in[11];
    const float* mu       = (const float*)d_in[12];
    const float* gamma_p  = (const float*)d_in[13];
    const float* kappa    = (const float*)d_in[14];
    const float* w_mix    = (const float*)d_in[15];
    const float* bn1_w    = (const float*)d_in[16];
    const float* bn1_b    = (const float*)d_in[17];
    const float* bn3_w    = (const float*)d_in[18];
    const float* bn3_b    = (const float*)d_in[19];
    const float* bn_out_w = (const float*)d_in[20];
    const float* bn_out_b = (const float*)d_in[21];
    const float* fc4_w    = (const float*)d_in[22];
    const float* fc4_b    = (const float*)d_in[23];

    float* ws = (float*)d_ws;
    // layout (float offsets):
    float* Y    = ws;                        // [0, 6,553,600): B0p early, then Y
    float* R    = ws + 6553600;              // front-end: APAD (3,699,200 fl); then step buffers
    float* X0f  = ws + 13107200;             // X0: 583,424 fl
    float* X1f  = ws + 13690624;             // X1: 291,712 fl
    float* WT0f = ws + 13982336;             // 25,088 fl
    float* WT1cf= ws + 14007424;             // 12,544 fl
    float* WT1f = ws + 14019968;             // 115,200 fl
    float* WT2f = ws + 14135168;             // 115,200 fl
    float* XTf  = ws + 14250368;             // 654,336 fl
    float* SC1  = ws + 14904704;
    float* SH1  = SC1 + 32;
    float* SC2  = SH1 + 32;
    float* SH2  = SC2 + 32;
    float* PART = SH2 + 32;                  // 1600 (800 x float2)
    float* PS   = PART + 1600;               // 400 (200 x float2)

    float* B0p  = Y;                         // 25 partials x 262,144
    float* H    = R;
    float* NS1  = R + 1 * NELEM;
    float* C1   = R + 2 * NELEM;             // pair
    float* C2   = R + 4 * NELEM;             // pair

    _Float16* APAD = (_Float16*)R;           // [2*25][8][136][136] f16 = 7,398,400 f16
    _Float16* X0  = (_Float16*)X0f;
    _Float16* X1  = (_Float16*)X1f;
    _Float16* WT0 = (_Float16*)WT0f;
    _Float16* WT1c= (_Float16*)WT1cf;
    _Float16* WT1 = (_Float16*)WT1f;
    _Float16* WT2 = (_Float16*)WT2f;
    _Float16* XT  = (_Float16*)XTf;

    // ---- front-end ----
    (void)hipMemsetAsync(APAD, 0, (size_t)7398400 * sizeof(_Float16), stream);
    (void)hipMemsetAsync(X0, 0, (size_t)1166848 * sizeof(_Float16), stream);
    (void)hipMemsetAsync(X1, 0, (size_t)583424 * sizeof(_Float16), stream);
    (void)hipMemsetAsync(XT, 0, (size_t)1308672 * sizeof(_Float16), stream);
    xpack0_kernel<<<1024, 256, 0, stream>>>(x, X0);
    repack_w00_kernel<<<196, 256, 0, stream>>>(conv00_w, WT0);
    repack_w1_kernel<<<98, 256, 0, stream>>>(conv1_w, WT1c);
    repack_w_kernel<<<900, 256, 0, stream>>>(w_inh, WT1);
    repack_w_kernel<<<900, 256, 0, stream>>>(w_exc, WT2);

    conv3d00_mfma<<<2048, 128, 0, stream>>>(X0, WT0, APAD);
    conv3d0_direct<<<dim3(8, 25, 16), 128, 0, stream>>>(APAD, conv0_w, B0p);
    xpack1_kernel<<<1024, 256, 0, stream>>>(B0p, X1);
    conv3d1_mfma<<<2048, 128, 0, stream>>>(X1, WT1c, conv1_b, Y);

    // ---- recurrence ----
    (void)hipMemsetAsync(H, 0, (size_t)NELEM * sizeof(float), stream);
    for (int t = 0; t < 8; ++t) {
        conv2d15_mfma<<<dim3(128, 2), 256, 0, stream>>>(XT, WT1, C1);
        bnstats1_kernel<true><<<dim3(25, 8), 256, 0, stream>>>(C1, (float2*)PS);
        bnstats2_kernel<<<1, 64, 0, stream>>>((const float2*)PS, bn1_w, bn1_b, SC1, SH1);
        nsg_kernel<<<128, 256, 0, stream>>>(Y, H, C1, SC1, SH1, alpha, mu, NS1, XT, t);
        conv2d15_mfma<<<dim3(128, 2), 256, 0, stream>>>(XT, WT2, C2);
        bnstats1_kernel<true><<<dim3(25, 8), 256, 0, stream>>>(C2, (float2*)PS);
        bnstats2_kernel<<<1, 64, 0, stream>>>((const float2*)PS, bn3_w, bn3_b, SC2, SH2);
        hg_kernel<<<128, 256, 0, stream>>>(H, NS1, C2, SC2, SH2,
                                           kappa, gamma_p, w_mix, u1_w, u1_b, u2_w, u2_b, XT);
    }

    // ---- head ----
    bnstats1_kernel<false><<<dim3(25, 8), 256, 0, stream>>>(H, (float2*)PS);
    bnstats2_kernel<<<1, 64, 0, stream>>>((const float2*)PS, bn_out_w, bn_out_b, SC1, SH1);
    fc1_kernel<<<800, 256, 0, stream>>>(H, SC1, SH1, fc4_w, (float2*)PART);
    fc2_kernel<<<1, 256, 0, stream>>>((const float2*)PART, fc4_b, (float*)d_out);
}

// Round 8
// 1313.533 us; speedup vs baseline: 6.5389x; 1.1688x over previous
//
#include <hip/hip_runtime.h>
#include <cstddef>

#define HW 16384           // 128*128
#define NELEM 819200       // 2*25*HW

typedef _Float16 f16x8 __attribute__((ext_vector_type(8)));
typedef _Float16 f16x4 __attribute__((ext_vector_type(4)));
typedef _Float16 f16x2 __attribute__((ext_vector_type(2)));
typedef float    f32x16 __attribute__((ext_vector_type(16)));

#define MFMA32(a, b, c) __builtin_amdgcn_mfma_f32_32x32x16_f16((a), (b), (c), 0, 0, 0)

#if __has_builtin(__builtin_amdgcn_fdot2)
#define HAS_FDOT2 1
#else
#define HAS_FDOT2 0
#endif

__device__ __forceinline__ float sp_f(float x) {
    return fmaxf(x, 0.f) + log1pf(expf(-fabsf(x)));
}
__device__ __forceinline__ float sig_f(float x) {
    return 1.f / (1.f + expf(-x));
}

// ---------------- front-end prepack kernels ----------------
__global__ __launch_bounds__(256) void xpack0_kernel(
    const float* __restrict__ x, _Float16* __restrict__ x0)
{
    const int p = blockIdx.x * 256 + threadIdx.x;   // < 262144
    const int b = p >> 17, rem = p & 131071;
    const int z = rem >> 14, pix = rem & 16383;
    const int y = pix >> 7, xx = pix & 127;
    const size_t sb = ((size_t)b * 3 * 8 + z) << 14;
    f16x4 v;
    v[0] = (_Float16)x[sb + pix];
    v[1] = (_Float16)x[sb + (8ull << 14) + pix];
    v[2] = (_Float16)x[sb + (16ull << 14) + pix];
    v[3] = (_Float16)0.f;
    *(f16x4*)(x0 + (((size_t)(b * 8 + z) * 134 + y + 3) * 136 + xx + 3) * 4) = v;
}

__global__ __launch_bounds__(256) void repack_w00_kernel(
    const float* __restrict__ w, _Float16* __restrict__ wt)
{
    const int idx = blockIdx.x * 256 + threadIdx.x;   // < 50176
    const int j  = idx & 7;
    const int m  = (idx >> 3) & 31;
    const int h  = (idx >> 8) & 1;
    const int kk = (idx >> 9) & 1;
    const int tapb = idx >> 10;                       // dz*7+dy, < 49
    const int dz = tapb / 7, dy = tapb - dz * 7;
    const int ic = j & 3, dxl = j >> 2;
    const int dx = kk * 4 + h * 2 + dxl;
    float v = 0.f;
    if (m < 25 && ic < 3 && dx < 7)
        v = w[(((m * 3 + ic) * 7 + dz) * 7 + dy) * 7 + dx];
    wt[idx] = (_Float16)v;
}

__global__ __launch_bounds__(256) void xpack1_kernel(
    const float* __restrict__ b0p, _Float16* __restrict__ x1)
{
    const int p = blockIdx.x * 256 + threadIdx.x;   // < 262144
    const int b = p >> 17, rem = p & 131071;
    const int z = rem >> 14, pix = rem & 16383;
    const int y = pix >> 7, xx = pix & 127;
    float s = 0.f;
    #pragma unroll
    for (int g = 0; g < 25; ++g) s += b0p[(size_t)g * 262144 + p];
    x1[(((size_t)(b * 8 + z) * 134 + y + 3) * 136 + xx + 3) * 2] = (_Float16)s;
}

__global__ __launch_bounds__(256) void repack_w1_kernel(
    const float* __restrict__ w, _Float16* __restrict__ wt)
{
    const int idx = blockIdx.x * 256 + threadIdx.x;   // < 25088
    const int j = idx & 7;
    const int m = (idx >> 3) & 31;
    const int h = (idx >> 8) & 1;
    const int tapb = idx >> 9;                        // < 49
    const int dz = tapb / 7, dy = tapb - dz * 7;
    const int c2 = j & 1, dx = h * 4 + (j >> 1);
    float v = 0.f;
    if (m < 25 && c2 == 0 && dx < 7)
        v = w[((m * 7 + dz) * 7 + dy) * 7 + dx];
    wt[idx] = (_Float16)v;
}

// ---------------- conv00 via MFMA: 3ch -> 25ch, writes halo-4-padded f16 planes ----
__global__ __launch_bounds__(128) void conv3d00_mfma(
    const _Float16* __restrict__ x0, const _Float16* __restrict__ wt0,
    _Float16* __restrict__ apad)
{
    const int g = blockIdx.x;
    const int b = g >> 10;
    const int zo = (g >> 7) & 7;
    const int y = g & 127;
    const int tid = threadIdx.x;
    const int wv = tid >> 6;
    const int lane = tid & 63;
    const int n = lane & 31;
    const int h = lane >> 5;
    const int xc = wv << 6;

    f32x16 acc0, acc1;
    #pragma unroll
    for (int i = 0; i < 16; ++i) { acc0[i] = 0.f; acc1[i] = 0.f; }

    for (int dz = 0; dz < 7; ++dz) {
        const int zin = zo + dz - 3;
        if (zin < 0 || zin >= 8) continue;
        const _Float16* xpl = x0 + (size_t)(b * 8 + zin) * (134 * 136 * 4);
        #pragma unroll
        for (int dy = 0; dy < 7; ++dy) {
            const _Float16* xr = xpl + (size_t)(y + dy) * (136 * 4);
            const _Float16* wb = wt0 + (size_t)((dz * 7 + dy) * 2) * 512 + h * 256 + n * 8;
            f16x8 a0 = *(const f16x8*)(wb);
            f16x8 a1 = *(const f16x8*)(wb + 512);
            const _Float16* bp = xr + (size_t)(xc + n + 2 * h) * 4;
            f16x8 b00 = *(const f16x8*)(bp);
            f16x8 b01 = *(const f16x8*)(bp + 16);
            f16x8 b10 = *(const f16x8*)(bp + 128);
            f16x8 b11 = *(const f16x8*)(bp + 144);
            acc0 = MFMA32(a0, b00, acc0);
            acc1 = MFMA32(a0, b10, acc1);
            acc0 = MFMA32(a1, b01, acc0);
            acc1 = MFMA32(a1, b11, acc1);
        }
    }
    _Float16* ob = apad + (size_t)((b * 25) * 8 + zo) * 18496
                 + (size_t)(y + 4) * 136 + 4 + xc + n;
    #pragma unroll
    for (int r = 0; r < 16; ++r) {
        const int row = (r & 3) + 8 * (r >> 2) + 4 * h;
        if (row < 25) {
            ob[(size_t)row * 147968]      = (_Float16)acc0[r];
            ob[(size_t)row * 147968 + 32] = (_Float16)acc1[r];
        }
    }
}

// ---------------- conv0: 25ch -> 1ch, direct-global f16 reads, fdot2 path ----------------
__global__ __launch_bounds__(128) void conv3d0_direct(
    const _Float16* __restrict__ apad, const float* __restrict__ wgt,
    float* __restrict__ out)
{
    const int y0 = blockIdx.x * 16;
    const int ic = blockIdx.y;
    const int b  = blockIdx.z >> 3;
    const int zo = blockIdx.z & 7;
    const int tid = threadIdx.x, tx = tid & 15, ty = tid >> 4;

    float acc0[8] = {0,0,0,0,0,0,0,0};
    float acc1[8] = {0,0,0,0,0,0,0,0};
    const float* wb0 = wgt + ic * 343;

    for (int dz = 0; dz < 7; ++dz) {
        const int zin = zo + dz - 3;
        if (zin < 0 || zin >= 8) continue;
        const _Float16* pl = apad + (size_t)((b * 25 + ic) * 8 + zin) * 18496
                           + (size_t)(y0 + (ty << 1) + 1) * 136 + (tx << 3);
        const float* wb = wb0 + dz * 49;
#if HAS_FDOT2
        f16x2 wpn[4], wpo[4];
        #pragma unroll
        for (int j = 0; j <= 7; ++j) {
            f16x8 r0 = *(const f16x8*)(pl + (size_t)j * 136);
            f16x8 r1 = *(const f16x8*)(pl + (size_t)j * 136 + 8);
            _Float16 rr[16];
            #pragma unroll
            for (int i = 0; i < 8; ++i) { rr[i] = r0[i]; rr[8 + i] = r1[i]; }
            f16x2 pr[14];
            #pragma unroll
            for (int i = 0; i < 14; ++i) { pr[i][0] = rr[i + 1]; pr[i][1] = rr[i + 2]; }
            if (j <= 6) {
                #pragma unroll
                for (int p = 0; p < 3; ++p) {
                    wpn[p][0] = (_Float16)wb[j * 7 + 2 * p];
                    wpn[p][1] = (_Float16)wb[j * 7 + 2 * p + 1];
                }
                wpn[3][0] = (_Float16)wb[j * 7 + 6];
                wpn[3][1] = (_Float16)0.f;
            }
            #pragma unroll
            for (int k = 0; k < 8; ++k) {
                if (j <= 6) {
                    #pragma unroll
                    for (int p = 0; p < 4; ++p)
                        acc0[k] = __builtin_amdgcn_fdot2(wpn[p], pr[k + 2 * p], acc0[k], false);
                }
                if (j >= 1) {
                    #pragma unroll
                    for (int p = 0; p < 4; ++p)
                        acc1[k] = __builtin_amdgcn_fdot2(wpo[p], pr[k + 2 * p], acc1[k], false);
                }
            }
            #pragma unroll
            for (int p = 0; p < 4; ++p) wpo[p] = wpn[p];
        }
#else
        float wn[7], wo[7];
        #pragma unroll
        for (int j = 0; j <= 7; ++j) {
            f16x8 r0 = *(const f16x8*)(pl + (size_t)j * 136);
            f16x8 r1 = *(const f16x8*)(pl + (size_t)j * 136 + 8);
            float rrf[16];
            #pragma unroll
            for (int i = 0; i < 8; ++i) { rrf[i] = (float)r0[i]; rrf[8 + i] = (float)r1[i]; }
            if (j <= 6) {
                #pragma unroll
                for (int d = 0; d < 7; ++d) wn[d] = wb[j * 7 + d];
            }
            #pragma unroll
            for (int dx = 0; dx < 7; ++dx) {
                if (j <= 6) {
                    float w0 = wn[dx];
                    #pragma unroll
                    for (int k = 0; k < 8; ++k) acc0[k] = fmaf(rrf[dx + k + 1], w0, acc0[k]);
                }
                if (j >= 1) {
                    float w1 = wo[dx];
                    #pragma unroll
                    for (int k = 0; k < 8; ++k) acc1[k] = fmaf(rrf[dx + k + 1], w1, acc1[k]);
                }
            }
            #pragma unroll
            for (int d = 0; d < 7; ++d) wo[d] = wn[d];
        }
#endif
    }
    float* op = out + (size_t)ic * 262144
              + (((size_t)(b * 8 + zo)) << 14) + ((size_t)(y0 + (ty << 1)) << 7) + (tx << 3);
    *(float4*)op         = make_float4(acc0[0], acc0[1], acc0[2], acc0[3]);
    *(float4*)(op + 4)   = make_float4(acc0[4], acc0[5], acc0[6], acc0[7]);
    *(float4*)(op + 128) = make_float4(acc1[0], acc1[1], acc1[2], acc1[3]);
    *(float4*)(op + 132) = make_float4(acc1[4], acc1[5], acc1[6], acc1[7]);
}

// ---------------- conv1 via MFMA: 1ch -> 25ch, bias+square fused ----------------
__global__ __launch_bounds__(128) void conv3d1_mfma(
    const _Float16* __restrict__ x1, const _Float16* __restrict__ wt1,
    const float* __restrict__ bias, float* __restrict__ out)
{
    const int g = blockIdx.x;
    const int b = g >> 10;
    const int zo = (g >> 7) & 7;
    const int y = g & 127;
    const int tid = threadIdx.x;
    const int wv = tid >> 6;
    const int lane = tid & 63;
    const int n = lane & 31;
    const int h = lane >> 5;
    const int xc = wv << 6;

    f32x16 acc0, acc1;
    #pragma unroll
    for (int i = 0; i < 16; ++i) { acc0[i] = 0.f; acc1[i] = 0.f; }

    for (int dz = 0; dz < 7; ++dz) {
        const int zin = zo + dz - 3;
        if (zin < 0 || zin >= 8) continue;
        const _Float16* xpl = x1 + (size_t)(b * 8 + zin) * (134 * 136 * 2);
        #pragma unroll
        for (int dy = 0; dy < 7; ++dy) {
            const _Float16* wb = wt1 + (size_t)(dz * 7 + dy) * 512 + h * 256 + n * 8;
            f16x8 a0 = *(const f16x8*)(wb);
            const _Float16* bp = xpl + ((size_t)(y + dy) * 136 + xc + n) * 2 + h * 8;
            f16x8 b0 = *(const f16x8*)(bp);
            f16x8 b1 = *(const f16x8*)(bp + 64);
            acc0 = MFMA32(a0, b0, acc0);
            acc1 = MFMA32(a0, b1, acc1);
        }
    }
    float* ob = out + ((((size_t)b * 25) * 8 + zo) << 14) + (y << 7) + xc + n;
    #pragma unroll
    for (int r = 0; r < 16; ++r) {
        const int row = (r & 3) + 8 * (r >> 2) + 4 * h;
        if (row < 25) {
            float v0 = acc0[r] + bias[row];
            float v1 = acc1[r] + bias[row];
            ob[(size_t)row * 131072]      = v0 * v0;
            ob[(size_t)row * 131072 + 32] = v1 * v1;
        }
    }
}

// ---------------- weight repack for 15x15 (A-frag) ----------------
__global__ __launch_bounds__(256) void repack_w_kernel(
    const float* __restrict__ w, _Float16* __restrict__ wt)
{
    const int idx = blockIdx.x * 256 + threadIdx.x;   // < 230400
    const int j    = idx & 7;
    const int m    = (idx >> 3) & 31;
    const int half = (idx >> 8) & 1;
    const int ks   = (idx >> 9) & 1;
    const int t    = idx >> 10;                       // t = ky*15+kx, < 225
    const int ic   = ks * 16 + half * 8 + j;
    float v = 0.f;
    if (m < 25 && ic < 25) v = w[(m * 25 + ic) * 225 + t];
    wt[idx] = (_Float16)v;
}

// ---------------- 2D conv 15x15 via MFMA: 4-way ky split, LDS A, rowpair A-reuse ----
template<int KY0, int NKY>
__device__ __forceinline__ void conv15_core(
    const _Float16* __restrict__ xbase, const _Float16* __restrict__ wt,
    _Float16* lA, int tid, int n, int half, f32x16& acc0, f32x16& acc1)
{
    for (int kx = 0; kx < 15; ++kx) {
        __syncthreads();
        #pragma unroll
        for (int p = 0; p < 2; ++p) {
            const int g = p * 256 + tid;
            if (g < NKY * 128) {
                const int ky_l = g >> 7, off = (g & 127) << 3;
                *(f16x8*)(lA + (size_t)g * 8) =
                    *(const f16x8*)(wt + (size_t)((KY0 + ky_l) * 15 + kx) * 1024 + off);
            }
        }
        __syncthreads();
        const _Float16* bp = xbase + kx * 32;
        f16x8 ap0, ap1;
        #pragma unroll
        for (int kl = 0; kl <= NKY; ++kl) {
            const int kyp = KY0 + kl;
            f16x8 b0 = *(const f16x8*)(bp + (size_t)kyp * 4608);
            f16x8 b1 = *(const f16x8*)(bp + (size_t)kyp * 4608 + 16);
            f16x8 an0, an1;
            if (kl < NKY) {
                an0 = *(const f16x8*)(lA + kl * 1024 + half * 256 + n * 8);
                an1 = *(const f16x8*)(lA + kl * 1024 + 512 + half * 256 + n * 8);
                acc0 = MFMA32(an0, b0, acc0);
                acc0 = MFMA32(an1, b1, acc0);
            }
            if (kl >= 1) {
                acc1 = MFMA32(ap0, b0, acc1);
                acc1 = MFMA32(ap1, b1, acc1);
            }
            ap0 = an0; ap1 = an1;
        }
    }
}

__global__ __launch_bounds__(256) void conv2d15_mfma(
    const _Float16* __restrict__ xt, const _Float16* __restrict__ wt,
    float* __restrict__ out)
{
    const int blk = blockIdx.x;
    const int b   = blk >> 6;
    const int y0  = (blk & 63) << 1;
    const int kg  = blockIdx.y;                 // 0..3

    __shared__ __align__(16) _Float16 lA[4096];  // 8 KB max (NKY=4)

    const int tid  = threadIdx.x;
    const int wv   = tid >> 6;
    const int lane = tid & 63;
    const int n    = lane & 31;
    const int half = lane >> 5;
    const int xc   = wv << 5;

    f32x16 acc0, acc1;
    #pragma unroll
    for (int i = 0; i < 16; ++i) { acc0[i] = 0.f; acc1[i] = 0.f; }

    const _Float16* xbase = xt + (((size_t)(b * 142 + y0) * 144 + xc + n) * 32) + half * 8;

    if      (kg == 0) conv15_core<0,  4>(xbase, wt, lA, tid, n, half, acc0, acc1);
    else if (kg == 1) conv15_core<4,  4>(xbase, wt, lA, tid, n, half, acc0, acc1);
    else if (kg == 2) conv15_core<8,  4>(xbase, wt, lA, tid, n, half, acc0, acc1);
    else              conv15_core<12, 3>(xbase, wt, lA, tid, n, half, acc0, acc1);

    float* ob = out + (size_t)kg * NELEM + (((size_t)b * 25) << 14) + (y0 << 7) + xc + n;
    #pragma unroll
    for (int r = 0; r < 16; ++r) {
        const int oc = (r & 3) + 8 * (r >> 2) + 4 * half;
        if (oc < 25) {
            ob[(size_t)oc << 14]         = acc0[r];   // row y0
            ob[((size_t)oc << 14) + 128] = acc1[r];   // row y0+1
        }
    }
}

// ---------------- BN batch-stats stage 1: sums partials, writes CS + PS ----------------
template<int NPART, bool WRITE_SUM>
__global__ __launch_bounds__(256) void bnstats1_kernel(
    const float* __restrict__ x, float* __restrict__ cs, float2* __restrict__ ps)
{
    const int c = blockIdx.x;     // 25
    const int s = blockIdx.y;     // 8
    const int tid = threadIdx.x;
    float s1 = 0.f, s2 = 0.f;
    #pragma unroll
    for (int bb = 0; bb < 2; ++bb) {
        const size_t plane = ((size_t)(bb * 25 + c)) << 14;
        const float4* p0 = (const float4*)(x + plane) + s * 512;
        float4* c0 = WRITE_SUM ? (float4*)(cs + plane) + s * 512 : nullptr;
        #pragma unroll
        for (int i = 0; i < 2; ++i) {
            const int idx = tid + i * 256;
            float4 v = p0[idx];
            #pragma unroll
            for (int j = 1; j < NPART; ++j) {
                float4 w = *((const float4*)(x + (size_t)j * NELEM + plane) + s * 512 + idx);
                v.x += w.x; v.y += w.y; v.z += w.z; v.w += w.w;
            }
            if (WRITE_SUM) c0[idx] = v;
            s1 += v.x + v.y + v.z + v.w;
            s2 += v.x * v.x + v.y * v.y + v.z * v.z + v.w * v.w;
        }
    }
    #pragma unroll
    for (int off = 32; off; off >>= 1) { s1 += __shfl_down(s1, off); s2 += __shfl_down(s2, off); }
    __shared__ float a1[4], a2[4];
    if ((tid & 63) == 0) { a1[tid >> 6] = s1; a2[tid >> 6] = s2; }
    __syncthreads();
    if (tid == 0)
        ps[c * 8 + s] = make_float2(a1[0] + a1[1] + a1[2] + a1[3],
                                    a2[0] + a2[1] + a2[2] + a2[3]);
}

__global__ __launch_bounds__(64) void bnstats2_kernel(
    const float2* __restrict__ ps, const float* __restrict__ gw,
    const float* __restrict__ gb, float* __restrict__ scale, float* __restrict__ shift)
{
    const int c = threadIdx.x;
    if (c < 25) {
        float s1 = 0.f, s2 = 0.f;
        #pragma unroll
        for (int s = 0; s < 8; ++s) { float2 v = ps[c * 8 + s]; s1 += v.x; s2 += v.y; }
        const float m = s1 * (1.f / 32768.f);
        const float var = fmaxf(s2 * (1.f / 32768.f) - m * m, 0.f);
        const float sc = gw[c] * rsqrtf(var + 1e-3f);
        scale[c] = sc;
        shift[c] = gb[c] - m * sc;
    }
}

// ---------------- fused ns1 (+in-block BN finalize): NS1, XT = f16(ns1) ----------------
__global__ __launch_bounds__(256) void nsg_kernel(
    const float* __restrict__ y, const float* __restrict__ h,
    const float* __restrict__ cs, const float2* __restrict__ ps,
    const float* __restrict__ gw, const float* __restrict__ gb,
    const float* __restrict__ alpha, const float* __restrict__ mu,
    float* __restrict__ ns1, _Float16* __restrict__ xt, int t)
{
    __shared__ float sc[25], sh[25];
    const int tid = threadIdx.x;
    if (tid < 25) {
        float s1 = 0.f, s2 = 0.f;
        #pragma unroll
        for (int s = 0; s < 8; ++s) { float2 v = ps[tid * 8 + s]; s1 += v.x; s2 += v.y; }
        const float m = s1 * (1.f / 32768.f);
        const float var = fmaxf(s2 * (1.f / 32768.f) - m * m, 0.f);
        const float scv = gw[tid] * rsqrtf(var + 1e-3f);
        sc[tid] = scv;
        sh[tid] = gb[tid] - m * scv;
    }
    __syncthreads();
    const int p = blockIdx.x * 256 + tid;   // < 32768
    const int b = p >> 14, pix = p & (HW - 1);
    const size_t base = (((size_t)b * 25) << 14) + pix;
    __align__(16) _Float16 xv[32];
    #pragma unroll
    for (int c = 0; c < 25; ++c) {
        const size_t idx = base + ((size_t)c << 14);
        const float yv = y[(((size_t)(b * 25 + c) * 8 + t) << 14) + pix];
        const float c1n = cs[idx] * sc[c] + sh[c];
        const float pre = c1n * (alpha[c] * h[idx] + mu[c]);
        const float n = sp_f(yv - sp_f(pre));
        ns1[idx] = n;
        xv[c] = (_Float16)n;
    }
    #pragma unroll
    for (int c = 25; c < 32; ++c) xv[c] = (_Float16)0.f;
    const int yy = pix >> 7, xx = pix & 127;
    _Float16* xp = xt + (((size_t)(b * 142 + yy + 7)) * 144 + (xx + 7)) * 32;
    #pragma unroll
    for (int i = 0; i < 4; ++i) ((float4*)xp)[i] = ((const float4*)xv)[i];
}

// ---------------- fused hnew + both gates (+in-block BN finalize) ----------------
__global__ __launch_bounds__(256) void hg_kernel(
    float* __restrict__ h, const float* __restrict__ ns1,
    const float* __restrict__ cs, const float2* __restrict__ ps,
    const float* __restrict__ gw, const float* __restrict__ gb,
    const float* __restrict__ kappa, const float* __restrict__ gp,
    const float* __restrict__ wmix, const float* __restrict__ u1w,
    const float* __restrict__ u1b, const float* __restrict__ u2w,
    const float* __restrict__ u2b, _Float16* __restrict__ xt)
{
    __shared__ float sc[25], sh[25];
    const int tid = threadIdx.x;
    if (tid < 25) {
        float s1 = 0.f, s2 = 0.f;
        #pragma unroll
        for (int s = 0; s < 8; ++s) { float2 v = ps[tid * 8 + s]; s1 += v.x; s2 += v.y; }
        const float m = s1 * (1.f / 32768.f);
        const float var = fmaxf(s2 * (1.f / 32768.f) - m * m, 0.f);
        const float scv = gw[tid] * rsqrtf(var + 1e-3f);
        sc[tid] = scv;
        sh[tid] = gb[tid] - m * scv;
    }
    __syncthreads();
    const int p = blockIdx.x * 256 + tid;   // < 32768
    const int b = p >> 14, pix = p & (HW - 1);
    const size_t base = (((size_t)b * 25) << 14) + pix;
    float nv[25];
    #pragma unroll
    for (int c = 0; c < 25; ++c) nv[c] = ns1[base + ((size_t)c << 14)];
    float g2v[25];
    #pragma unroll
    for (int oc = 0; oc < 25; ++oc) {
        float acc = u2b[oc];
        #pragma unroll
        for (int ic = 0; ic < 25; ++ic) acc += u2w[oc * 25 + ic] * nv[ic];
        g2v[oc] = sig_f(acc);
    }
    float hv[25];
    #pragma unroll
    for (int c = 0; c < 25; ++c) {
        const size_t idx = base + ((size_t)c << 14);
        const float c2n = cs[idx] * sc[c] + sh[c];
        const float n = nv[c];
        const float h2 = sp_f(kappa[c] * n + gp[c] * c2n + wmix[c] * n * c2n);
        const float g = g2v[c];
        const float hn = sp_f((1.f - g) * h[idx] + g * h2);
        hv[c] = hn;
        h[idx] = hn;
    }
    __align__(16) _Float16 xv[32];
    #pragma unroll
    for (int oc = 0; oc < 25; ++oc) {
        float acc = u1b[oc];
        #pragma unroll
        for (int ic = 0; ic < 25; ++ic) acc += u1w[oc * 25 + ic] * hv[ic];
        xv[oc] = (_Float16)(hv[oc] * sig_f(acc));
    }
    #pragma unroll
    for (int oc = 25; oc < 32; ++oc) xv[oc] = (_Float16)0.f;
    const int yy = pix >> 7, xx = pix & 127;
    _Float16* xp = xt + (((size_t)(b * 142 + yy + 7)) * 144 + (xx + 7)) * 32;
    #pragma unroll
    for (int i = 0; i < 4; ++i) ((float4*)xp)[i] = ((const float4*)xv)[i];
}

// ---------------- fused bn_out + avgpool2 + fc partial dot ----------------
__global__ __launch_bounds__(256) void fc1_kernel(
    const float* __restrict__ h, const float* __restrict__ scale,
    const float* __restrict__ shift, const float* __restrict__ fcw,
    float2* __restrict__ part)
{
    const int tid = threadIdx.x;
    const int i = blockIdx.x * 256 + tid;   // < 204800
    int px = i & 63;
    int t = i >> 6;
    int py = t & 63; t >>= 6;               // t = b*25 + c
    int c = t >= 25 ? t - 25 : t;
    const float* hp = h + ((size_t)t << 14);
    const int y0 = py << 1, xg = px << 1;
    float s = hp[(y0 << 7) + xg] + hp[(y0 << 7) + xg + 1]
            + hp[((y0 + 1) << 7) + xg] + hp[((y0 + 1) << 7) + xg + 1];
    const float o = 0.25f * s * scale[c] + shift[c];
    float p0 = o * fcw[i];
    float p1 = o * fcw[204800 + i];
    #pragma unroll
    for (int off = 32; off; off >>= 1) { p0 += __shfl_down(p0, off); p1 += __shfl_down(p1, off); }
    __shared__ float a0[4], a1[4];
    if ((tid & 63) == 0) { a0[tid >> 6] = p0; a1[tid >> 6] = p1; }
    __syncthreads();
    if (tid == 0)
        part[blockIdx.x] = make_float2(a0[0] + a0[1] + a0[2] + a0[3],
                                       a1[0] + a1[1] + a1[2] + a1[3]);
}

__global__ __launch_bounds__(256) void fc2_kernel(
    const float2* __restrict__ part, const float* __restrict__ fcb, float* __restrict__ out)
{
    const int tid = threadIdx.x;
    float s0 = 0.f, s1 = 0.f;
    for (int i = tid; i < 800; i += 256) { float2 v = part[i]; s0 += v.x; s1 += v.y; }
    #pragma unroll
    for (int off = 32; off; off >>= 1) { s0 += __shfl_down(s0, off); s1 += __shfl_down(s1, off); }
    __shared__ float a0[4], a1[4];
    if ((tid & 63) == 0) { a0[tid >> 6] = s0; a1[tid >> 6] = s1; }
    __syncthreads();
    if (tid == 0) {
        out[0] = sig_f(a0[0] + a0[1] + a0[2] + a0[3] + fcb[0]);
        out[1] = sig_f(a1[0] + a1[1] + a1[2] + a1[3] + fcb[1]);
    }
}

extern "C" void kernel_launch(void* const* d_in, const int* in_sizes, int n_in,
                              void* d_out, int out_size, void* d_ws, size_t ws_size,
                              hipStream_t stream)
{
    const float* x        = (const float*)d_in[0];
    const float* conv00_w = (const float*)d_in[1];
    const float* conv0_w  = (const float*)d_in[2];
    const float* conv1_w  = (const float*)d_in[3];
    const float* conv1_b  = (const float*)d_in[4];
    const float* u1_w     = (const float*)d_in[5];
    const float* u1_b     = (const float*)d_in[6];
    const float* u2_w     = (const float*)d_in[7];
    const float* u2_b     = (const float*)d_in[8];
    const float* w_inh    = (const float*)d_in[9];
    const float* w_exc    = (const float*)d_in[10];
    const float* alpha    = (const float*)d_in[11];
    const float* mu       = (const float*)d_in[12];
    const float* gamma_p  = (const float*)d_in[13];
    const float* kappa    = (const float*)d_in[14];
    const float* w_mix    = (const float*)d_in[15];
    const float* bn1_w    = (const float*)d_in[16];
    const float* bn1_b    = (const float*)d_in[17];
    const float* bn3_w    = (const float*)d_in[18];
    const float* bn3_b    = (const float*)d_in[19];
    const float* bn_out_w = (const float*)d_in[20];
    const float* bn_out_b = (const float*)d_in[21];
    const float* fc4_w    = (const float*)d_in[22];
    const float* fc4_b    = (const float*)d_in[23];

    float* ws = (float*)d_ws;
    // layout (float offsets):
    float* Y    = ws;                        // [0, 6,553,600): B0p early, then Y
    float* R    = ws + 6553600;              // front-end: APAD; then step buffers
    float* X0f  = ws + 13107200;             // X0: 583,424 fl
    float* X1f  = ws + 13690624;             // X1: 291,712 fl
    float* WT0f = ws + 13982336;             // 25,088 fl
    float* WT1cf= ws + 14007424;             // 12,544 fl
    float* WT1f = ws + 14019968;             // 115,200 fl
    float* WT2f = ws + 14135168;             // 115,200 fl
    float* XTf  = ws + 14250368;             // 654,336 fl
    float* SC1  = ws + 14904704;
    float* SH1  = SC1 + 32;
    float* PART = SH1 + 32;                  // 1600 (800 x float2)
    float* PS   = PART + 1600;               // 400 (200 x float2)

    float* B0p  = Y;                         // 25 partials x 262,144
    float* H    = R;                         // step buffers: H, NS1, CS, CP[4]
    float* NS1  = R + 1 * NELEM;
    float* CS   = R + 2 * NELEM;
    float* CP   = R + 3 * NELEM;             // 4 partials

    _Float16* APAD = (_Float16*)R;           // [2*25][8][136][136] f16
    _Float16* X0  = (_Float16*)X0f;
    _Float16* X1  = (_Float16*)X1f;
    _Float16* WT0 = (_Float16*)WT0f;
    _Float16* WT1c= (_Float16*)WT1cf;
    _Float16* WT1 = (_Float16*)WT1f;
    _Float16* WT2 = (_Float16*)WT2f;
    _Float16* XT  = (_Float16*)XTf;

    // ---- front-end ----
    (void)hipMemsetAsync(APAD, 0, (size_t)7398400 * sizeof(_Float16), stream);
    (void)hipMemsetAsync(X0, 0, (size_t)1166848 * sizeof(_Float16), stream);
    (void)hipMemsetAsync(X1, 0, (size_t)583424 * sizeof(_Float16), stream);
    (void)hipMemsetAsync(XT, 0, (size_t)1308672 * sizeof(_Float16), stream);
    xpack0_kernel<<<1024, 256, 0, stream>>>(x, X0);
    repack_w00_kernel<<<196, 256, 0, stream>>>(conv00_w, WT0);
    repack_w1_kernel<<<98, 256, 0, stream>>>(conv1_w, WT1c);
    repack_w_kernel<<<900, 256, 0, stream>>>(w_inh, WT1);
    repack_w_kernel<<<900, 256, 0, stream>>>(w_exc, WT2);

    conv3d00_mfma<<<2048, 128, 0, stream>>>(X0, WT0, APAD);
    conv3d0_direct<<<dim3(8, 25, 16), 128, 0, stream>>>(APAD, conv0_w, B0p);
    xpack1_kernel<<<1024, 256, 0, stream>>>(B0p, X1);
    conv3d1_mfma<<<2048, 128, 0, stream>>>(X1, WT1c, conv1_b, Y);

    // ---- recurrence ----
    (void)hipMemsetAsync(H, 0, (size_t)NELEM * sizeof(float), stream);
    for (int t = 0; t < 8; ++t) {
        conv2d15_mfma<<<dim3(128, 4), 256, 0, stream>>>(XT, WT1, CP);
        bnstats1_kernel<4, true><<<dim3(25, 8), 256, 0, stream>>>(CP, CS, (float2*)PS);
        nsg_kernel<<<128, 256, 0, stream>>>(Y, H, CS, (const float2*)PS, bn1_w, bn1_b,
                                            alpha, mu, NS1, XT, t);
        conv2d15_mfma<<<dim3(128, 4), 256, 0, stream>>>(XT, WT2, CP);
        bnstats1_kernel<4, true><<<dim3(25, 8), 256, 0, stream>>>(CP, CS, (float2*)PS);
        hg_kernel<<<128, 256, 0, stream>>>(H, NS1, CS, (const float2*)PS, bn3_w, bn3_b,
                                           kappa, gamma_p, w_mix, u1_w, u1_b, u2_w, u2_b, XT);
    }

    // ---- head ----
    bnstats1_kernel<1, false><<<dim3(25, 8), 256, 0, stream>>>(H, nullptr, (float2*)PS);
    bnstats2_kernel<<<1, 64, 0, stream>>>((const float2*)PS, bn_out_w, bn_out_b, SC1, SH1);
    fc1_kernel<<<800, 256, 0, stream>>>(H, SC1, SH1, fc4_w, (float2*)PART);
    fc2_kernel<<<1, 256, 0, stream>>>((const float2*)PART, fc4_b, (float*)d_out);
}